// Round 9
// baseline (214.257 us; speedup 1.0000x reference)
//
#include <hip/hip_runtime.h>
#include <math.h>

#define NPTS 262144
#define GBLK (NPTS / 128)     // 2048 gate blocks (128 points each)
#define CPE  2048             // chunks per expert in expert grid
#define TAU  0.01f            // refine margin threshold (logit units)

typedef float f4v __attribute__((ext_vector_type(4)));
typedef short s8v __attribute__((ext_vector_type(8)));

// manual RNE (used in prep only; identical rounding to HW cvt)
static __device__ __forceinline__ unsigned short f2bf(float f) {
    unsigned u = __float_as_uint(f);
    u += 0x7fffu + ((u >> 16) & 1u);
    return (unsigned short)(u >> 16);
}
// HW bf16 convert path: clang lowers paired fptrunc to v_cvt_pk_bf16_f32 (RNE)
static __device__ __forceinline__ unsigned short f2bf_hw(float f) {
    __bf16 b = (__bf16)f;
    unsigned short u;
    __builtin_memcpy(&u, &b, 2);
    return u;
}
static __device__ __forceinline__ float bf2f(unsigned short h) {
    return __uint_as_float(((unsigned)h) << 16);
}
static __device__ __forceinline__ unsigned pk2b(unsigned short lo, unsigned short hi) {
    return ((unsigned)hi << 16) | (unsigned)lo;
}
static __device__ __forceinline__ unsigned cpack(float lo, float hi) {
    return pk2b(f2bf_hw(lo), f2bf_hw(hi));
}
static __device__ __forceinline__ float sinrev(float x) {   // sin(2*pi*x)
    return __builtin_amdgcn_sinf(x);
}

union BFrag { uint4 q; unsigned u[4]; s8v s; };

// ---------------- prep: pack expert A-frags + scaled biases + gate hi/lo packs ----------------
__global__ __launch_bounds__(256) void prep_kernel(
    const float* __restrict__ we0, const float* __restrict__ be0,
    const float* __restrict__ wm, const float* __restrict__ bm,
    const float* __restrict__ gw1, const float* __restrict__ gw2,
    uint4* __restrict__ packA, float* __restrict__ biasS,
    uint4* __restrict__ packGW1H, uint4* __restrict__ packGW1L,
    uint4* __restrict__ packGW2H, uint4* __restrict__ packGW2L)
{
    const int idx = blockIdx.x * 256 + threadIdx.x;
    const float PI2I = 0.15915494309189535f;
    if (idx < 12288) {
        const int l = idx & 63;
        const int fr = (idx >> 6) & 7;
        const int grp = idx >> 9;            // e*3 + ell
        const int e = grp / 3, ell = grp % 3;
        const int tau = fr >> 1, ks = fr & 1;
        const int g = l >> 4, m = l & 15;
        const int row = tau * 16 + m;
        const float scale = (ell == 0) ? (22.5f + 45.0f * (float)e) * PI2I : 30.0f * PI2I;
        const float* W = (ell == 0) ? (we0 + e * 4096) : (wm + ((ell - 1) * 8 + e) * 4096);
        unsigned short v[8];
#pragma unroll
        for (int i = 0; i < 8; i++) {
            const int k = 32 * ks + 4 * g + (i < 4 ? i : i + 12);
            v[i] = f2bf(W[row * 64 + k] * scale);
        }
        uint4 q;
        q.x = pk2b(v[0], v[1]); q.y = pk2b(v[2], v[3]);
        q.z = pk2b(v[4], v[5]); q.w = pk2b(v[6], v[7]);
        packA[idx] = q;
    } else if (idx < 13824) {
        const int j = idx - 12288;           // e*192 + ell*64 + r
        const int r = j & 63;
        const int grp = j >> 6;
        const int e = grp / 3, ell = grp % 3;
        const float scale = (ell == 0) ? (22.5f + 45.0f * (float)e) * PI2I : 30.0f * PI2I;
        const float b = (ell == 0) ? be0[e * 64 + r] : bm[((ell - 1) * 8 + e) * 64 + r];
        biasS[j] = b * scale;
    } else if (idx < 14336) {
        // gate gw1 hi/lo A-frags: 8 frags (tau*2+ks) x 64 lanes
        const int j = idx - 13824;           // 0..511
        const int l = j & 63;
        const int fr = j >> 6;
        const int tau = fr >> 1, ks = fr & 1;
        const int g = l >> 4;
        const int row = tau * 16 + (l & 15);
        unsigned short vh[8], vl[8];
#pragma unroll
        for (int i = 0; i < 8; i++) {
            const int k = 32 * ks + 4 * g + (i < 4 ? i : i + 12);
            const float x = gw1[row * 64 + k];
            const unsigned short h = f2bf(x);
            vh[i] = h;
            vl[i] = f2bf(x - bf2f(h));
        }
        uint4 qh, ql;
        qh.x = pk2b(vh[0], vh[1]); qh.y = pk2b(vh[2], vh[3]);
        qh.z = pk2b(vh[4], vh[5]); qh.w = pk2b(vh[6], vh[7]);
        ql.x = pk2b(vl[0], vl[1]); ql.y = pk2b(vl[2], vl[3]);
        ql.z = pk2b(vl[4], vl[5]); ql.w = pk2b(vl[6], vl[7]);
        packGW1H[j] = qh; packGW1L[j] = ql;
    } else if (idx < 14464) {
        // gate gw2 hi/lo A-frags: rows 0..7 = gw2, rows 8..15 = 0; 2 frags (ks) x 64 lanes
        const int j = idx - 14336;           // 0..127
        const int l = j & 63;
        const int ks = j >> 6;
        const int g = l >> 4;
        const int row = l & 15;
        unsigned short vh[8], vl[8];
#pragma unroll
        for (int i = 0; i < 8; i++) {
            const int k = 32 * ks + 4 * g + (i < 4 ? i : i + 12);
            const float x = (row < 8) ? gw2[row * 64 + k] : 0.f;
            const unsigned short h = f2bf(x);
            vh[i] = h;
            vl[i] = f2bf(x - bf2f(h));
        }
        uint4 qh, ql;
        qh.x = pk2b(vh[0], vh[1]); qh.y = pk2b(vh[2], vh[3]);
        qh.z = pk2b(vh[4], vh[5]); qh.w = pk2b(vh[6], vh[7]);
        ql.x = pk2b(vl[0], vl[1]); ql.y = pk2b(vl[2], vl[3]);
        ql.z = pk2b(vl[4], vl[5]); ql.w = pk2b(vl[6], vl[7]);
        packGW2H[j] = qh; packGW2L[j] = ql;
    }
}

// ---------------- K1: gate via MFMA (hi/lo split) + FUSED in-wave fp32 refine ----------------
// 512 threads = 8 waves x 16 points = 128 points per block.
__global__ __launch_bounds__(512) void gate_kernel(
    const float* __restrict__ coords,
    const float* __restrict__ fw, const float* __restrict__ fb,
    const float* __restrict__ gw1, const float* __restrict__ gb1,
    const float* __restrict__ lng, const float* __restrict__ lnb,
    const float* __restrict__ gw2, const float* __restrict__ gb2,
    const uint4* __restrict__ packGW1H, const uint4* __restrict__ packGW1L,
    const uint4* __restrict__ packGW2H, const uint4* __restrict__ packGW2L,
    unsigned char* __restrict__ sel, int* __restrict__ blkcnt)
{
    __shared__ float s_fw[192], s_fb[64], s_gb1[64], s_lng[64], s_lnb[64], s_gb2[8];
    __shared__ int s_cnt[8];
    const int t = threadIdx.x;
    if (t < 192) s_fw[t] = fw[t];
    if (t < 64) { s_fb[t] = fb[t]; s_gb1[t] = gb1[t]; s_lng[t] = lng[t]; s_lnb[t] = lnb[t]; }
    if (t < 8) { s_gb2[t] = gb2[t]; s_cnt[t] = 0; }
    __syncthreads();

    const int lane = t & 63;
    const int wv = t >> 6;
    const int g = lane >> 4, c = lane & 15;
    const int n = blockIdx.x * 128 + wv * 16 + c;

    // ---- features: this lane's 16 k-values of point n (fp32, exact order) ----
    const float c0 = coords[n * 3], c1 = coords[n * 3 + 1], c2 = coords[n * 3 + 2];
    float fv[16];
#pragma unroll
    for (int s = 0; s < 4; s++) {
#pragma unroll
        for (int j = 0; j < 4; j++) {
            const int k = 16 * s + 4 * g + j;
            fv[s * 4 + j] = s_fb[k] + c0 * s_fw[k * 3] + c1 * s_fw[k * 3 + 1] + c2 * s_fw[k * 3 + 2];
        }
    }
    unsigned short fh[16]; float fl[16];
#pragma unroll
    for (int i = 0; i < 16; i++) {
        fh[i] = f2bf_hw(fv[i]);
        fl[i] = fv[i] - bf2f(fh[i]);
    }
    BFrag Bh[2], Bl[2];
#pragma unroll
    for (int ks = 0; ks < 2; ks++) {
#pragma unroll
        for (int q = 0; q < 4; q++) {
            Bh[ks].u[q] = pk2b(fh[ks * 8 + 2 * q], fh[ks * 8 + 2 * q + 1]);
            Bl[ks].u[q] = cpack(fl[ks * 8 + 2 * q], fl[ks * 8 + 2 * q + 1]);
        }
    }

    // ---- g = gw1 @ f + gb1 via 3-term MFMA ----
    f4v acc[4];
#pragma unroll
    for (int tau = 0; tau < 4; tau++) {
        const float4 b = *(const float4*)&s_gb1[tau * 16 + 4 * g];
        acc[tau][0] = b.x; acc[tau][1] = b.y; acc[tau][2] = b.z; acc[tau][3] = b.w;
    }
#pragma unroll
    for (int tau = 0; tau < 4; tau++) {
        BFrag AH0, AH1, AL0, AL1;
        AH0.q = packGW1H[(tau * 2 + 0) * 64 + lane];
        AH1.q = packGW1H[(tau * 2 + 1) * 64 + lane];
        AL0.q = packGW1L[(tau * 2 + 0) * 64 + lane];
        AL1.q = packGW1L[(tau * 2 + 1) * 64 + lane];
        acc[tau] = __builtin_amdgcn_mfma_f32_16x16x32_bf16(AH0.s, Bh[0].s, acc[tau], 0, 0, 0);
        acc[tau] = __builtin_amdgcn_mfma_f32_16x16x32_bf16(AH1.s, Bh[1].s, acc[tau], 0, 0, 0);
        acc[tau] = __builtin_amdgcn_mfma_f32_16x16x32_bf16(AH0.s, Bl[0].s, acc[tau], 0, 0, 0);
        acc[tau] = __builtin_amdgcn_mfma_f32_16x16x32_bf16(AH1.s, Bl[1].s, acc[tau], 0, 0, 0);
        acc[tau] = __builtin_amdgcn_mfma_f32_16x16x32_bf16(AL0.s, Bh[0].s, acc[tau], 0, 0, 0);
        acc[tau] = __builtin_amdgcn_mfma_f32_16x16x32_bf16(AL1.s, Bh[1].s, acc[tau], 0, 0, 0);
    }

    // ---- LayerNorm over the 64 rows (cross-lane over g groups) ----
    float s1 = 0.f;
#pragma unroll
    for (int tau = 0; tau < 4; tau++)
#pragma unroll
        for (int j = 0; j < 4; j++) s1 += acc[tau][j];
    s1 += __shfl_xor(s1, 16, 64); s1 += __shfl_xor(s1, 32, 64);
    const float mu = s1 * (1.f / 64.f);
    float s2 = 0.f;
#pragma unroll
    for (int tau = 0; tau < 4; tau++)
#pragma unroll
        for (int j = 0; j < 4; j++) { const float d = acc[tau][j] - mu; s2 += d * d; }
    s2 += __shfl_xor(s2, 16, 64); s2 += __shfl_xor(s2, 32, 64);
    const float rs = rsqrtf(s2 * (1.f / 64.f) + 1e-5f);

    float gn[16];
#pragma unroll
    for (int tau = 0; tau < 4; tau++) {
        const float4 lg = *(const float4*)&s_lng[tau * 16 + 4 * g];
        const float4 lb = *(const float4*)&s_lnb[tau * 16 + 4 * g];
        gn[tau * 4 + 0] = (acc[tau][0] - mu) * rs * lg.x + lb.x;
        gn[tau * 4 + 1] = (acc[tau][1] - mu) * rs * lg.y + lb.y;
        gn[tau * 4 + 2] = (acc[tau][2] - mu) * rs * lg.z + lb.z;
        gn[tau * 4 + 3] = (acc[tau][3] - mu) * rs * lg.w + lb.w;
    }
    unsigned short gh[16]; float gl[16];
#pragma unroll
    for (int i = 0; i < 16; i++) { gh[i] = f2bf_hw(gn[i]); gl[i] = gn[i] - bf2f(gh[i]); }
    BFrag Gh[2], Gl[2];
#pragma unroll
    for (int ks = 0; ks < 2; ks++) {
        Gh[ks].u[0] = pk2b(gh[(2 * ks) * 4 + 0], gh[(2 * ks) * 4 + 1]);
        Gh[ks].u[1] = pk2b(gh[(2 * ks) * 4 + 2], gh[(2 * ks) * 4 + 3]);
        Gh[ks].u[2] = pk2b(gh[(2 * ks + 1) * 4 + 0], gh[(2 * ks + 1) * 4 + 1]);
        Gh[ks].u[3] = pk2b(gh[(2 * ks + 1) * 4 + 2], gh[(2 * ks + 1) * 4 + 3]);
        Gl[ks].u[0] = cpack(gl[(2 * ks) * 4 + 0], gl[(2 * ks) * 4 + 1]);
        Gl[ks].u[1] = cpack(gl[(2 * ks) * 4 + 2], gl[(2 * ks) * 4 + 3]);
        Gl[ks].u[2] = cpack(gl[(2 * ks + 1) * 4 + 0], gl[(2 * ks + 1) * 4 + 1]);
        Gl[ks].u[3] = cpack(gl[(2 * ks + 1) * 4 + 2], gl[(2 * ks + 1) * 4 + 3]);
    }

    // ---- logits = gw2 @ gn via 3-term MFMA (rows 0..7 valid) ----
    f4v lacc = {0.f, 0.f, 0.f, 0.f};
    BFrag W0, W1, V0, V1;
    W0.q = packGW2H[0 * 64 + lane]; W1.q = packGW2H[1 * 64 + lane];
    V0.q = packGW2L[0 * 64 + lane]; V1.q = packGW2L[1 * 64 + lane];
    lacc = __builtin_amdgcn_mfma_f32_16x16x32_bf16(W0.s, Gh[0].s, lacc, 0, 0, 0);
    lacc = __builtin_amdgcn_mfma_f32_16x16x32_bf16(W1.s, Gh[1].s, lacc, 0, 0, 0);
    lacc = __builtin_amdgcn_mfma_f32_16x16x32_bf16(W0.s, Gl[0].s, lacc, 0, 0, 0);
    lacc = __builtin_amdgcn_mfma_f32_16x16x32_bf16(W1.s, Gl[1].s, lacc, 0, 0, 0);
    lacc = __builtin_amdgcn_mfma_f32_16x16x32_bf16(V0.s, Gh[0].s, lacc, 0, 0, 0);
    lacc = __builtin_amdgcn_mfma_f32_16x16x32_bf16(V1.s, Gh[1].s, lacc, 0, 0, 0);

    float other[4];
#pragma unroll
    for (int j = 0; j < 4; j++) other[j] = __shfl_xor(lacc[j], 16, 64);
    float logit[8];
#pragma unroll
    for (int j = 0; j < 4; j++) {
        logit[j] = lacc[j] + s_gb2[j];
        logit[4 + j] = other[j] + s_gb2[4 + j];
    }

    // ---- top-2 (>= 2nd-largest semantics) + margin flag ----
    float m1 = logit[0]; int i1 = 0;
#pragma unroll
    for (int e = 1; e < 8; e++) if (logit[e] > m1) { m1 = logit[e]; i1 = e; }
    float m2 = -INFINITY; int i2 = -1;
#pragma unroll
    for (int e = 0; e < 8; e++) if (e != i1 && logit[e] > m2) { m2 = logit[e]; i2 = e; }
    float m3 = -INFINITY;
#pragma unroll
    for (int e = 0; e < 8; e++) if (e != i1 && e != i2 && logit[e] > m3) m3 = logit[e];
    unsigned mbits = 0;
#pragma unroll
    for (int e = 0; e < 8; e++) if (logit[e] >= m2) mbits |= 1u << e;

    const bool active = (g == 0);
    const bool flg = active && (m2 - m3 < TAU);

    // ---- FUSED refine: exact-fp32 recompute for flagged points (64-lane cooperative) ----
    unsigned long long fmask = __ballot(flg);
    while (fmask) {
        const int src = (int)__ffsll((long long)fmask) - 1;
        fmask &= fmask - 1;
        const int pn = __shfl(n, src, 64);
        const float rc0 = coords[pn * 3], rc1 = coords[pn * 3 + 1], rc2 = coords[pn * 3 + 2];
        float a = s_gb1[lane];
        const float* wrow = gw1 + lane * 64;
#pragma unroll
        for (int k4 = 0; k4 < 16; k4++) {
            const float4 w = *(const float4*)&wrow[k4 * 4];
            const int k = 4 * k4;
            const float fk0 = s_fb[k] + rc0 * s_fw[k * 3] + rc1 * s_fw[k * 3 + 1] + rc2 * s_fw[k * 3 + 2];
            const float fk1 = s_fb[k + 1] + rc0 * s_fw[(k + 1) * 3] + rc1 * s_fw[(k + 1) * 3 + 1] + rc2 * s_fw[(k + 1) * 3 + 2];
            const float fk2 = s_fb[k + 2] + rc0 * s_fw[(k + 2) * 3] + rc1 * s_fw[(k + 2) * 3 + 1] + rc2 * s_fw[(k + 2) * 3 + 2];
            const float fk3 = s_fb[k + 3] + rc0 * s_fw[(k + 3) * 3] + rc1 * s_fw[(k + 3) * 3 + 1] + rc2 * s_fw[(k + 3) * 3 + 2];
            a += fk0 * w.x + fk1 * w.y + fk2 * w.z + fk3 * w.w;
        }
        float rmu = a;
#pragma unroll
        for (int d = 1; d < 64; d <<= 1) rmu += __shfl_xor(rmu, d, 64);
        rmu *= (1.f / 64.f);
        const float dv = a - rmu;
        float vv = dv * dv;
#pragma unroll
        for (int d = 1; d < 64; d <<= 1) vv += __shfl_xor(vv, d, 64);
        const float rrs = rsqrtf(vv * (1.f / 64.f) + 1e-5f);
        const float gnr = dv * rrs * s_lng[lane] + s_lnb[lane];
        float lp[8];
#pragma unroll
        for (int e = 0; e < 8; e++) lp[e] = gnr * gw2[e * 64 + lane];
#pragma unroll
        for (int e = 0; e < 8; e++) {
#pragma unroll
            for (int d = 1; d < 64; d <<= 1) lp[e] += __shfl_xor(lp[e], d, 64);
            lp[e] += s_gb2[e];
        }
        // top-2 (computed redundantly on all lanes)
        float r1 = lp[0]; int j1 = 0;
#pragma unroll
        for (int e = 1; e < 8; e++) if (lp[e] > r1) { r1 = lp[e]; j1 = e; }
        float r2 = -INFINITY;
#pragma unroll
        for (int e = 0; e < 8; e++) if (e != j1 && lp[e] > r2) r2 = lp[e];
        unsigned rm = 0;
#pragma unroll
        for (int e = 0; e < 8; e++) if (lp[e] >= r2) rm |= 1u << e;
        if (lane == src) mbits = rm;
    }

    if (active) sel[n] = (unsigned char)mbits;
#pragma unroll
    for (int e = 0; e < 8; e++) {
        const unsigned long long bal = __ballot(active && ((mbits >> e) & 1u));
        if (lane == 0) atomicAdd(&s_cnt[e], (int)__popcll(bal));
    }
    __syncthreads();
    if (t < 8) blkcnt[blockIdx.x * 8 + t] = s_cnt[t];
}

// ---------------- K1.5: single-block scan -> baseoff, counts, aux ----------------
__global__ __launch_bounds__(256) void scan_kernel(
    const int* __restrict__ blkcnt, int* __restrict__ baseoff,
    int* __restrict__ counts, float* __restrict__ out)
{
    __shared__ int s_tot[8];
    const int t = threadIdx.x;
    const int e = t >> 5;        // 8 experts x 32 lanes
    const int q = t & 31;
    const int b0 = q * (GBLK / 32);
    int partial = 0;
    for (int b = b0; b < b0 + GBLK / 32; b++) partial += blkcnt[b * 8 + e];
    int incl = partial;
#pragma unroll
    for (int d = 1; d < 32; d <<= 1) {
        const int v = __shfl_up(incl, d, 32);
        if (q >= d) incl += v;
    }
    const int excl = incl - partial;
    const int total = __shfl(incl, 31, 32);
    if (q == 0) { counts[e] = total; s_tot[e] = total; }
    int run = excl;
    for (int b = b0; b < b0 + GBLK / 32; b++) {
        baseoff[b * 8 + e] = run;
        run += blkcnt[b * 8 + e];
    }
    __syncthreads();
    if (t == 0) {
        double s = 0.0;
        for (int i = 0; i < 8; i++) { const double c = (double)s_tot[i]; s += c * c; }
        out[NPTS] = (float)(8.0 * s / ((double)NPTS * (double)NPTS));
    }
}

// ---------------- K2: scatter points into buckets (no atomics) + zero out[] ----------------
__global__ __launch_bounds__(128) void scatter_kernel(
    const unsigned char* __restrict__ sel, const int* __restrict__ baseoff,
    int* __restrict__ buckets, float* __restrict__ out)
{
    __shared__ int s_w0[8];
    const int t = threadIdx.x;
    const int n = blockIdx.x * 128 + t;
    out[n] = 0.f;                        // replaces hipMemsetAsync(d_out)
    const unsigned m = sel[n];
    const int w = t >> 6, lane = t & 63;
    unsigned long long bal[8];
#pragma unroll
    for (int e = 0; e < 8; e++) {
        bal[e] = __ballot((m >> e) & 1u);
        if (w == 0 && lane == 0) s_w0[e] = (int)__popcll(bal[e]);
    }
    __syncthreads();
#pragma unroll
    for (int e = 0; e < 8; e++) {
        if ((m >> e) & 1u) {
            int rank = (int)__popcll(bal[e] & ((1ull << lane) - 1ull));
            if (w == 1) rank += s_w0[e];
            buckets[e * NPTS + baseoff[blockIdx.x * 8 + e] + rank] = n;
        }
    }
}

// ---------------- K3: per-expert MFMA SIREN; direct per-lane fragment build (no s_ft) ----------------
__global__ __launch_bounds__(256) void expert_kernel(
    const float* __restrict__ coords,
    const float* __restrict__ fw, const float* __restrict__ fb,
    const float* __restrict__ wl, const float* __restrict__ bl,
    const uint4* __restrict__ packA, const float* __restrict__ biasS,
    const int* __restrict__ counts, const int* __restrict__ buckets,
    float* __restrict__ out)
{
    const int e = blockIdx.x >> 11;            // CPE == 2048
    const int chunk = blockIdx.x & (CPE - 1);
    const int cnt = counts[e];
    const int base = chunk * 128;
    if (base >= cnt) return;

    __shared__ float s_b[192];
    __shared__ float s_wl[64];
    __shared__ float s_fw[192];
    __shared__ float s_fb[64];
    __shared__ float s_bl;

    const int t = threadIdx.x;
    if (t < 192) {
        s_b[t] = biasS[e * 192 + t];
        s_fw[t] = fw[t];
    }
    if (t < 64) {
        s_fb[t] = fb[t];
        s_wl[t] = wl[e * 64 + t];
    }
    if (t == 0) s_bl = bl[e];
    __syncthreads();

    const int lane = t & 63;
    const int wv = t >> 6;
    const int g = lane >> 4, c = lane & 15;
    const int i0 = base + wv * 32 + c;
    const int i1 = i0 + 16;
    const int id0 = (i0 < cnt) ? buckets[e * NPTS + i0] : -1;
    const int id1 = (i1 < cnt) ? buckets[e * NPTS + i1] : -1;

    // ---- direct per-lane B-fragment features: lane needs k = 16s + 4g + j (s=0..3, j=0..3) ----
    BFrag B0[2], B1[2];
    {
        const float a0 = (id0 >= 0) ? coords[id0 * 3] : 0.f;
        const float a1 = (id0 >= 0) ? coords[id0 * 3 + 1] : 0.f;
        const float a2 = (id0 >= 0) ? coords[id0 * 3 + 2] : 0.f;
        const float b0 = (id1 >= 0) ? coords[id1 * 3] : 0.f;
        const float b1 = (id1 >= 0) ? coords[id1 * 3 + 1] : 0.f;
        const float b2 = (id1 >= 0) ? coords[id1 * 3 + 2] : 0.f;
        float f0[4][4], f1[4][4];
#pragma unroll
        for (int s = 0; s < 4; s++) {
#pragma unroll
            for (int j = 0; j < 4; j++) {
                const int k = 16 * s + 4 * g + j;
                const float wx = s_fw[k * 3], wy = s_fw[k * 3 + 1], wz = s_fw[k * 3 + 2];
                const float bb = s_fb[k];
                f0[s][j] = bb + a0 * wx + a1 * wy + a2 * wz;
                f1[s][j] = bb + b0 * wx + b1 * wy + b2 * wz;
            }
        }
#pragma unroll
        for (int ks = 0; ks < 2; ks++) {
            B0[ks].u[0] = cpack(f0[2 * ks][0], f0[2 * ks][1]);
            B0[ks].u[1] = cpack(f0[2 * ks][2], f0[2 * ks][3]);
            B0[ks].u[2] = cpack(f0[2 * ks + 1][0], f0[2 * ks + 1][1]);
            B0[ks].u[3] = cpack(f0[2 * ks + 1][2], f0[2 * ks + 1][3]);
            B1[ks].u[0] = cpack(f1[2 * ks][0], f1[2 * ks][1]);
            B1[ks].u[1] = cpack(f1[2 * ks][2], f1[2 * ks][3]);
            B1[ks].u[2] = cpack(f1[2 * ks + 1][0], f1[2 * ks + 1][1]);
            B1[ks].u[3] = cpack(f1[2 * ks + 1][2], f1[2 * ks + 1][3]);
        }
    }

#pragma unroll 1
    for (int ell = 0; ell < 2; ell++) {
        f4v acc0[4], acc1[4];
#pragma unroll
        for (int tau = 0; tau < 4; tau++) {
            const float4 b = *(const float4*)&s_b[ell * 64 + tau * 16 + 4 * g];
            acc0[tau][0] = b.x; acc0[tau][1] = b.y; acc0[tau][2] = b.z; acc0[tau][3] = b.w;
            acc1[tau][0] = b.x; acc1[tau][1] = b.y; acc1[tau][2] = b.z; acc1[tau][3] = b.w;
        }
        const uint4* Ab = packA + (size_t)((e * 3 + ell) * 8) * 64 + lane;
#pragma unroll
        for (int tau = 0; tau < 4; tau++) {
            BFrag A0, A1;
            A0.q = Ab[(tau * 2 + 0) * 64];
            A1.q = Ab[(tau * 2 + 1) * 64];
            acc0[tau] = __builtin_amdgcn_mfma_f32_16x16x32_bf16(A0.s, B0[0].s, acc0[tau], 0, 0, 0);
            acc0[tau] = __builtin_amdgcn_mfma_f32_16x16x32_bf16(A1.s, B0[1].s, acc0[tau], 0, 0, 0);
            acc1[tau] = __builtin_amdgcn_mfma_f32_16x16x32_bf16(A0.s, B1[0].s, acc1[tau], 0, 0, 0);
            acc1[tau] = __builtin_amdgcn_mfma_f32_16x16x32_bf16(A1.s, B1[1].s, acc1[tau], 0, 0, 0);
        }
        // sin + repack: D registers become next layer's B fragments
#pragma unroll
        for (int ks = 0; ks < 2; ks++) {
            B0[ks].u[0] = cpack(sinrev(acc0[2 * ks][0]), sinrev(acc0[2 * ks][1]));
            B0[ks].u[1] = cpack(sinrev(acc0[2 * ks][2]), sinrev(acc0[2 * ks][3]));
            B0[ks].u[2] = cpack(sinrev(acc0[2 * ks + 1][0]), sinrev(acc0[2 * ks + 1][1]));
            B0[ks].u[3] = cpack(sinrev(acc0[2 * ks + 1][2]), sinrev(acc0[2 * ks + 1][3]));
            B1[ks].u[0] = cpack(sinrev(acc1[2 * ks][0]), sinrev(acc1[2 * ks][1]));
            B1[ks].u[1] = cpack(sinrev(acc1[2 * ks][2]), sinrev(acc1[2 * ks][3]));
            B1[ks].u[2] = cpack(sinrev(acc1[2 * ks + 1][0]), sinrev(acc1[2 * ks + 1][1]));
            B1[ks].u[3] = cpack(sinrev(acc1[2 * ks + 1][2]), sinrev(acc1[2 * ks + 1][3]));
        }
    }

    // ---- layer 2 + final dot ----
    {
        f4v acc0[4], acc1[4];
#pragma unroll
        for (int tau = 0; tau < 4; tau++) {
            const float4 b = *(const float4*)&s_b[2 * 64 + tau * 16 + 4 * g];
            acc0[tau][0] = b.x; acc0[tau][1] = b.y; acc0[tau][2] = b.z; acc0[tau][3] = b.w;
            acc1[tau][0] = b.x; acc1[tau][1] = b.y; acc1[tau][2] = b.z; acc1[tau][3] = b.w;
        }
        const uint4* Ab = packA + (size_t)((e * 3 + 2) * 8) * 64 + lane;
#pragma unroll
        for (int tau = 0; tau < 4; tau++) {
            BFrag A0, A1;
            A0.q = Ab[(tau * 2 + 0) * 64];
            A1.q = Ab[(tau * 2 + 1) * 64];
            acc0[tau] = __builtin_amdgcn_mfma_f32_16x16x32_bf16(A0.s, B0[0].s, acc0[tau], 0, 0, 0);
            acc0[tau] = __builtin_amdgcn_mfma_f32_16x16x32_bf16(A1.s, B0[1].s, acc0[tau], 0, 0, 0);
            acc1[tau] = __builtin_amdgcn_mfma_f32_16x16x32_bf16(A0.s, B1[0].s, acc1[tau], 0, 0, 0);
            acc1[tau] = __builtin_amdgcn_mfma_f32_16x16x32_bf16(A1.s, B1[1].s, acc1[tau], 0, 0, 0);
        }
        float px0 = 0.f, px1 = 0.f;
#pragma unroll
        for (int tau = 0; tau < 4; tau++) {
            const float4 w = *(const float4*)&s_wl[tau * 16 + 4 * g];
            px0 += sinrev(acc0[tau][0]) * w.x + sinrev(acc0[tau][1]) * w.y
                 + sinrev(acc0[tau][2]) * w.z + sinrev(acc0[tau][3]) * w.w;
            px1 += sinrev(acc1[tau][0]) * w.x + sinrev(acc1[tau][1]) * w.y
                 + sinrev(acc1[tau][2]) * w.z + sinrev(acc1[tau][3]) * w.w;
        }
        px0 += __shfl_xor(px0, 16, 64); px0 += __shfl_xor(px0, 32, 64);
        px1 += __shfl_xor(px1, 16, 64); px1 += __shfl_xor(px1, 32, 64);
        if (g == 0) {
            if (id0 >= 0) atomicAdd(&out[id0], px0 + s_bl);
            if (id1 >= 0) atomicAdd(&out[id1], px1 + s_bl);
        }
    }
}

extern "C" void kernel_launch(void* const* d_in, const int* in_sizes, int n_in,
                              void* d_out, int out_size, void* d_ws, size_t ws_size,
                              hipStream_t stream)
{
    const float* coords = (const float*)d_in[0];
    const float* fw  = (const float*)d_in[1];
    const float* fb  = (const float*)d_in[2];
    const float* gw1 = (const float*)d_in[3];
    const float* gb1 = (const float*)d_in[4];
    const float* lng = (const float*)d_in[5];
    const float* lnb = (const float*)d_in[6];
    const float* gw2 = (const float*)d_in[7];
    const float* gb2 = (const float*)d_in[8];
    const float* we0 = (const float*)d_in[9];
    const float* be0 = (const float*)d_in[10];
    const float* wm  = (const float*)d_in[11];
    const float* bm  = (const float*)d_in[12];
    const float* wl  = (const float*)d_in[13];
    const float* bl  = (const float*)d_in[14];
    float* out = (float*)d_out;

    char* ws = (char*)d_ws;
    int* counts           = (int*)ws;                        // 64
    int* buckets          = (int*)(ws + 64);                 // 8*NPTS*4 = 8388608
    uint4* packA          = (uint4*)(ws + 8388672);          // 196608
    float* biasS          = (float*)(ws + 8585280);          // 6144
    int* blkcnt           = (int*)(ws + 8591424);            // 65536
    int* baseoff          = (int*)(ws + 8656960);            // 65536
    unsigned char* sel    = (unsigned char*)(ws + 8722496);  // 262144
    uint4* packGW1H       = (uint4*)(ws + 8984640);          // 8192
    uint4* packGW1L       = (uint4*)(ws + 8992832);          // 8192
    uint4* packGW2H       = (uint4*)(ws + 9001024);          // 2048
    uint4* packGW2L       = (uint4*)(ws + 9003072);          // 2048

    prep_kernel<<<57, 256, 0, stream>>>(we0, be0, wm, bm, gw1, gw2, packA, biasS,
                                        packGW1H, packGW1L, packGW2H, packGW2L);
    gate_kernel<<<GBLK, 512, 0, stream>>>(coords, fw, fb, gw1, gb1, lng, lnb, gw2, gb2,
                                          packGW1H, packGW1L, packGW2H, packGW2L,
                                          sel, blkcnt);
    scan_kernel<<<1, 256, 0, stream>>>(blkcnt, baseoff, counts, out);
    scatter_kernel<<<GBLK, 128, 0, stream>>>(sel, baseoff, buckets, out);
    expert_kernel<<<8 * CPE, 256, 0, stream>>>(coords, fw, fb, wl, bl, packA, biasS,
                                               counts, buckets, out);
}

// Round 10
// 124.795 us; speedup vs baseline: 1.7169x; 1.7169x over previous
//
#include <hip/hip_runtime.h>
#include <math.h>

#define NPTS 262144
#define GBLK (NPTS / 128)     // 2048 gate blocks (128 points each)
#define CPE  2048             // chunks per expert in expert grid
#define TAU  0.01f            // refine margin threshold (logit units)

typedef float f4v __attribute__((ext_vector_type(4)));
typedef short s8v __attribute__((ext_vector_type(8)));

// manual RNE (prep only; identical rounding to HW cvt)
static __device__ __forceinline__ unsigned short f2bf(float f) {
    unsigned u = __float_as_uint(f);
    u += 0x7fffu + ((u >> 16) & 1u);
    return (unsigned short)(u >> 16);
}
// HW bf16 convert (clang lowers paired fptrunc to v_cvt_pk_bf16_f32, RNE)
static __device__ __forceinline__ unsigned short f2bf_hw(float f) {
    __bf16 b = (__bf16)f;
    unsigned short u;
    __builtin_memcpy(&u, &b, 2);
    return u;
}
static __device__ __forceinline__ float bf2f(unsigned short h) {
    return __uint_as_float(((unsigned)h) << 16);
}
static __device__ __forceinline__ unsigned pk2b(unsigned short lo, unsigned short hi) {
    return ((unsigned)hi << 16) | (unsigned)lo;
}
static __device__ __forceinline__ unsigned cpack(float lo, float hi) {
    return pk2b(f2bf_hw(lo), f2bf_hw(hi));
}
static __device__ __forceinline__ float sinrev(float x) {   // sin(2*pi*x)
    return __builtin_amdgcn_sinf(x);
}

union BFrag { uint4 q; unsigned u[4]; s8v s; };

// ---------------- prep: pack expert A-frags + scaled biases + gate hi/lo packs ----------------
__global__ __launch_bounds__(256) void prep_kernel(
    const float* __restrict__ we0, const float* __restrict__ be0,
    const float* __restrict__ wm, const float* __restrict__ bm,
    const float* __restrict__ gw1, const float* __restrict__ gw2,
    uint4* __restrict__ packA, float* __restrict__ biasS,
    uint4* __restrict__ packGW1H, uint4* __restrict__ packGW1L,
    uint4* __restrict__ packGW2H, uint4* __restrict__ packGW2L)
{
    const int idx = blockIdx.x * 256 + threadIdx.x;
    const float PI2I = 0.15915494309189535f;
    if (idx < 12288) {
        const int l = idx & 63;
        const int fr = (idx >> 6) & 7;
        const int grp = idx >> 9;            // e*3 + ell
        const int e = grp / 3, ell = grp % 3;
        const int tau = fr >> 1, ks = fr & 1;
        const int g = l >> 4, m = l & 15;
        const int row = tau * 16 + m;
        const float scale = (ell == 0) ? (22.5f + 45.0f * (float)e) * PI2I : 30.0f * PI2I;
        const float* W = (ell == 0) ? (we0 + e * 4096) : (wm + ((ell - 1) * 8 + e) * 4096);
        unsigned short v[8];
#pragma unroll
        for (int i = 0; i < 8; i++) {
            const int k = 32 * ks + 4 * g + (i < 4 ? i : i + 12);
            v[i] = f2bf(W[row * 64 + k] * scale);
        }
        uint4 q;
        q.x = pk2b(v[0], v[1]); q.y = pk2b(v[2], v[3]);
        q.z = pk2b(v[4], v[5]); q.w = pk2b(v[6], v[7]);
        packA[idx] = q;
    } else if (idx < 13824) {
        const int j = idx - 12288;           // e*192 + ell*64 + r
        const int r = j & 63;
        const int grp = j >> 6;
        const int e = grp / 3, ell = grp % 3;
        const float scale = (ell == 0) ? (22.5f + 45.0f * (float)e) * PI2I : 30.0f * PI2I;
        const float b = (ell == 0) ? be0[e * 64 + r] : bm[((ell - 1) * 8 + e) * 64 + r];
        biasS[j] = b * scale;
    } else if (idx < 14336) {
        // gate gw1 hi/lo A-frags: 8 frags (tau*2+ks) x 64 lanes
        const int j = idx - 13824;           // 0..511
        const int l = j & 63;
        const int fr = j >> 6;
        const int tau = fr >> 1, ks = fr & 1;
        const int g = l >> 4;
        const int row = tau * 16 + (l & 15);
        unsigned short vh[8], vl[8];
#pragma unroll
        for (int i = 0; i < 8; i++) {
            const int k = 32 * ks + 4 * g + (i < 4 ? i : i + 12);
            const float x = gw1[row * 64 + k];
            const unsigned short h = f2bf(x);
            vh[i] = h;
            vl[i] = f2bf(x - bf2f(h));
        }
        uint4 qh, ql;
        qh.x = pk2b(vh[0], vh[1]); qh.y = pk2b(vh[2], vh[3]);
        qh.z = pk2b(vh[4], vh[5]); qh.w = pk2b(vh[6], vh[7]);
        ql.x = pk2b(vl[0], vl[1]); ql.y = pk2b(vl[2], vl[3]);
        ql.z = pk2b(vl[4], vl[5]); ql.w = pk2b(vl[6], vl[7]);
        packGW1H[j] = qh; packGW1L[j] = ql;
    } else if (idx < 14464) {
        // gate gw2 hi/lo A-frags: rows 0..7 = gw2, rows 8..15 = 0; 2 frags (ks) x 64 lanes
        const int j = idx - 14336;           // 0..127
        const int l = j & 63;
        const int ks = j >> 6;
        const int g = l >> 4;
        const int row = l & 15;
        unsigned short vh[8], vl[8];
#pragma unroll
        for (int i = 0; i < 8; i++) {
            const int k = 32 * ks + 4 * g + (i < 4 ? i : i + 12);
            const float x = (row < 8) ? gw2[row * 64 + k] : 0.f;
            const unsigned short h = f2bf(x);
            vh[i] = h;
            vl[i] = f2bf(x - bf2f(h));
        }
        uint4 qh, ql;
        qh.x = pk2b(vh[0], vh[1]); qh.y = pk2b(vh[2], vh[3]);
        qh.z = pk2b(vh[4], vh[5]); qh.w = pk2b(vh[6], vh[7]);
        ql.x = pk2b(vl[0], vl[1]); ql.y = pk2b(vl[2], vl[3]);
        ql.z = pk2b(vl[4], vl[5]); ql.w = pk2b(vl[6], vl[7]);
        packGW2H[j] = qh; packGW2L[j] = ql;
    }
}

// ---------------- K1: gate via MFMA (hi/lo split) + margin flag for separate refine ----------------
// 512 threads = 8 waves x 16 points = 128 points per block.
__global__ __launch_bounds__(512) void gate_kernel(
    const float* __restrict__ coords,
    const float* __restrict__ fw, const float* __restrict__ fb,
    const float* __restrict__ gb1, const float* __restrict__ lng,
    const float* __restrict__ lnb, const float* __restrict__ gb2,
    const uint4* __restrict__ packGW1H, const uint4* __restrict__ packGW1L,
    const uint4* __restrict__ packGW2H, const uint4* __restrict__ packGW2L,
    unsigned char* __restrict__ sel, int* __restrict__ blkcnt,
    int* __restrict__ reflist, int* __restrict__ refcnt)
{
    __shared__ float s_fw[192], s_fb[64], s_gb1[64], s_lng[64], s_lnb[64], s_gb2[8];
    __shared__ int s_cnt[8];
    const int t = threadIdx.x;
    if (t < 192) s_fw[t] = fw[t];
    if (t < 64) { s_fb[t] = fb[t]; s_gb1[t] = gb1[t]; s_lng[t] = lng[t]; s_lnb[t] = lnb[t]; }
    if (t < 8) { s_gb2[t] = gb2[t]; s_cnt[t] = 0; }
    __syncthreads();

    const int lane = t & 63;
    const int wv = t >> 6;
    const int g = lane >> 4, c = lane & 15;
    const int n = blockIdx.x * 128 + wv * 16 + c;

    // ---- features: this lane's 16 k-values of point n (fp32, exact order) ----
    const float c0 = coords[n * 3], c1 = coords[n * 3 + 1], c2 = coords[n * 3 + 2];
    float fv[16];
#pragma unroll
    for (int s = 0; s < 4; s++) {
#pragma unroll
        for (int j = 0; j < 4; j++) {
            const int k = 16 * s + 4 * g + j;
            fv[s * 4 + j] = s_fb[k] + c0 * s_fw[k * 3] + c1 * s_fw[k * 3 + 1] + c2 * s_fw[k * 3 + 2];
        }
    }
    unsigned short fh[16]; float fl[16];
#pragma unroll
    for (int i = 0; i < 16; i++) {
        fh[i] = f2bf_hw(fv[i]);
        fl[i] = fv[i] - bf2f(fh[i]);
    }
    BFrag Bh[2], Bl[2];
#pragma unroll
    for (int ks = 0; ks < 2; ks++) {
#pragma unroll
        for (int q = 0; q < 4; q++) {
            Bh[ks].u[q] = pk2b(fh[ks * 8 + 2 * q], fh[ks * 8 + 2 * q + 1]);
            Bl[ks].u[q] = cpack(fl[ks * 8 + 2 * q], fl[ks * 8 + 2 * q + 1]);
        }
    }

    // ---- g = gw1 @ f + gb1 via 3-term MFMA ----
    f4v acc[4];
#pragma unroll
    for (int tau = 0; tau < 4; tau++) {
        const float4 b = *(const float4*)&s_gb1[tau * 16 + 4 * g];
        acc[tau][0] = b.x; acc[tau][1] = b.y; acc[tau][2] = b.z; acc[tau][3] = b.w;
    }
#pragma unroll
    for (int tau = 0; tau < 4; tau++) {
        BFrag AH0, AH1, AL0, AL1;
        AH0.q = packGW1H[(tau * 2 + 0) * 64 + lane];
        AH1.q = packGW1H[(tau * 2 + 1) * 64 + lane];
        AL0.q = packGW1L[(tau * 2 + 0) * 64 + lane];
        AL1.q = packGW1L[(tau * 2 + 1) * 64 + lane];
        acc[tau] = __builtin_amdgcn_mfma_f32_16x16x32_bf16(AH0.s, Bh[0].s, acc[tau], 0, 0, 0);
        acc[tau] = __builtin_amdgcn_mfma_f32_16x16x32_bf16(AH1.s, Bh[1].s, acc[tau], 0, 0, 0);
        acc[tau] = __builtin_amdgcn_mfma_f32_16x16x32_bf16(AH0.s, Bl[0].s, acc[tau], 0, 0, 0);
        acc[tau] = __builtin_amdgcn_mfma_f32_16x16x32_bf16(AH1.s, Bl[1].s, acc[tau], 0, 0, 0);
        acc[tau] = __builtin_amdgcn_mfma_f32_16x16x32_bf16(AL0.s, Bh[0].s, acc[tau], 0, 0, 0);
        acc[tau] = __builtin_amdgcn_mfma_f32_16x16x32_bf16(AL1.s, Bh[1].s, acc[tau], 0, 0, 0);
    }

    // ---- LayerNorm over the 64 rows (cross-lane over g groups) ----
    float s1 = 0.f;
#pragma unroll
    for (int tau = 0; tau < 4; tau++)
#pragma unroll
        for (int j = 0; j < 4; j++) s1 += acc[tau][j];
    s1 += __shfl_xor(s1, 16, 64); s1 += __shfl_xor(s1, 32, 64);
    const float mu = s1 * (1.f / 64.f);
    float s2 = 0.f;
#pragma unroll
    for (int tau = 0; tau < 4; tau++)
#pragma unroll
        for (int j = 0; j < 4; j++) { const float d = acc[tau][j] - mu; s2 += d * d; }
    s2 += __shfl_xor(s2, 16, 64); s2 += __shfl_xor(s2, 32, 64);
    const float rs = rsqrtf(s2 * (1.f / 64.f) + 1e-5f);

    float gn[16];
#pragma unroll
    for (int tau = 0; tau < 4; tau++) {
        const float4 lg = *(const float4*)&s_lng[tau * 16 + 4 * g];
        const float4 lb = *(const float4*)&s_lnb[tau * 16 + 4 * g];
        gn[tau * 4 + 0] = (acc[tau][0] - mu) * rs * lg.x + lb.x;
        gn[tau * 4 + 1] = (acc[tau][1] - mu) * rs * lg.y + lb.y;
        gn[tau * 4 + 2] = (acc[tau][2] - mu) * rs * lg.z + lb.z;
        gn[tau * 4 + 3] = (acc[tau][3] - mu) * rs * lg.w + lb.w;
    }
    unsigned short gh[16]; float gl[16];
#pragma unroll
    for (int i = 0; i < 16; i++) { gh[i] = f2bf_hw(gn[i]); gl[i] = gn[i] - bf2f(gh[i]); }
    BFrag Gh[2], Gl[2];
#pragma unroll
    for (int ks = 0; ks < 2; ks++) {
        Gh[ks].u[0] = pk2b(gh[(2 * ks) * 4 + 0], gh[(2 * ks) * 4 + 1]);
        Gh[ks].u[1] = pk2b(gh[(2 * ks) * 4 + 2], gh[(2 * ks) * 4 + 3]);
        Gh[ks].u[2] = pk2b(gh[(2 * ks + 1) * 4 + 0], gh[(2 * ks + 1) * 4 + 1]);
        Gh[ks].u[3] = pk2b(gh[(2 * ks + 1) * 4 + 2], gh[(2 * ks + 1) * 4 + 3]);
        Gl[ks].u[0] = cpack(gl[(2 * ks) * 4 + 0], gl[(2 * ks) * 4 + 1]);
        Gl[ks].u[1] = cpack(gl[(2 * ks) * 4 + 2], gl[(2 * ks) * 4 + 3]);
        Gl[ks].u[2] = cpack(gl[(2 * ks + 1) * 4 + 0], gl[(2 * ks + 1) * 4 + 1]);
        Gl[ks].u[3] = cpack(gl[(2 * ks + 1) * 4 + 2], gl[(2 * ks + 1) * 4 + 3]);
    }

    // ---- logits = gw2 @ gn via 3-term MFMA (rows 0..7 valid) ----
    f4v lacc = {0.f, 0.f, 0.f, 0.f};
    BFrag W0, W1, V0, V1;
    W0.q = packGW2H[0 * 64 + lane]; W1.q = packGW2H[1 * 64 + lane];
    V0.q = packGW2L[0 * 64 + lane]; V1.q = packGW2L[1 * 64 + lane];
    lacc = __builtin_amdgcn_mfma_f32_16x16x32_bf16(W0.s, Gh[0].s, lacc, 0, 0, 0);
    lacc = __builtin_amdgcn_mfma_f32_16x16x32_bf16(W1.s, Gh[1].s, lacc, 0, 0, 0);
    lacc = __builtin_amdgcn_mfma_f32_16x16x32_bf16(W0.s, Gl[0].s, lacc, 0, 0, 0);
    lacc = __builtin_amdgcn_mfma_f32_16x16x32_bf16(W1.s, Gl[1].s, lacc, 0, 0, 0);
    lacc = __builtin_amdgcn_mfma_f32_16x16x32_bf16(V0.s, Gh[0].s, lacc, 0, 0, 0);
    lacc = __builtin_amdgcn_mfma_f32_16x16x32_bf16(V1.s, Gh[1].s, lacc, 0, 0, 0);

    float other[4];
#pragma unroll
    for (int j = 0; j < 4; j++) other[j] = __shfl_xor(lacc[j], 16, 64);
    float logit[8];
#pragma unroll
    for (int j = 0; j < 4; j++) {
        logit[j] = lacc[j] + s_gb2[j];
        logit[4 + j] = other[j] + s_gb2[4 + j];
    }

    // ---- top-2 (>= 2nd-largest semantics) + margin flag ----
    float m1 = logit[0]; int i1 = 0;
#pragma unroll
    for (int e = 1; e < 8; e++) if (logit[e] > m1) { m1 = logit[e]; i1 = e; }
    float m2 = -INFINITY; int i2 = -1;
#pragma unroll
    for (int e = 0; e < 8; e++) if (e != i1 && logit[e] > m2) { m2 = logit[e]; i2 = e; }
    float m3 = -INFINITY;
#pragma unroll
    for (int e = 0; e < 8; e++) if (e != i1 && e != i2 && logit[e] > m3) m3 = logit[e];
    unsigned mbits = 0;
#pragma unroll
    for (int e = 0; e < 8; e++) if (logit[e] >= m2) mbits |= 1u << e;

    const bool active = (g == 0);
    if (active) sel[n] = (unsigned char)mbits;
    const bool flg = active && (m2 - m3 < TAU);

#pragma unroll
    for (int e = 0; e < 8; e++) {
        const unsigned long long bal = __ballot(active && ((mbits >> e) & 1u));
        if (lane == 0) atomicAdd(&s_cnt[e], (int)__popcll(bal));
    }
    {
        const unsigned long long bal = __ballot(flg);
        int pos0 = 0;
        if (lane == 0 && bal) pos0 = atomicAdd(refcnt, (int)__popcll(bal));
        pos0 = __shfl(pos0, 0, 64);
        if (flg) {
            const int rank = (int)__popcll(bal & ((1ull << lane) - 1ull));
            reflist[pos0 + rank] = n;
        }
    }
    __syncthreads();
    if (t < 8) blkcnt[blockIdx.x * 8 + t] = s_cnt[t];
}

// ---------------- K1.25: exact-fp32 refine, ONE WAVE PER POINT (no scratch arrays) ----------------
__global__ __launch_bounds__(256) void refine_kernel(
    const float* __restrict__ coords,
    const float* __restrict__ fw, const float* __restrict__ fb,
    const float* __restrict__ gw1, const float* __restrict__ gb1,
    const float* __restrict__ lng, const float* __restrict__ lnb,
    const float* __restrict__ gw2, const float* __restrict__ gb2,
    const int* __restrict__ reflist, const int* __restrict__ refcnt,
    unsigned char* __restrict__ sel, int* __restrict__ blkcnt)
{
    const int R = *refcnt;
    if (blockIdx.x * 4 >= R) return;            // uniform early exit, before any barrier

    __shared__ float s_gw1t[64 * 65];           // transposed + pad: [k][r] at k*65+r
    __shared__ float s_gw2[512];
    __shared__ float s_fw[192], s_fb[64], s_gb1[64], s_lng[64], s_lnb[64], s_gb2[8];
    __shared__ float s_f[4][64];                // per-wave feature buffer

    const int t = threadIdx.x;
    for (int i = t; i < 4096; i += 256) s_gw1t[(i & 63) * 65 + (i >> 6)] = gw1[i];
    for (int i = t; i < 512; i += 256) s_gw2[i] = gw2[i];
    if (t < 192) s_fw[t] = fw[t];
    if (t < 64) { s_fb[t] = fb[t]; s_gb1[t] = gb1[t]; s_lng[t] = lng[t]; s_lnb[t] = lnb[t]; }
    if (t < 8) s_gb2[t] = gb2[t];
    __syncthreads();

    const int wv = t >> 6, lane = t & 63;
    for (int idx = blockIdx.x * 4 + wv; idx < R; idx += gridDim.x * 4) {
        const int n = reflist[idx];
        const float c0 = coords[n * 3], c1 = coords[n * 3 + 1], c2 = coords[n * 3 + 2];
        const float fr = s_fb[lane] + c0 * s_fw[lane * 3] + c1 * s_fw[lane * 3 + 1]
                       + c2 * s_fw[lane * 3 + 2];
        s_f[wv][lane] = fr;
        float a = s_gb1[lane];
#pragma unroll
        for (int k = 0; k < 64; k++)
            a += s_f[wv][k] * s_gw1t[k * 65 + lane];
        float mu = a;
#pragma unroll
        for (int d = 1; d < 64; d <<= 1) mu += __shfl_xor(mu, d, 64);
        mu *= (1.f / 64.f);
        const float dv = a - mu;
        float v = dv * dv;
#pragma unroll
        for (int d = 1; d < 64; d <<= 1) v += __shfl_xor(v, d, 64);
        const float rs = rsqrtf(v * (1.f / 64.f) + 1e-5f);
        const float gn = dv * rs * s_lng[lane] + s_lnb[lane];
        float lp[8];
#pragma unroll
        for (int e = 0; e < 8; e++) lp[e] = gn * s_gw2[e * 64 + lane];
#pragma unroll
        for (int e = 0; e < 8; e++) {
#pragma unroll
            for (int d = 1; d < 64; d <<= 1) lp[e] += __shfl_xor(lp[e], d, 64);
            lp[e] += s_gb2[e];
        }
        if (lane == 0) {
            float m1 = lp[0]; int i1 = 0;
#pragma unroll
            for (int e = 1; e < 8; e++) if (lp[e] > m1) { m1 = lp[e]; i1 = e; }
            float m2 = -INFINITY;
#pragma unroll
            for (int e = 0; e < 8; e++) if (e != i1 && lp[e] > m2) m2 = lp[e];
            unsigned mbits = 0;
#pragma unroll
            for (int e = 0; e < 8; e++) if (lp[e] >= m2) mbits |= 1u << e;
            const unsigned old = sel[n];
            if (mbits != old) {
                sel[n] = (unsigned char)mbits;
                const int b = n >> 7;
#pragma unroll
                for (int e = 0; e < 8; e++) {
                    const int was = (old >> e) & 1, now = (mbits >> e) & 1;
                    if (was != now) atomicAdd(&blkcnt[b * 8 + e], now - was);
                }
            }
        }
    }
}

// ---------------- K1.5: single-block scan -> baseoff, counts, aux ----------------
__global__ __launch_bounds__(256) void scan_kernel(
    const int* __restrict__ blkcnt, int* __restrict__ baseoff,
    int* __restrict__ counts, float* __restrict__ out)
{
    __shared__ int s_tot[8];
    const int t = threadIdx.x;
    const int e = t >> 5;        // 8 experts x 32 lanes
    const int q = t & 31;
    const int b0 = q * (GBLK / 32);
    int partial = 0;
    for (int b = b0; b < b0 + GBLK / 32; b++) partial += blkcnt[b * 8 + e];
    int incl = partial;
#pragma unroll
    for (int d = 1; d < 32; d <<= 1) {
        const int v = __shfl_up(incl, d, 32);
        if (q >= d) incl += v;
    }
    const int excl = incl - partial;
    const int total = __shfl(incl, 31, 32);
    if (q == 0) { counts[e] = total; s_tot[e] = total; }
    int run = excl;
    for (int b = b0; b < b0 + GBLK / 32; b++) {
        baseoff[b * 8 + e] = run;
        run += blkcnt[b * 8 + e];
    }
    __syncthreads();
    if (t == 0) {
        double s = 0.0;
        for (int i = 0; i < 8; i++) { const double c = (double)s_tot[i]; s += c * c; }
        out[NPTS] = (float)(8.0 * s / ((double)NPTS * (double)NPTS));
    }
}

// ---------------- K2: scatter points into buckets (no atomics) + zero out[] ----------------
__global__ __launch_bounds__(128) void scatter_kernel(
    const unsigned char* __restrict__ sel, const int* __restrict__ baseoff,
    int* __restrict__ buckets, float* __restrict__ out)
{
    __shared__ int s_w0[8];
    const int t = threadIdx.x;
    const int n = blockIdx.x * 128 + t;
    out[n] = 0.f;                        // replaces hipMemsetAsync(d_out)
    const unsigned m = sel[n];
    const int w = t >> 6, lane = t & 63;
    unsigned long long bal[8];
#pragma unroll
    for (int e = 0; e < 8; e++) {
        bal[e] = __ballot((m >> e) & 1u);
        if (w == 0 && lane == 0) s_w0[e] = (int)__popcll(bal[e]);
    }
    __syncthreads();
#pragma unroll
    for (int e = 0; e < 8; e++) {
        if ((m >> e) & 1u) {
            int rank = (int)__popcll(bal[e] & ((1ull << lane) - 1ull));
            if (w == 1) rank += s_w0[e];
            buckets[e * NPTS + baseoff[blockIdx.x * 8 + e] + rank] = n;
        }
    }
}

// ---------------- K3: per-expert MFMA SIREN; direct per-lane fragment build (no s_ft) ----------------
__global__ __launch_bounds__(256) void expert_kernel(
    const float* __restrict__ coords,
    const float* __restrict__ fw, const float* __restrict__ fb,
    const float* __restrict__ wl, const float* __restrict__ bl,
    const uint4* __restrict__ packA, const float* __restrict__ biasS,
    const int* __restrict__ counts, const int* __restrict__ buckets,
    float* __restrict__ out)
{
    const int e = blockIdx.x >> 11;            // CPE == 2048
    const int chunk = blockIdx.x & (CPE - 1);
    const int cnt = counts[e];
    const int base = chunk * 128;
    if (base >= cnt) return;

    __shared__ float s_b[192];
    __shared__ float s_wl[64];
    __shared__ float s_fw[192];
    __shared__ float s_fb[64];
    __shared__ float s_bl;

    const int t = threadIdx.x;
    if (t < 192) {
        s_b[t] = biasS[e * 192 + t];
        s_fw[t] = fw[t];
    }
    if (t < 64) {
        s_fb[t] = fb[t];
        s_wl[t] = wl[e * 64 + t];
    }
    if (t == 0) s_bl = bl[e];
    __syncthreads();

    const int lane = t & 63;
    const int wv = t >> 6;
    const int g = lane >> 4, c = lane & 15;
    const int i0 = base + wv * 32 + c;
    const int i1 = i0 + 16;
    const int id0 = (i0 < cnt) ? buckets[e * NPTS + i0] : -1;
    const int id1 = (i1 < cnt) ? buckets[e * NPTS + i1] : -1;

    // ---- direct per-lane B-fragment features: lane needs k = 16s + 4g + j (s=0..3, j=0..3) ----
    BFrag B0[2], B1[2];
    {
        const float a0 = (id0 >= 0) ? coords[id0 * 3] : 0.f;
        const float a1 = (id0 >= 0) ? coords[id0 * 3 + 1] : 0.f;
        const float a2 = (id0 >= 0) ? coords[id0 * 3 + 2] : 0.f;
        const float b0 = (id1 >= 0) ? coords[id1 * 3] : 0.f;
        const float b1 = (id1 >= 0) ? coords[id1 * 3 + 1] : 0.f;
        const float b2 = (id1 >= 0) ? coords[id1 * 3 + 2] : 0.f;
        float f0[4][4], f1[4][4];
#pragma unroll
        for (int s = 0; s < 4; s++) {
#pragma unroll
            for (int j = 0; j < 4; j++) {
                const int k = 16 * s + 4 * g + j;
                const float wx = s_fw[k * 3], wy = s_fw[k * 3 + 1], wz = s_fw[k * 3 + 2];
                const float bb = s_fb[k];
                f0[s][j] = bb + a0 * wx + a1 * wy + a2 * wz;
                f1[s][j] = bb + b0 * wx + b1 * wy + b2 * wz;
            }
        }
#pragma unroll
        for (int ks = 0; ks < 2; ks++) {
            B0[ks].u[0] = cpack(f0[2 * ks][0], f0[2 * ks][1]);
            B0[ks].u[1] = cpack(f0[2 * ks][2], f0[2 * ks][3]);
            B0[ks].u[2] = cpack(f0[2 * ks + 1][0], f0[2 * ks + 1][1]);
            B0[ks].u[3] = cpack(f0[2 * ks + 1][2], f0[2 * ks + 1][3]);
            B1[ks].u[0] = cpack(f1[2 * ks][0], f1[2 * ks][1]);
            B1[ks].u[1] = cpack(f1[2 * ks][2], f1[2 * ks][3]);
            B1[ks].u[2] = cpack(f1[2 * ks + 1][0], f1[2 * ks + 1][1]);
            B1[ks].u[3] = cpack(f1[2 * ks + 1][2], f1[2 * ks + 1][3]);
        }
    }

#pragma unroll 1
    for (int ell = 0; ell < 2; ell++) {
        f4v acc0[4], acc1[4];
#pragma unroll
        for (int tau = 0; tau < 4; tau++) {
            const float4 b = *(const float4*)&s_b[ell * 64 + tau * 16 + 4 * g];
            acc0[tau][0] = b.x; acc0[tau][1] = b.y; acc0[tau][2] = b.z; acc0[tau][3] = b.w;
            acc1[tau][0] = b.x; acc1[tau][1] = b.y; acc1[tau][2] = b.z; acc1[tau][3] = b.w;
        }
        const uint4* Ab = packA + (size_t)((e * 3 + ell) * 8) * 64 + lane;
#pragma unroll
        for (int tau = 0; tau < 4; tau++) {
            BFrag A0, A1;
            A0.q = Ab[(tau * 2 + 0) * 64];
            A1.q = Ab[(tau * 2 + 1) * 64];
            acc0[tau] = __builtin_amdgcn_mfma_f32_16x16x32_bf16(A0.s, B0[0].s, acc0[tau], 0, 0, 0);
            acc0[tau] = __builtin_amdgcn_mfma_f32_16x16x32_bf16(A1.s, B0[1].s, acc0[tau], 0, 0, 0);
            acc1[tau] = __builtin_amdgcn_mfma_f32_16x16x32_bf16(A0.s, B1[0].s, acc1[tau], 0, 0, 0);
            acc1[tau] = __builtin_amdgcn_mfma_f32_16x16x32_bf16(A1.s, B1[1].s, acc1[tau], 0, 0, 0);
        }
        // sin + repack: D registers become next layer's B fragments
#pragma unroll
        for (int ks = 0; ks < 2; ks++) {
            B0[ks].u[0] = cpack(sinrev(acc0[2 * ks][0]), sinrev(acc0[2 * ks][1]));
            B0[ks].u[1] = cpack(sinrev(acc0[2 * ks][2]), sinrev(acc0[2 * ks][3]));
            B0[ks].u[2] = cpack(sinrev(acc0[2 * ks + 1][0]), sinrev(acc0[2 * ks + 1][1]));
            B0[ks].u[3] = cpack(sinrev(acc0[2 * ks + 1][2]), sinrev(acc0[2 * ks + 1][3]));
            B1[ks].u[0] = cpack(sinrev(acc1[2 * ks][0]), sinrev(acc1[2 * ks][1]));
            B1[ks].u[1] = cpack(sinrev(acc1[2 * ks][2]), sinrev(acc1[2 * ks][3]));
            B1[ks].u[2] = cpack(sinrev(acc1[2 * ks + 1][0]), sinrev(acc1[2 * ks + 1][1]));
            B1[ks].u[3] = cpack(sinrev(acc1[2 * ks + 1][2]), sinrev(acc1[2 * ks + 1][3]));
        }
    }

    // ---- layer 2 + final dot ----
    {
        f4v acc0[4], acc1[4];
#pragma unroll
        for (int tau = 0; tau < 4; tau++) {
            const float4 b = *(const float4*)&s_b[2 * 64 + tau * 16 + 4 * g];
            acc0[tau][0] = b.x; acc0[tau][1] = b.y; acc0[tau][2] = b.z; acc0[tau][3] = b.w;
            acc1[tau][0] = b.x; acc1[tau][1] = b.y; acc1[tau][2] = b.z; acc1[tau][3] = b.w;
        }
        const uint4* Ab = packA + (size_t)((e * 3 + 2) * 8) * 64 + lane;
#pragma unroll
        for (int tau = 0; tau < 4; tau++) {
            BFrag A0, A1;
            A0.q = Ab[(tau * 2 + 0) * 64];
            A1.q = Ab[(tau * 2 + 1) * 64];
            acc0[tau] = __builtin_amdgcn_mfma_f32_16x16x32_bf16(A0.s, B0[0].s, acc0[tau], 0, 0, 0);
            acc0[tau] = __builtin_amdgcn_mfma_f32_16x16x32_bf16(A1.s, B0[1].s, acc0[tau], 0, 0, 0);
            acc1[tau] = __builtin_amdgcn_mfma_f32_16x16x32_bf16(A0.s, B1[0].s, acc1[tau], 0, 0, 0);
            acc1[tau] = __builtin_amdgcn_mfma_f32_16x16x32_bf16(A1.s, B1[1].s, acc1[tau], 0, 0, 0);
        }
        float px0 = 0.f, px1 = 0.f;
#pragma unroll
        for (int tau = 0; tau < 4; tau++) {
            const float4 w = *(const float4*)&s_wl[tau * 16 + 4 * g];
            px0 += sinrev(acc0[tau][0]) * w.x + sinrev(acc0[tau][1]) * w.y
                 + sinrev(acc0[tau][2]) * w.z + sinrev(acc0[tau][3]) * w.w;
            px1 += sinrev(acc1[tau][0]) * w.x + sinrev(acc1[tau][1]) * w.y
                 + sinrev(acc1[tau][2]) * w.z + sinrev(acc1[tau][3]) * w.w;
        }
        px0 += __shfl_xor(px0, 16, 64); px0 += __shfl_xor(px0, 32, 64);
        px1 += __shfl_xor(px1, 16, 64); px1 += __shfl_xor(px1, 32, 64);
        if (g == 0) {
            if (id0 >= 0) atomicAdd(&out[id0], px0 + s_bl);
            if (id1 >= 0) atomicAdd(&out[id1], px1 + s_bl);
        }
    }
}

extern "C" void kernel_launch(void* const* d_in, const int* in_sizes, int n_in,
                              void* d_out, int out_size, void* d_ws, size_t ws_size,
                              hipStream_t stream)
{
    const float* coords = (const float*)d_in[0];
    const float* fw  = (const float*)d_in[1];
    const float* fb  = (const float*)d_in[2];
    const float* gw1 = (const float*)d_in[3];
    const float* gb1 = (const float*)d_in[4];
    const float* lng = (const float*)d_in[5];
    const float* lnb = (const float*)d_in[6];
    const float* gw2 = (const float*)d_in[7];
    const float* gb2 = (const float*)d_in[8];
    const float* we0 = (const float*)d_in[9];
    const float* be0 = (const float*)d_in[10];
    const float* wm  = (const float*)d_in[11];
    const float* bm  = (const float*)d_in[12];
    const float* wl  = (const float*)d_in[13];
    const float* bl  = (const float*)d_in[14];
    float* out = (float*)d_out;

    char* ws = (char*)d_ws;
    int* counts           = (int*)ws;                        // 64
    int* buckets          = (int*)(ws + 64);                 // 8*NPTS*4 = 8388608
    uint4* packA          = (uint4*)(ws + 8388672);          // 196608
    float* biasS          = (float*)(ws + 8585280);          // 6144
    int* blkcnt           = (int*)(ws + 8591424);            // 65536
    int* baseoff          = (int*)(ws + 8656960);            // 65536
    unsigned char* sel    = (unsigned char*)(ws + 8722496);  // 262144
    uint4* packGW1H       = (uint4*)(ws + 8984640);          // 8192
    uint4* packGW1L       = (uint4*)(ws + 8992832);          // 8192
    uint4* packGW2H       = (uint4*)(ws + 9001024);          // 2048
    uint4* packGW2L       = (uint4*)(ws + 9003072);          // 2048
    int* reflist          = (int*)(ws + 9005120);            // 1048576
    int* refcnt           = (int*)(ws + 10053696);           // 64

    hipMemsetAsync(refcnt, 0, 64, stream);

    prep_kernel<<<57, 256, 0, stream>>>(we0, be0, wm, bm, gw1, gw2, packA, biasS,
                                        packGW1H, packGW1L, packGW2H, packGW2L);
    gate_kernel<<<GBLK, 512, 0, stream>>>(coords, fw, fb, gb1, lng, lnb, gb2,
                                          packGW1H, packGW1L, packGW2H, packGW2L,
                                          sel, blkcnt, reflist, refcnt);
    refine_kernel<<<128, 256, 0, stream>>>(coords, fw, fb, gw1, gb1, lng, lnb, gw2, gb2,
                                           reflist, refcnt, sel, blkcnt);
    scan_kernel<<<1, 256, 0, stream>>>(blkcnt, baseoff, counts, out);
    scatter_kernel<<<GBLK, 128, 0, stream>>>(sel, baseoff, buckets, out);
    expert_kernel<<<8 * CPE, 256, 0, stream>>>(coords, fw, fb, wl, bl, packA, biasS,
                                               counts, buckets, out);
}

// Round 11
// 107.448 us; speedup vs baseline: 1.9940x; 1.1614x over previous
//
#include <hip/hip_runtime.h>
#include <math.h>

#define NPTS 262144
#define GBLK (NPTS / 128)     // 2048 gate blocks (128 points each)
#define CPE  2048             // chunks per expert in expert grid
#define TAU  0.01f            // refine margin threshold (logit units)

typedef float f4v __attribute__((ext_vector_type(4)));
typedef short s8v __attribute__((ext_vector_type(8)));

// manual RNE (prep only; identical rounding to HW cvt)
static __device__ __forceinline__ unsigned short f2bf(float f) {
    unsigned u = __float_as_uint(f);
    u += 0x7fffu + ((u >> 16) & 1u);
    return (unsigned short)(u >> 16);
}
// HW bf16 convert (clang lowers paired fptrunc to v_cvt_pk_bf16_f32, RNE)
static __device__ __forceinline__ unsigned short f2bf_hw(float f) {
    __bf16 b = (__bf16)f;
    unsigned short u;
    __builtin_memcpy(&u, &b, 2);
    return u;
}
static __device__ __forceinline__ float bf2f(unsigned short h) {
    return __uint_as_float(((unsigned)h) << 16);
}
static __device__ __forceinline__ unsigned pk2b(unsigned short lo, unsigned short hi) {
    return ((unsigned)hi << 16) | (unsigned)lo;
}
static __device__ __forceinline__ unsigned cpack(float lo, float hi) {
    return pk2b(f2bf_hw(lo), f2bf_hw(hi));
}
static __device__ __forceinline__ float sinrev(float x) {   // sin(2*pi*x)
    return __builtin_amdgcn_sinf(x);
}

union BFrag { uint4 q; unsigned u[4]; s8v s; };

// ---------------- prep: pack expert A-frags + scaled biases + gate hi/lo packs ----------------
__global__ __launch_bounds__(256) void prep_kernel(
    const float* __restrict__ we0, const float* __restrict__ be0,
    const float* __restrict__ wm, const float* __restrict__ bm,
    const float* __restrict__ gw1, const float* __restrict__ gw2,
    uint4* __restrict__ packA, float* __restrict__ biasS,
    uint4* __restrict__ packGW1H, uint4* __restrict__ packGW1L,
    uint4* __restrict__ packGW2H, uint4* __restrict__ packGW2L)
{
    const int idx = blockIdx.x * 256 + threadIdx.x;
    const float PI2I = 0.15915494309189535f;
    if (idx < 12288) {
        const int l = idx & 63;
        const int fr = (idx >> 6) & 7;
        const int grp = idx >> 9;            // e*3 + ell
        const int e = grp / 3, ell = grp % 3;
        const int tau = fr >> 1, ks = fr & 1;
        const int g = l >> 4, m = l & 15;
        const int row = tau * 16 + m;
        const float scale = (ell == 0) ? (22.5f + 45.0f * (float)e) * PI2I : 30.0f * PI2I;
        const float* W = (ell == 0) ? (we0 + e * 4096) : (wm + ((ell - 1) * 8 + e) * 4096);
        unsigned short v[8];
#pragma unroll
        for (int i = 0; i < 8; i++) {
            const int k = 32 * ks + 4 * g + (i < 4 ? i : i + 12);
            v[i] = f2bf(W[row * 64 + k] * scale);
        }
        uint4 q;
        q.x = pk2b(v[0], v[1]); q.y = pk2b(v[2], v[3]);
        q.z = pk2b(v[4], v[5]); q.w = pk2b(v[6], v[7]);
        packA[idx] = q;
    } else if (idx < 13824) {
        const int j = idx - 12288;           // e*192 + ell*64 + r
        const int r = j & 63;
        const int grp = j >> 6;
        const int e = grp / 3, ell = grp % 3;
        const float scale = (ell == 0) ? (22.5f + 45.0f * (float)e) * PI2I : 30.0f * PI2I;
        const float b = (ell == 0) ? be0[e * 64 + r] : bm[((ell - 1) * 8 + e) * 64 + r];
        biasS[j] = b * scale;
    } else if (idx < 14336) {
        // gate gw1 hi/lo A-frags: 8 frags (tau*2+ks) x 64 lanes
        const int j = idx - 13824;           // 0..511
        const int l = j & 63;
        const int fr = j >> 6;
        const int tau = fr >> 1, ks = fr & 1;
        const int g = l >> 4;
        const int row = tau * 16 + (l & 15);
        unsigned short vh[8], vl[8];
#pragma unroll
        for (int i = 0; i < 8; i++) {
            const int k = 32 * ks + 4 * g + (i < 4 ? i : i + 12);
            const float x = gw1[row * 64 + k];
            const unsigned short h = f2bf(x);
            vh[i] = h;
            vl[i] = f2bf(x - bf2f(h));
        }
        uint4 qh, ql;
        qh.x = pk2b(vh[0], vh[1]); qh.y = pk2b(vh[2], vh[3]);
        qh.z = pk2b(vh[4], vh[5]); qh.w = pk2b(vh[6], vh[7]);
        ql.x = pk2b(vl[0], vl[1]); ql.y = pk2b(vl[2], vl[3]);
        ql.z = pk2b(vl[4], vl[5]); ql.w = pk2b(vl[6], vl[7]);
        packGW1H[j] = qh; packGW1L[j] = ql;
    } else if (idx < 14464) {
        // gate gw2 hi/lo A-frags: rows 0..7 = gw2, rows 8..15 = 0; 2 frags (ks) x 64 lanes
        const int j = idx - 14336;           // 0..127
        const int l = j & 63;
        const int ks = j >> 6;
        const int g = l >> 4;
        const int row = l & 15;
        unsigned short vh[8], vl[8];
#pragma unroll
        for (int i = 0; i < 8; i++) {
            const int k = 32 * ks + 4 * g + (i < 4 ? i : i + 12);
            const float x = (row < 8) ? gw2[row * 64 + k] : 0.f;
            const unsigned short h = f2bf(x);
            vh[i] = h;
            vl[i] = f2bf(x - bf2f(h));
        }
        uint4 qh, ql;
        qh.x = pk2b(vh[0], vh[1]); qh.y = pk2b(vh[2], vh[3]);
        qh.z = pk2b(vh[4], vh[5]); qh.w = pk2b(vh[6], vh[7]);
        ql.x = pk2b(vl[0], vl[1]); ql.y = pk2b(vl[2], vl[3]);
        ql.z = pk2b(vl[4], vl[5]); ql.w = pk2b(vl[6], vl[7]);
        packGW2H[j] = qh; packGW2L[j] = ql;
    }
}

// ---------------- K1: gate via MFMA (hi/lo split); gate packs staged in LDS ----------------
// 512 threads = 8 waves x 16 points = 128 points per block.
__global__ __launch_bounds__(512) void gate_kernel(
    const float* __restrict__ coords,
    const float* __restrict__ fw, const float* __restrict__ fb,
    const float* __restrict__ gb1, const float* __restrict__ lng,
    const float* __restrict__ lnb, const float* __restrict__ gb2,
    const uint4* __restrict__ packGW1H, const uint4* __restrict__ packGW1L,
    const uint4* __restrict__ packGW2H, const uint4* __restrict__ packGW2L,
    unsigned char* __restrict__ sel, int* __restrict__ blkcnt,
    int* __restrict__ reflist, int* __restrict__ refcnt)
{
    __shared__ float s_fw[192], s_fb[64], s_gb1[64], s_lng[64], s_lnb[64], s_gb2[8];
    __shared__ uint4 sW1H[512], sW1L[512];      // 8 frags x 64 lanes (16 KB)
    __shared__ uint4 sW2H[128], sW2L[128];      // 2 frags x 64 lanes (4 KB)
    __shared__ int s_cnt[8];
    const int t = threadIdx.x;
    sW1H[t] = packGW1H[t];
    sW1L[t] = packGW1L[t];
    if (t < 128) { sW2H[t] = packGW2H[t]; sW2L[t] = packGW2L[t]; }
    if (t < 192) s_fw[t] = fw[t];
    if (t < 64) { s_fb[t] = fb[t]; s_gb1[t] = gb1[t]; s_lng[t] = lng[t]; s_lnb[t] = lnb[t]; }
    if (t < 8) { s_gb2[t] = gb2[t]; s_cnt[t] = 0; }
    __syncthreads();

    const int lane = t & 63;
    const int wv = t >> 6;
    const int g = lane >> 4, c = lane & 15;
    const int n = blockIdx.x * 128 + wv * 16 + c;

    // ---- features: this lane's 16 k-values of point n (fp32, exact order) ----
    const float c0 = coords[n * 3], c1 = coords[n * 3 + 1], c2 = coords[n * 3 + 2];
    float fv[16];
#pragma unroll
    for (int s = 0; s < 4; s++) {
#pragma unroll
        for (int j = 0; j < 4; j++) {
            const int k = 16 * s + 4 * g + j;
            fv[s * 4 + j] = s_fb[k] + c0 * s_fw[k * 3] + c1 * s_fw[k * 3 + 1] + c2 * s_fw[k * 3 + 2];
        }
    }
    unsigned short fh[16]; float fl[16];
#pragma unroll
    for (int i = 0; i < 16; i++) {
        fh[i] = f2bf_hw(fv[i]);
        fl[i] = fv[i] - bf2f(fh[i]);
    }
    BFrag Bh[2], Bl[2];
#pragma unroll
    for (int ks = 0; ks < 2; ks++) {
#pragma unroll
        for (int q = 0; q < 4; q++) {
            Bh[ks].u[q] = pk2b(fh[ks * 8 + 2 * q], fh[ks * 8 + 2 * q + 1]);
            Bl[ks].u[q] = cpack(fl[ks * 8 + 2 * q], fl[ks * 8 + 2 * q + 1]);
        }
    }

    // ---- g = gw1 @ f + gb1 via 3-term MFMA (A-frags from LDS) ----
    f4v acc[4];
#pragma unroll
    for (int tau = 0; tau < 4; tau++) {
        const float4 b = *(const float4*)&s_gb1[tau * 16 + 4 * g];
        acc[tau][0] = b.x; acc[tau][1] = b.y; acc[tau][2] = b.z; acc[tau][3] = b.w;
    }
#pragma unroll
    for (int tau = 0; tau < 4; tau++) {
        BFrag AH0, AH1, AL0, AL1;
        AH0.q = sW1H[(tau * 2 + 0) * 64 + lane];
        AH1.q = sW1H[(tau * 2 + 1) * 64 + lane];
        AL0.q = sW1L[(tau * 2 + 0) * 64 + lane];
        AL1.q = sW1L[(tau * 2 + 1) * 64 + lane];
        acc[tau] = __builtin_amdgcn_mfma_f32_16x16x32_bf16(AH0.s, Bh[0].s, acc[tau], 0, 0, 0);
        acc[tau] = __builtin_amdgcn_mfma_f32_16x16x32_bf16(AH1.s, Bh[1].s, acc[tau], 0, 0, 0);
        acc[tau] = __builtin_amdgcn_mfma_f32_16x16x32_bf16(AH0.s, Bl[0].s, acc[tau], 0, 0, 0);
        acc[tau] = __builtin_amdgcn_mfma_f32_16x16x32_bf16(AH1.s, Bl[1].s, acc[tau], 0, 0, 0);
        acc[tau] = __builtin_amdgcn_mfma_f32_16x16x32_bf16(AL0.s, Bh[0].s, acc[tau], 0, 0, 0);
        acc[tau] = __builtin_amdgcn_mfma_f32_16x16x32_bf16(AL1.s, Bh[1].s, acc[tau], 0, 0, 0);
    }

    // ---- LayerNorm over the 64 rows (cross-lane over g groups) ----
    float s1 = 0.f;
#pragma unroll
    for (int tau = 0; tau < 4; tau++)
#pragma unroll
        for (int j = 0; j < 4; j++) s1 += acc[tau][j];
    s1 += __shfl_xor(s1, 16, 64); s1 += __shfl_xor(s1, 32, 64);
    const float mu = s1 * (1.f / 64.f);
    float s2 = 0.f;
#pragma unroll
    for (int tau = 0; tau < 4; tau++)
#pragma unroll
        for (int j = 0; j < 4; j++) { const float d = acc[tau][j] - mu; s2 += d * d; }
    s2 += __shfl_xor(s2, 16, 64); s2 += __shfl_xor(s2, 32, 64);
    const float rs = rsqrtf(s2 * (1.f / 64.f) + 1e-5f);

    float gn[16];
#pragma unroll
    for (int tau = 0; tau < 4; tau++) {
        const float4 lg = *(const float4*)&s_lng[tau * 16 + 4 * g];
        const float4 lb = *(const float4*)&s_lnb[tau * 16 + 4 * g];
        gn[tau * 4 + 0] = (acc[tau][0] - mu) * rs * lg.x + lb.x;
        gn[tau * 4 + 1] = (acc[tau][1] - mu) * rs * lg.y + lb.y;
        gn[tau * 4 + 2] = (acc[tau][2] - mu) * rs * lg.z + lb.z;
        gn[tau * 4 + 3] = (acc[tau][3] - mu) * rs * lg.w + lb.w;
    }
    unsigned short gh[16]; float gl[16];
#pragma unroll
    for (int i = 0; i < 16; i++) { gh[i] = f2bf_hw(gn[i]); gl[i] = gn[i] - bf2f(gh[i]); }
    BFrag Gh[2], Gl[2];
#pragma unroll
    for (int ks = 0; ks < 2; ks++) {
        Gh[ks].u[0] = pk2b(gh[(2 * ks) * 4 + 0], gh[(2 * ks) * 4 + 1]);
        Gh[ks].u[1] = pk2b(gh[(2 * ks) * 4 + 2], gh[(2 * ks) * 4 + 3]);
        Gh[ks].u[2] = pk2b(gh[(2 * ks + 1) * 4 + 0], gh[(2 * ks + 1) * 4 + 1]);
        Gh[ks].u[3] = pk2b(gh[(2 * ks + 1) * 4 + 2], gh[(2 * ks + 1) * 4 + 3]);
        Gl[ks].u[0] = cpack(gl[(2 * ks) * 4 + 0], gl[(2 * ks) * 4 + 1]);
        Gl[ks].u[1] = cpack(gl[(2 * ks) * 4 + 2], gl[(2 * ks) * 4 + 3]);
        Gl[ks].u[2] = cpack(gl[(2 * ks + 1) * 4 + 0], gl[(2 * ks + 1) * 4 + 1]);
        Gl[ks].u[3] = cpack(gl[(2 * ks + 1) * 4 + 2], gl[(2 * ks + 1) * 4 + 3]);
    }

    // ---- logits = gw2 @ gn via 3-term MFMA (rows 0..7 valid; A-frags from LDS) ----
    f4v lacc = {0.f, 0.f, 0.f, 0.f};
    BFrag W0, W1, V0, V1;
    W0.q = sW2H[0 * 64 + lane]; W1.q = sW2H[1 * 64 + lane];
    V0.q = sW2L[0 * 64 + lane]; V1.q = sW2L[1 * 64 + lane];
    lacc = __builtin_amdgcn_mfma_f32_16x16x32_bf16(W0.s, Gh[0].s, lacc, 0, 0, 0);
    lacc = __builtin_amdgcn_mfma_f32_16x16x32_bf16(W1.s, Gh[1].s, lacc, 0, 0, 0);
    lacc = __builtin_amdgcn_mfma_f32_16x16x32_bf16(W0.s, Gl[0].s, lacc, 0, 0, 0);
    lacc = __builtin_amdgcn_mfma_f32_16x16x32_bf16(W1.s, Gl[1].s, lacc, 0, 0, 0);
    lacc = __builtin_amdgcn_mfma_f32_16x16x32_bf16(V0.s, Gh[0].s, lacc, 0, 0, 0);
    lacc = __builtin_amdgcn_mfma_f32_16x16x32_bf16(V1.s, Gh[1].s, lacc, 0, 0, 0);

    float other[4];
#pragma unroll
    for (int j = 0; j < 4; j++) other[j] = __shfl_xor(lacc[j], 16, 64);
    float logit[8];
#pragma unroll
    for (int j = 0; j < 4; j++) {
        logit[j] = lacc[j] + s_gb2[j];
        logit[4 + j] = other[j] + s_gb2[4 + j];
    }

    // ---- top-2 (>= 2nd-largest semantics) + margin flag ----
    float m1 = logit[0]; int i1 = 0;
#pragma unroll
    for (int e = 1; e < 8; e++) if (logit[e] > m1) { m1 = logit[e]; i1 = e; }
    float m2 = -INFINITY; int i2 = -1;
#pragma unroll
    for (int e = 0; e < 8; e++) if (e != i1 && logit[e] > m2) { m2 = logit[e]; i2 = e; }
    float m3 = -INFINITY;
#pragma unroll
    for (int e = 0; e < 8; e++) if (e != i1 && e != i2 && logit[e] > m3) m3 = logit[e];
    unsigned mbits = 0;
#pragma unroll
    for (int e = 0; e < 8; e++) if (logit[e] >= m2) mbits |= 1u << e;

    const bool active = (g == 0);
    if (active) sel[n] = (unsigned char)mbits;
    const bool flg = active && (m2 - m3 < TAU);

#pragma unroll
    for (int e = 0; e < 8; e++) {
        const unsigned long long bal = __ballot(active && ((mbits >> e) & 1u));
        if (lane == 0) atomicAdd(&s_cnt[e], (int)__popcll(bal));
    }
    {
        const unsigned long long bal = __ballot(flg);
        int pos0 = 0;
        if (lane == 0 && bal) pos0 = atomicAdd(refcnt, (int)__popcll(bal));
        pos0 = __shfl(pos0, 0, 64);
        if (flg) {
            const int rank = (int)__popcll(bal & ((1ull << lane) - 1ull));
            reflist[pos0 + rank] = n;
        }
    }
    __syncthreads();
    if (t < 8) blkcnt[blockIdx.x * 8 + t] = s_cnt[t];
}

// ---------------- K1.25: exact-fp32 refine, ONE WAVE PER POINT (no scratch arrays) ----------------
__global__ __launch_bounds__(256) void refine_kernel(
    const float* __restrict__ coords,
    const float* __restrict__ fw, const float* __restrict__ fb,
    const float* __restrict__ gw1, const float* __restrict__ gb1,
    const float* __restrict__ lng, const float* __restrict__ lnb,
    const float* __restrict__ gw2, const float* __restrict__ gb2,
    const int* __restrict__ reflist, const int* __restrict__ refcnt,
    unsigned char* __restrict__ sel, int* __restrict__ blkcnt)
{
    const int R = *refcnt;
    if (blockIdx.x * 4 >= R) return;            // uniform early exit, before any barrier

    __shared__ float s_gw1t[64 * 65];           // transposed + pad: [k][r] at k*65+r
    __shared__ float s_gw2[512];
    __shared__ float s_fw[192], s_fb[64], s_gb1[64], s_lng[64], s_lnb[64], s_gb2[8];
    __shared__ float s_f[4][64];                // per-wave feature buffer

    const int t = threadIdx.x;
    for (int i = t; i < 4096; i += 256) s_gw1t[(i & 63) * 65 + (i >> 6)] = gw1[i];
    for (int i = t; i < 512; i += 256) s_gw2[i] = gw2[i];
    if (t < 192) s_fw[t] = fw[t];
    if (t < 64) { s_fb[t] = fb[t]; s_gb1[t] = gb1[t]; s_lng[t] = lng[t]; s_lnb[t] = lnb[t]; }
    if (t < 8) s_gb2[t] = gb2[t];
    __syncthreads();

    const int wv = t >> 6, lane = t & 63;
    for (int idx = blockIdx.x * 4 + wv; idx < R; idx += gridDim.x * 4) {
        const int n = reflist[idx];
        const float c0 = coords[n * 3], c1 = coords[n * 3 + 1], c2 = coords[n * 3 + 2];
        const float fr = s_fb[lane] + c0 * s_fw[lane * 3] + c1 * s_fw[lane * 3 + 1]
                       + c2 * s_fw[lane * 3 + 2];
        s_f[wv][lane] = fr;
        float a = s_gb1[lane];
#pragma unroll
        for (int k = 0; k < 64; k++)
            a += s_f[wv][k] * s_gw1t[k * 65 + lane];
        float mu = a;
#pragma unroll
        for (int d = 1; d < 64; d <<= 1) mu += __shfl_xor(mu, d, 64);
        mu *= (1.f / 64.f);
        const float dv = a - mu;
        float v = dv * dv;
#pragma unroll
        for (int d = 1; d < 64; d <<= 1) v += __shfl_xor(v, d, 64);
        const float rs = rsqrtf(v * (1.f / 64.f) + 1e-5f);
        const float gn = dv * rs * s_lng[lane] + s_lnb[lane];
        float lp[8];
#pragma unroll
        for (int e = 0; e < 8; e++) lp[e] = gn * s_gw2[e * 64 + lane];
#pragma unroll
        for (int e = 0; e < 8; e++) {
#pragma unroll
            for (int d = 1; d < 64; d <<= 1) lp[e] += __shfl_xor(lp[e], d, 64);
            lp[e] += s_gb2[e];
        }
        if (lane == 0) {
            float m1 = lp[0]; int i1 = 0;
#pragma unroll
            for (int e = 1; e < 8; e++) if (lp[e] > m1) { m1 = lp[e]; i1 = e; }
            float m2 = -INFINITY;
#pragma unroll
            for (int e = 0; e < 8; e++) if (e != i1 && lp[e] > m2) m2 = lp[e];
            unsigned mbits = 0;
#pragma unroll
            for (int e = 0; e < 8; e++) if (lp[e] >= m2) mbits |= 1u << e;
            const unsigned old = sel[n];
            if (mbits != old) {
                sel[n] = (unsigned char)mbits;
                const int b = n >> 7;
#pragma unroll
                for (int e = 0; e < 8; e++) {
                    const int was = (old >> e) & 1, now = (mbits >> e) & 1;
                    if (was != now) atomicAdd(&blkcnt[b * 8 + e], now - was);
                }
            }
        }
    }
}

// ---------------- K1.5: scan, one block per expert ----------------
__global__ __launch_bounds__(256) void scan_kernel(
    const int* __restrict__ blkcnt, int* __restrict__ baseoff,
    int* __restrict__ counts)
{
    const int e = blockIdx.x;          // 0..7
    const int t = threadIdx.x;         // each thread: 8 consecutive gate blocks
    const int lane = t & 63, wv = t >> 6;
    __shared__ int s_w[4];

    int v[8]; int sum = 0;
#pragma unroll
    for (int i = 0; i < 8; i++) { v[i] = blkcnt[(t * 8 + i) * 8 + e]; sum += v[i]; }
    int incl = sum;
#pragma unroll
    for (int d = 1; d < 64; d <<= 1) {
        const int x = __shfl_up(incl, d, 64);
        if (lane >= d) incl += x;
    }
    if (lane == 63) s_w[wv] = incl;
    __syncthreads();
    int woff = 0;
#pragma unroll
    for (int i = 0; i < 4; i++) if (i < wv) woff += s_w[i];
    int run = woff + incl - sum;       // exclusive prefix for this thread's first block
#pragma unroll
    for (int i = 0; i < 8; i++) { baseoff[(t * 8 + i) * 8 + e] = run; run += v[i]; }
    if (t == 255) counts[e] = run;
}

// ---------------- K2: scatter points into buckets (no atomics) + zero out[] + aux ----------------
__global__ __launch_bounds__(128) void scatter_kernel(
    const unsigned char* __restrict__ sel, const int* __restrict__ baseoff,
    const int* __restrict__ counts, int* __restrict__ buckets, float* __restrict__ out)
{
    __shared__ int s_w0[8];
    const int t = threadIdx.x;
    const int n = blockIdx.x * 128 + t;
    out[n] = 0.f;                        // replaces hipMemsetAsync(d_out)
    if (blockIdx.x == 0 && t == 0) {     // aux loss (counts final after scan)
        double s = 0.0;
        for (int e = 0; e < 8; e++) { const double c = (double)counts[e]; s += c * c; }
        out[NPTS] = (float)(8.0 * s / ((double)NPTS * (double)NPTS));
    }
    const unsigned m = sel[n];
    const int w = t >> 6, lane = t & 63;
    unsigned long long bal[8];
#pragma unroll
    for (int e = 0; e < 8; e++) {
        bal[e] = __ballot((m >> e) & 1u);
        if (w == 0 && lane == 0) s_w0[e] = (int)__popcll(bal[e]);
    }
    __syncthreads();
#pragma unroll
    for (int e = 0; e < 8; e++) {
        if ((m >> e) & 1u) {
            int rank = (int)__popcll(bal[e] & ((1ull << lane) - 1ull));
            if (w == 1) rank += s_w0[e];
            buckets[e * NPTS + baseoff[blockIdx.x * 8 + e] + rank] = n;
        }
    }
}

// ---------------- K3: per-expert MFMA SIREN; direct per-lane fragment build (no s_ft) ----------------
__global__ __launch_bounds__(256) void expert_kernel(
    const float* __restrict__ coords,
    const float* __restrict__ fw, const float* __restrict__ fb,
    const float* __restrict__ wl, const float* __restrict__ bl,
    const uint4* __restrict__ packA, const float* __restrict__ biasS,
    const int* __restrict__ counts, const int* __restrict__ buckets,
    float* __restrict__ out)
{
    const int e = blockIdx.x >> 11;            // CPE == 2048
    const int chunk = blockIdx.x & (CPE - 1);
    const int cnt = counts[e];
    const int base = chunk * 128;
    if (base >= cnt) return;

    __shared__ float s_b[192];
    __shared__ float s_wl[64];
    __shared__ float s_fw[192];
    __shared__ float s_fb[64];
    __shared__ float s_bl;

    const int t = threadIdx.x;
    if (t < 192) {
        s_b[t] = biasS[e * 192 + t];
        s_fw[t] = fw[t];
    }
    if (t < 64) {
        s_fb[t] = fb[t];
        s_wl[t] = wl[e * 64 + t];
    }
    if (t == 0) s_bl = bl[e];
    __syncthreads();

    const int lane = t & 63;
    const int wv = t >> 6;
    const int g = lane >> 4, c = lane & 15;
    const int i0 = base + wv * 32 + c;
    const int i1 = i0 + 16;
    const int id0 = (i0 < cnt) ? buckets[e * NPTS + i0] : -1;
    const int id1 = (i1 < cnt) ? buckets[e * NPTS + i1] : -1;

    // ---- direct per-lane B-fragment features: lane needs k = 16s + 4g + j (s=0..3, j=0..3) ----
    BFrag B0[2], B1[2];
    {
        const float a0 = (id0 >= 0) ? coords[id0 * 3] : 0.f;
        const float a1 = (id0 >= 0) ? coords[id0 * 3 + 1] : 0.f;
        const float a2 = (id0 >= 0) ? coords[id0 * 3 + 2] : 0.f;
        const float b0 = (id1 >= 0) ? coords[id1 * 3] : 0.f;
        const float b1 = (id1 >= 0) ? coords[id1 * 3 + 1] : 0.f;
        const float b2 = (id1 >= 0) ? coords[id1 * 3 + 2] : 0.f;
        float f0[4][4], f1[4][4];
#pragma unroll
        for (int s = 0; s < 4; s++) {
#pragma unroll
            for (int j = 0; j < 4; j++) {
                const int k = 16 * s + 4 * g + j;
                const float wx = s_fw[k * 3], wy = s_fw[k * 3 + 1], wz = s_fw[k * 3 + 2];
                const float bb = s_fb[k];
                f0[s][j] = bb + a0 * wx + a1 * wy + a2 * wz;
                f1[s][j] = bb + b0 * wx + b1 * wy + b2 * wz;
            }
        }
#pragma unroll
        for (int ks = 0; ks < 2; ks++) {
            B0[ks].u[0] = cpack(f0[2 * ks][0], f0[2 * ks][1]);
            B0[ks].u[1] = cpack(f0[2 * ks][2], f0[2 * ks][3]);
            B0[ks].u[2] = cpack(f0[2 * ks + 1][0], f0[2 * ks + 1][1]);
            B0[ks].u[3] = cpack(f0[2 * ks + 1][2], f0[2 * ks + 1][3]);
            B1[ks].u[0] = cpack(f1[2 * ks][0], f1[2 * ks][1]);
            B1[ks].u[1] = cpack(f1[2 * ks][2], f1[2 * ks][3]);
            B1[ks].u[2] = cpack(f1[2 * ks + 1][0], f1[2 * ks + 1][1]);
            B1[ks].u[3] = cpack(f1[2 * ks + 1][2], f1[2 * ks + 1][3]);
        }
    }

#pragma unroll 1
    for (int ell = 0; ell < 2; ell++) {
        f4v acc0[4], acc1[4];
#pragma unroll
        for (int tau = 0; tau < 4; tau++) {
            const float4 b = *(const float4*)&s_b[ell * 64 + tau * 16 + 4 * g];
            acc0[tau][0] = b.x; acc0[tau][1] = b.y; acc0[tau][2] = b.z; acc0[tau][3] = b.w;
            acc1[tau][0] = b.x; acc1[tau][1] = b.y; acc1[tau][2] = b.z; acc1[tau][3] = b.w;
        }
        const uint4* Ab = packA + (size_t)((e * 3 + ell) * 8) * 64 + lane;
#pragma unroll
        for (int tau = 0; tau < 4; tau++) {
            BFrag A0, A1;
            A0.q = Ab[(tau * 2 + 0) * 64];
            A1.q = Ab[(tau * 2 + 1) * 64];
            acc0[tau] = __builtin_amdgcn_mfma_f32_16x16x32_bf16(A0.s, B0[0].s, acc0[tau], 0, 0, 0);
            acc0[tau] = __builtin_amdgcn_mfma_f32_16x16x32_bf16(A1.s, B0[1].s, acc0[tau], 0, 0, 0);
            acc1[tau] = __builtin_amdgcn_mfma_f32_16x16x32_bf16(A0.s, B1[0].s, acc1[tau], 0, 0, 0);
            acc1[tau] = __builtin_amdgcn_mfma_f32_16x16x32_bf16(A1.s, B1[1].s, acc1[tau], 0, 0, 0);
        }
        // sin + repack: D registers become next layer's B fragments
#pragma unroll
        for (int ks = 0; ks < 2; ks++) {
            B0[ks].u[0] = cpack(sinrev(acc0[2 * ks][0]), sinrev(acc0[2 * ks][1]));
            B0[ks].u[1] = cpack(sinrev(acc0[2 * ks][2]), sinrev(acc0[2 * ks][3]));
            B0[ks].u[2] = cpack(sinrev(acc0[2 * ks + 1][0]), sinrev(acc0[2 * ks + 1][1]));
            B0[ks].u[3] = cpack(sinrev(acc0[2 * ks + 1][2]), sinrev(acc0[2 * ks + 1][3]));
            B1[ks].u[0] = cpack(sinrev(acc1[2 * ks][0]), sinrev(acc1[2 * ks][1]));
            B1[ks].u[1] = cpack(sinrev(acc1[2 * ks][2]), sinrev(acc1[2 * ks][3]));
            B1[ks].u[2] = cpack(sinrev(acc1[2 * ks + 1][0]), sinrev(acc1[2 * ks + 1][1]));
            B1[ks].u[3] = cpack(sinrev(acc1[2 * ks + 1][2]), sinrev(acc1[2 * ks + 1][3]));
        }
    }

    // ---- layer 2 + final dot ----
    {
        f4v acc0[4], acc1[4];
#pragma unroll
        for (int tau = 0; tau < 4; tau++) {
            const float4 b = *(const float4*)&s_b[2 * 64 + tau * 16 + 4 * g];
            acc0[tau][0] = b.x; acc0[tau][1] = b.y; acc0[tau][2] = b.z; acc0[tau][3] = b.w;
            acc1[tau][0] = b.x; acc1[tau][1] = b.y; acc1[tau][2] = b.z; acc1[tau][3] = b.w;
        }
        const uint4* Ab = packA + (size_t)((e * 3 + 2) * 8) * 64 + lane;
#pragma unroll
        for (int tau = 0; tau < 4; tau++) {
            BFrag A0, A1;
            A0.q = Ab[(tau * 2 + 0) * 64];
            A1.q = Ab[(tau * 2 + 1) * 64];
            acc0[tau] = __builtin_amdgcn_mfma_f32_16x16x32_bf16(A0.s, B0[0].s, acc0[tau], 0, 0, 0);
            acc0[tau] = __builtin_amdgcn_mfma_f32_16x16x32_bf16(A1.s, B0[1].s, acc0[tau], 0, 0, 0);
            acc1[tau] = __builtin_amdgcn_mfma_f32_16x16x32_bf16(A0.s, B1[0].s, acc1[tau], 0, 0, 0);
            acc1[tau] = __builtin_amdgcn_mfma_f32_16x16x32_bf16(A1.s, B1[1].s, acc1[tau], 0, 0, 0);
        }
        float px0 = 0.f, px1 = 0.f;
#pragma unroll
        for (int tau = 0; tau < 4; tau++) {
            const float4 w = *(const float4*)&s_wl[tau * 16 + 4 * g];
            px0 += sinrev(acc0[tau][0]) * w.x + sinrev(acc0[tau][1]) * w.y
                 + sinrev(acc0[tau][2]) * w.z + sinrev(acc0[tau][3]) * w.w;
            px1 += sinrev(acc1[tau][0]) * w.x + sinrev(acc1[tau][1]) * w.y
                 + sinrev(acc1[tau][2]) * w.z + sinrev(acc1[tau][3]) * w.w;
        }
        px0 += __shfl_xor(px0, 16, 64); px0 += __shfl_xor(px0, 32, 64);
        px1 += __shfl_xor(px1, 16, 64); px1 += __shfl_xor(px1, 32, 64);
        if (g == 0) {
            if (id0 >= 0) atomicAdd(&out[id0], px0 + s_bl);
            if (id1 >= 0) atomicAdd(&out[id1], px1 + s_bl);
        }
    }
}

extern "C" void kernel_launch(void* const* d_in, const int* in_sizes, int n_in,
                              void* d_out, int out_size, void* d_ws, size_t ws_size,
                              hipStream_t stream)
{
    const float* coords = (const float*)d_in[0];
    const float* fw  = (const float*)d_in[1];
    const float* fb  = (const float*)d_in[2];
    const float* gw1 = (const float*)d_in[3];
    const float* gb1 = (const float*)d_in[4];
    const float* lng = (const float*)d_in[5];
    const float* lnb = (const float*)d_in[6];
    const float* gw2 = (const float*)d_in[7];
    const float* gb2 = (const float*)d_in[8];
    const float* we0 = (const float*)d_in[9];
    const float* be0 = (const float*)d_in[10];
    const float* wm  = (const float*)d_in[11];
    const float* bm  = (const float*)d_in[12];
    const float* wl  = (const float*)d_in[13];
    const float* bl  = (const float*)d_in[14];
    float* out = (float*)d_out;

    char* ws = (char*)d_ws;
    int* counts           = (int*)ws;                        // 64
    int* buckets          = (int*)(ws + 64);                 // 8*NPTS*4 = 8388608
    uint4* packA          = (uint4*)(ws + 8388672);          // 196608
    float* biasS          = (float*)(ws + 8585280);          // 6144
    int* blkcnt           = (int*)(ws + 8591424);            // 65536
    int* baseoff          = (int*)(ws + 8656960);            // 65536
    unsigned char* sel    = (unsigned char*)(ws + 8722496);  // 262144
    uint4* packGW1H       = (uint4*)(ws + 8984640);          // 8192
    uint4* packGW1L       = (uint4*)(ws + 8992832);          // 8192
    uint4* packGW2H       = (uint4*)(ws + 9001024);          // 2048
    uint4* packGW2L       = (uint4*)(ws + 9003072);          // 2048
    int* reflist          = (int*)(ws + 9005120);            // 1048576
    int* refcnt           = (int*)(ws + 10053696);           // 64

    hipMemsetAsync(refcnt, 0, 64, stream);

    prep_kernel<<<57, 256, 0, stream>>>(we0, be0, wm, bm, gw1, gw2, packA, biasS,
                                        packGW1H, packGW1L, packGW2H, packGW2L);
    gate_kernel<<<GBLK, 512, 0, stream>>>(coords, fw, fb, gb1, lng, lnb, gb2,
                                          packGW1H, packGW1L, packGW2H, packGW2L,
                                          sel, blkcnt, reflist, refcnt);
    refine_kernel<<<128, 256, 0, stream>>>(coords, fw, fb, gw1, gb1, lng, lnb, gw2, gb2,
                                           reflist, refcnt, sel, blkcnt);
    scan_kernel<<<8, 256, 0, stream>>>(blkcnt, baseoff, counts);
    scatter_kernel<<<GBLK, 128, 0, stream>>>(sel, baseoff, counts, buckets, out);
    expert_kernel<<<8 * CPE, 256, 0, stream>>>(coords, fw, fb, wl, bl, packA, biasS,
                                               counts, buckets, out);
}

// Round 12
// 104.330 us; speedup vs baseline: 2.0536x; 1.0299x over previous
//
#include <hip/hip_runtime.h>
#include <math.h>

#define NPTS 262144
#define GBLK (NPTS / 128)     // 2048 128-point groups (blkcnt/scatter granularity)
#define GGRID (NPTS / 256)    // 1024 gate blocks (256 points each)
#define CPE  2048             // chunks per expert in expert grid
#define TAU  0.01f            // refine margin threshold (logit units)

typedef float f4v __attribute__((ext_vector_type(4)));
typedef short s8v __attribute__((ext_vector_type(8)));

// manual RNE (prep only; identical rounding to HW cvt)
static __device__ __forceinline__ unsigned short f2bf(float f) {
    unsigned u = __float_as_uint(f);
    u += 0x7fffu + ((u >> 16) & 1u);
    return (unsigned short)(u >> 16);
}
// HW bf16 convert (clang lowers paired fptrunc to v_cvt_pk_bf16_f32, RNE)
static __device__ __forceinline__ unsigned short f2bf_hw(float f) {
    __bf16 b = (__bf16)f;
    unsigned short u;
    __builtin_memcpy(&u, &b, 2);
    return u;
}
static __device__ __forceinline__ float bf2f(unsigned short h) {
    return __uint_as_float(((unsigned)h) << 16);
}
static __device__ __forceinline__ unsigned pk2b(unsigned short lo, unsigned short hi) {
    return ((unsigned)hi << 16) | (unsigned)lo;
}
static __device__ __forceinline__ unsigned cpack(float lo, float hi) {
    return pk2b(f2bf_hw(lo), f2bf_hw(hi));
}
static __device__ __forceinline__ float sinrev(float x) {   // sin(2*pi*x)
    return __builtin_amdgcn_sinf(x);
}

union BFrag { uint4 q; unsigned u[4]; s8v s; };

// ---------------- prep: pack expert A-frags + scaled biases + gate hi/lo packs ----------------
__global__ __launch_bounds__(256) void prep_kernel(
    const float* __restrict__ we0, const float* __restrict__ be0,
    const float* __restrict__ wm, const float* __restrict__ bm,
    const float* __restrict__ gw1, const float* __restrict__ gw2,
    uint4* __restrict__ packA, float* __restrict__ biasS,
    uint4* __restrict__ packGW1H, uint4* __restrict__ packGW1L,
    uint4* __restrict__ packGW2H, uint4* __restrict__ packGW2L)
{
    const int idx = blockIdx.x * 256 + threadIdx.x;
    const float PI2I = 0.15915494309189535f;
    if (idx < 12288) {
        const int l = idx & 63;
        const int fr = (idx >> 6) & 7;
        const int grp = idx >> 9;            // e*3 + ell
        const int e = grp / 3, ell = grp % 3;
        const int tau = fr >> 1, ks = fr & 1;
        const int g = l >> 4, m = l & 15;
        const int row = tau * 16 + m;
        const float scale = (ell == 0) ? (22.5f + 45.0f * (float)e) * PI2I : 30.0f * PI2I;
        const float* W = (ell == 0) ? (we0 + e * 4096) : (wm + ((ell - 1) * 8 + e) * 4096);
        unsigned short v[8];
#pragma unroll
        for (int i = 0; i < 8; i++) {
            const int k = 32 * ks + 4 * g + (i < 4 ? i : i + 12);
            v[i] = f2bf(W[row * 64 + k] * scale);
        }
        uint4 q;
        q.x = pk2b(v[0], v[1]); q.y = pk2b(v[2], v[3]);
        q.z = pk2b(v[4], v[5]); q.w = pk2b(v[6], v[7]);
        packA[idx] = q;
    } else if (idx < 13824) {
        const int j = idx - 12288;           // e*192 + ell*64 + r
        const int r = j & 63;
        const int grp = j >> 6;
        const int e = grp / 3, ell = grp % 3;
        const float scale = (ell == 0) ? (22.5f + 45.0f * (float)e) * PI2I : 30.0f * PI2I;
        const float b = (ell == 0) ? be0[e * 64 + r] : bm[((ell - 1) * 8 + e) * 64 + r];
        biasS[j] = b * scale;
    } else if (idx < 14336) {
        // gate gw1 hi/lo A-frags: 8 frags (tau*2+ks) x 64 lanes
        const int j = idx - 13824;           // 0..511
        const int l = j & 63;
        const int fr = j >> 6;
        const int tau = fr >> 1, ks = fr & 1;
        const int g = l >> 4;
        const int row = tau * 16 + (l & 15);
        unsigned short vh[8], vl[8];
#pragma unroll
        for (int i = 0; i < 8; i++) {
            const int k = 32 * ks + 4 * g + (i < 4 ? i : i + 12);
            const float x = gw1[row * 64 + k];
            const unsigned short h = f2bf(x);
            vh[i] = h;
            vl[i] = f2bf(x - bf2f(h));
        }
        uint4 qh, ql;
        qh.x = pk2b(vh[0], vh[1]); qh.y = pk2b(vh[2], vh[3]);
        qh.z = pk2b(vh[4], vh[5]); qh.w = pk2b(vh[6], vh[7]);
        ql.x = pk2b(vl[0], vl[1]); ql.y = pk2b(vl[2], vl[3]);
        ql.z = pk2b(vl[4], vl[5]); ql.w = pk2b(vl[6], vl[7]);
        packGW1H[j] = qh; packGW1L[j] = ql;
    } else if (idx < 14464) {
        // gate gw2 hi/lo A-frags: rows 0..7 = gw2, rows 8..15 = 0; 2 frags (ks) x 64 lanes
        const int j = idx - 14336;           // 0..127
        const int l = j & 63;
        const int ks = j >> 6;
        const int g = l >> 4;
        const int row = l & 15;
        unsigned short vh[8], vl[8];
#pragma unroll
        for (int i = 0; i < 8; i++) {
            const int k = 32 * ks + 4 * g + (i < 4 ? i : i + 12);
            const float x = (row < 8) ? gw2[row * 64 + k] : 0.f;
            const unsigned short h = f2bf(x);
            vh[i] = h;
            vl[i] = f2bf(x - bf2f(h));
        }
        uint4 qh, ql;
        qh.x = pk2b(vh[0], vh[1]); qh.y = pk2b(vh[2], vh[3]);
        qh.z = pk2b(vh[4], vh[5]); qh.w = pk2b(vh[6], vh[7]);
        ql.x = pk2b(vl[0], vl[1]); ql.y = pk2b(vl[2], vl[3]);
        ql.z = pk2b(vl[4], vl[5]); ql.w = pk2b(vl[6], vl[7]);
        packGW2H[j] = qh; packGW2L[j] = ql;
    }
}

// ---------------- K1: gate via MFMA; 32 points/wave (2 independent chains) ----------------
// 512 threads = 8 waves x 32 points = 256 points per block.
__global__ __launch_bounds__(512, 2) void gate_kernel(
    const float* __restrict__ coords,
    const float* __restrict__ fw, const float* __restrict__ fb,
    const float* __restrict__ gb1, const float* __restrict__ lng,
    const float* __restrict__ lnb, const float* __restrict__ gb2,
    const uint4* __restrict__ packGW1H, const uint4* __restrict__ packGW1L,
    const uint4* __restrict__ packGW2H, const uint4* __restrict__ packGW2L,
    unsigned char* __restrict__ sel, int* __restrict__ blkcnt,
    int* __restrict__ reflist, int* __restrict__ refcnt)
{
    __shared__ float s_fw[192], s_fb[64], s_gb1[64], s_lng[64], s_lnb[64], s_gb2[8];
    __shared__ uint4 sW1H[512], sW1L[512];      // 8 frags x 64 lanes (16 KB)
    __shared__ uint4 sW2H[128], sW2L[128];      // 2 frags x 64 lanes (4 KB)
    __shared__ int s_cnt[2][8];
    const int t = threadIdx.x;
    sW1H[t] = packGW1H[t];
    sW1L[t] = packGW1L[t];
    if (t < 128) { sW2H[t] = packGW2H[t]; sW2L[t] = packGW2L[t]; }
    if (t < 192) s_fw[t] = fw[t];
    if (t < 64) { s_fb[t] = fb[t]; s_gb1[t] = gb1[t]; s_lng[t] = lng[t]; s_lnb[t] = lnb[t]; }
    if (t < 8) s_gb2[t] = gb2[t];
    if (t < 16) s_cnt[t >> 3][t & 7] = 0;
    __syncthreads();

    const int lane = t & 63;
    const int wv = t >> 6;
    const int g = lane >> 4, c = lane & 15;
    const int half = wv >> 2;                   // which 128-point half of the block
    const int n0 = blockIdx.x * 256 + wv * 32 + c;
    const int n1 = n0 + 16;

    // ---- features for both points (fp32, exact order) ----
    const float a0 = coords[n0 * 3], a1 = coords[n0 * 3 + 1], a2 = coords[n0 * 3 + 2];
    const float b0 = coords[n1 * 3], b1 = coords[n1 * 3 + 1], b2 = coords[n1 * 3 + 2];
    BFrag Bh0[2], Bl0[2], Bh1[2], Bl1[2];
#pragma unroll
    for (int ks = 0; ks < 2; ks++) {
#pragma unroll
        for (int q = 0; q < 4; q++) {
            // element pair (2q, 2q+1) of this frag: k = 32*ks + 16*(q>>1) ... mapping below
            // fv index i = ks*8 + 2q + {0,1}; k = 16*(i/4) + 4*g + (i%4) with s-grouping:
            const int i0 = ks * 8 + 2 * q, i1 = i0 + 1;
            const int s0 = i0 >> 2, j0 = i0 & 3;
            const int s1 = i1 >> 2, j1 = i1 & 3;
            const int k0 = 16 * s0 + 4 * g + j0;
            const int k1 = 16 * s1 + 4 * g + j1;
            const float w0x = s_fw[k0 * 3], w0y = s_fw[k0 * 3 + 1], w0z = s_fw[k0 * 3 + 2];
            const float w1x = s_fw[k1 * 3], w1y = s_fw[k1 * 3 + 1], w1z = s_fw[k1 * 3 + 2];
            const float bb0 = s_fb[k0], bb1 = s_fb[k1];
            const float p0 = bb0 + a0 * w0x + a1 * w0y + a2 * w0z;
            const float p1 = bb1 + a0 * w1x + a1 * w1y + a2 * w1z;
            const float q0 = bb0 + b0 * w0x + b1 * w0y + b2 * w0z;
            const float q1 = bb1 + b0 * w1x + b1 * w1y + b2 * w1z;
            const unsigned short ph0 = f2bf_hw(p0), ph1 = f2bf_hw(p1);
            const unsigned short qh0 = f2bf_hw(q0), qh1 = f2bf_hw(q1);
            Bh0[ks].u[q] = pk2b(ph0, ph1);
            Bl0[ks].u[q] = cpack(p0 - bf2f(ph0), p1 - bf2f(ph1));
            Bh1[ks].u[q] = pk2b(qh0, qh1);
            Bl1[ks].u[q] = cpack(q0 - bf2f(qh0), q1 - bf2f(qh1));
        }
    }

    // ---- g = gw1 @ f + gb1 via 3-term MFMA, two independent chains share A-frags ----
    f4v acc0[4], acc1[4];
#pragma unroll
    for (int tau = 0; tau < 4; tau++) {
        const float4 b = *(const float4*)&s_gb1[tau * 16 + 4 * g];
        acc0[tau][0] = b.x; acc0[tau][1] = b.y; acc0[tau][2] = b.z; acc0[tau][3] = b.w;
        acc1[tau][0] = b.x; acc1[tau][1] = b.y; acc1[tau][2] = b.z; acc1[tau][3] = b.w;
    }
#pragma unroll
    for (int tau = 0; tau < 4; tau++) {
        BFrag AH0, AH1, AL0, AL1;
        AH0.q = sW1H[(tau * 2 + 0) * 64 + lane];
        AH1.q = sW1H[(tau * 2 + 1) * 64 + lane];
        AL0.q = sW1L[(tau * 2 + 0) * 64 + lane];
        AL1.q = sW1L[(tau * 2 + 1) * 64 + lane];
        acc0[tau] = __builtin_amdgcn_mfma_f32_16x16x32_bf16(AH0.s, Bh0[0].s, acc0[tau], 0, 0, 0);
        acc1[tau] = __builtin_amdgcn_mfma_f32_16x16x32_bf16(AH0.s, Bh1[0].s, acc1[tau], 0, 0, 0);
        acc0[tau] = __builtin_amdgcn_mfma_f32_16x16x32_bf16(AH1.s, Bh0[1].s, acc0[tau], 0, 0, 0);
        acc1[tau] = __builtin_amdgcn_mfma_f32_16x16x32_bf16(AH1.s, Bh1[1].s, acc1[tau], 0, 0, 0);
        acc0[tau] = __builtin_amdgcn_mfma_f32_16x16x32_bf16(AH0.s, Bl0[0].s, acc0[tau], 0, 0, 0);
        acc1[tau] = __builtin_amdgcn_mfma_f32_16x16x32_bf16(AH0.s, Bl1[0].s, acc1[tau], 0, 0, 0);
        acc0[tau] = __builtin_amdgcn_mfma_f32_16x16x32_bf16(AH1.s, Bl0[1].s, acc0[tau], 0, 0, 0);
        acc1[tau] = __builtin_amdgcn_mfma_f32_16x16x32_bf16(AH1.s, Bl1[1].s, acc1[tau], 0, 0, 0);
        acc0[tau] = __builtin_amdgcn_mfma_f32_16x16x32_bf16(AL0.s, Bh0[0].s, acc0[tau], 0, 0, 0);
        acc1[tau] = __builtin_amdgcn_mfma_f32_16x16x32_bf16(AL0.s, Bh1[0].s, acc1[tau], 0, 0, 0);
        acc0[tau] = __builtin_amdgcn_mfma_f32_16x16x32_bf16(AL1.s, Bh0[1].s, acc0[tau], 0, 0, 0);
        acc1[tau] = __builtin_amdgcn_mfma_f32_16x16x32_bf16(AL1.s, Bh1[1].s, acc1[tau], 0, 0, 0);
    }

    // ---- LayerNorm (both sets, independent shfl chains) ----
    float s1a = 0.f, s1b = 0.f;
#pragma unroll
    for (int tau = 0; tau < 4; tau++)
#pragma unroll
        for (int j = 0; j < 4; j++) { s1a += acc0[tau][j]; s1b += acc1[tau][j]; }
    s1a += __shfl_xor(s1a, 16, 64); s1a += __shfl_xor(s1a, 32, 64);
    s1b += __shfl_xor(s1b, 16, 64); s1b += __shfl_xor(s1b, 32, 64);
    const float mu0 = s1a * (1.f / 64.f), mu1 = s1b * (1.f / 64.f);
    float s2a = 0.f, s2b = 0.f;
#pragma unroll
    for (int tau = 0; tau < 4; tau++)
#pragma unroll
        for (int j = 0; j < 4; j++) {
            const float d0 = acc0[tau][j] - mu0; s2a += d0 * d0;
            const float d1 = acc1[tau][j] - mu1; s2b += d1 * d1;
        }
    s2a += __shfl_xor(s2a, 16, 64); s2a += __shfl_xor(s2a, 32, 64);
    s2b += __shfl_xor(s2b, 16, 64); s2b += __shfl_xor(s2b, 32, 64);
    const float rs0 = rsqrtf(s2a * (1.f / 64.f) + 1e-5f);
    const float rs1 = rsqrtf(s2b * (1.f / 64.f) + 1e-5f);

    BFrag Gh0[2], Gl0[2], Gh1[2], Gl1[2];
#pragma unroll
    for (int ks = 0; ks < 2; ks++) {
#pragma unroll
        for (int q = 0; q < 4; q++) {
            const int i0 = ks * 8 + 2 * q, i1 = i0 + 1;
            const int tau0 = i0 >> 2, j0 = i0 & 3;
            const int tau1 = i1 >> 2, j1 = i1 & 3;
            const int r0 = tau0 * 16 + 4 * g + j0;
            const int r1 = tau1 * 16 + 4 * g + j1;
            const float gnA0 = (acc0[tau0][j0] - mu0) * rs0 * s_lng[r0] + s_lnb[r0];
            const float gnA1 = (acc0[tau1][j1] - mu0) * rs0 * s_lng[r1] + s_lnb[r1];
            const float gnB0 = (acc1[tau0][j0] - mu1) * rs1 * s_lng[r0] + s_lnb[r0];
            const float gnB1 = (acc1[tau1][j1] - mu1) * rs1 * s_lng[r1] + s_lnb[r1];
            const unsigned short hA0 = f2bf_hw(gnA0), hA1 = f2bf_hw(gnA1);
            const unsigned short hB0 = f2bf_hw(gnB0), hB1 = f2bf_hw(gnB1);
            Gh0[ks].u[q] = pk2b(hA0, hA1);
            Gl0[ks].u[q] = cpack(gnA0 - bf2f(hA0), gnA1 - bf2f(hA1));
            Gh1[ks].u[q] = pk2b(hB0, hB1);
            Gl1[ks].u[q] = cpack(gnB0 - bf2f(hB0), gnB1 - bf2f(hB1));
        }
    }

    // ---- logits = gw2 @ gn via 3-term MFMA (two independent chains) ----
    f4v lacc0 = {0.f, 0.f, 0.f, 0.f}, lacc1 = {0.f, 0.f, 0.f, 0.f};
    {
        BFrag W0, W1, V0, V1;
        W0.q = sW2H[0 * 64 + lane]; W1.q = sW2H[1 * 64 + lane];
        V0.q = sW2L[0 * 64 + lane]; V1.q = sW2L[1 * 64 + lane];
        lacc0 = __builtin_amdgcn_mfma_f32_16x16x32_bf16(W0.s, Gh0[0].s, lacc0, 0, 0, 0);
        lacc1 = __builtin_amdgcn_mfma_f32_16x16x32_bf16(W0.s, Gh1[0].s, lacc1, 0, 0, 0);
        lacc0 = __builtin_amdgcn_mfma_f32_16x16x32_bf16(W1.s, Gh0[1].s, lacc0, 0, 0, 0);
        lacc1 = __builtin_amdgcn_mfma_f32_16x16x32_bf16(W1.s, Gh1[1].s, lacc1, 0, 0, 0);
        lacc0 = __builtin_amdgcn_mfma_f32_16x16x32_bf16(W0.s, Gl0[0].s, lacc0, 0, 0, 0);
        lacc1 = __builtin_amdgcn_mfma_f32_16x16x32_bf16(W0.s, Gl1[0].s, lacc1, 0, 0, 0);
        lacc0 = __builtin_amdgcn_mfma_f32_16x16x32_bf16(W1.s, Gl0[1].s, lacc0, 0, 0, 0);
        lacc1 = __builtin_amdgcn_mfma_f32_16x16x32_bf16(W1.s, Gl1[1].s, lacc1, 0, 0, 0);
        lacc0 = __builtin_amdgcn_mfma_f32_16x16x32_bf16(V0.s, Gh0[0].s, lacc0, 0, 0, 0);
        lacc1 = __builtin_amdgcn_mfma_f32_16x16x32_bf16(V0.s, Gh1[0].s, lacc1, 0, 0, 0);
        lacc0 = __builtin_amdgcn_mfma_f32_16x16x32_bf16(V1.s, Gh0[1].s, lacc0, 0, 0, 0);
        lacc1 = __builtin_amdgcn_mfma_f32_16x16x32_bf16(V1.s, Gh1[1].s, lacc1, 0, 0, 0);
    }

    float logit0[8], logit1[8];
#pragma unroll
    for (int j = 0; j < 4; j++) {
        const float o0 = __shfl_xor(lacc0[j], 16, 64);
        const float o1 = __shfl_xor(lacc1[j], 16, 64);
        logit0[j] = lacc0[j] + s_gb2[j];
        logit0[4 + j] = o0 + s_gb2[4 + j];
        logit1[j] = lacc1[j] + s_gb2[j];
        logit1[4 + j] = o1 + s_gb2[4 + j];
    }

    // ---- top-2 + margin flag (per set) ----
    unsigned mbits0 = 0, mbits1 = 0;
    bool flg0, flg1;
    {
        float m1 = logit0[0]; int i1 = 0;
#pragma unroll
        for (int e = 1; e < 8; e++) if (logit0[e] > m1) { m1 = logit0[e]; i1 = e; }
        float m2 = -INFINITY; int i2 = -1;
#pragma unroll
        for (int e = 0; e < 8; e++) if (e != i1 && logit0[e] > m2) { m2 = logit0[e]; i2 = e; }
        float m3 = -INFINITY;
#pragma unroll
        for (int e = 0; e < 8; e++) if (e != i1 && e != i2 && logit0[e] > m3) m3 = logit0[e];
#pragma unroll
        for (int e = 0; e < 8; e++) if (logit0[e] >= m2) mbits0 |= 1u << e;
        flg0 = (m2 - m3 < TAU);
    }
    {
        float m1 = logit1[0]; int i1 = 0;
#pragma unroll
        for (int e = 1; e < 8; e++) if (logit1[e] > m1) { m1 = logit1[e]; i1 = e; }
        float m2 = -INFINITY; int i2 = -1;
#pragma unroll
        for (int e = 0; e < 8; e++) if (e != i1 && logit1[e] > m2) { m2 = logit1[e]; i2 = e; }
        float m3 = -INFINITY;
#pragma unroll
        for (int e = 0; e < 8; e++) if (e != i1 && e != i2 && logit1[e] > m3) m3 = logit1[e];
#pragma unroll
        for (int e = 0; e < 8; e++) if (logit1[e] >= m2) mbits1 |= 1u << e;
        flg1 = (m2 - m3 < TAU);
    }

    const bool active = (g == 0);
    if (active) { sel[n0] = (unsigned char)mbits0; sel[n1] = (unsigned char)mbits1; }

#pragma unroll
    for (int e = 0; e < 8; e++) {
        const unsigned long long bal0 = __ballot(active && ((mbits0 >> e) & 1u));
        const unsigned long long bal1 = __ballot(active && ((mbits1 >> e) & 1u));
        if (lane == 0) atomicAdd(&s_cnt[half][e], (int)(__popcll(bal0) + __popcll(bal1)));
    }
    {
        const unsigned long long bal0 = __ballot(active && flg0);
        const unsigned long long bal1 = __ballot(active && flg1);
        const int p0 = (int)__popcll(bal0);
        int pos0 = 0;
        if (lane == 0 && (bal0 | bal1)) pos0 = atomicAdd(refcnt, p0 + (int)__popcll(bal1));
        pos0 = __shfl(pos0, 0, 64);
        if (active && flg0) {
            const int rank = (int)__popcll(bal0 & ((1ull << lane) - 1ull));
            reflist[pos0 + rank] = n0;
        }
        if (active && flg1) {
            const int rank = p0 + (int)__popcll(bal1 & ((1ull << lane) - 1ull));
            reflist[pos0 + rank] = n1;
        }
    }
    __syncthreads();
    if (t < 16) blkcnt[blockIdx.x * 16 + t] = s_cnt[t >> 3][t & 7];
}

// ---------------- K1.25: exact-fp32 refine, ONE WAVE PER POINT (no scratch arrays) ----------------
__global__ __launch_bounds__(256) void refine_kernel(
    const float* __restrict__ coords,
    const float* __restrict__ fw, const float* __restrict__ fb,
    const float* __restrict__ gw1, const float* __restrict__ gb1,
    const float* __restrict__ lng, const float* __restrict__ lnb,
    const float* __restrict__ gw2, const float* __restrict__ gb2,
    const int* __restrict__ reflist, const int* __restrict__ refcnt,
    unsigned char* __restrict__ sel, int* __restrict__ blkcnt)
{
    const int R = *refcnt;
    if (blockIdx.x * 4 >= R) return;            // uniform early exit, before any barrier

    __shared__ float s_gw1t[64 * 65];           // transposed + pad: [k][r] at k*65+r
    __shared__ float s_gw2[512];
    __shared__ float s_fw[192], s_fb[64], s_gb1[64], s_lng[64], s_lnb[64], s_gb2[8];
    __shared__ float s_f[4][64];                // per-wave feature buffer

    const int t = threadIdx.x;
    for (int i = t; i < 4096; i += 256) s_gw1t[(i & 63) * 65 + (i >> 6)] = gw1[i];
    for (int i = t; i < 512; i += 256) s_gw2[i] = gw2[i];
    if (t < 192) s_fw[t] = fw[t];
    if (t < 64) { s_fb[t] = fb[t]; s_gb1[t] = gb1[t]; s_lng[t] = lng[t]; s_lnb[t] = lnb[t]; }
    if (t < 8) s_gb2[t] = gb2[t];
    __syncthreads();

    const int wv = t >> 6, lane = t & 63;
    for (int idx = blockIdx.x * 4 + wv; idx < R; idx += gridDim.x * 4) {
        const int n = reflist[idx];
        const float c0 = coords[n * 3], c1 = coords[n * 3 + 1], c2 = coords[n * 3 + 2];
        const float fr = s_fb[lane] + c0 * s_fw[lane * 3] + c1 * s_fw[lane * 3 + 1]
                       + c2 * s_fw[lane * 3 + 2];
        s_f[wv][lane] = fr;
        float a = s_gb1[lane];
#pragma unroll
        for (int k = 0; k < 64; k++)
            a += s_f[wv][k] * s_gw1t[k * 65 + lane];
        float mu = a;
#pragma unroll
        for (int d = 1; d < 64; d <<= 1) mu += __shfl_xor(mu, d, 64);
        mu *= (1.f / 64.f);
        const float dv = a - mu;
        float v = dv * dv;
#pragma unroll
        for (int d = 1; d < 64; d <<= 1) v += __shfl_xor(v, d, 64);
        const float rs = rsqrtf(v * (1.f / 64.f) + 1e-5f);
        const float gn = dv * rs * s_lng[lane] + s_lnb[lane];
        float lp[8];
#pragma unroll
        for (int e = 0; e < 8; e++) lp[e] = gn * s_gw2[e * 64 + lane];
#pragma unroll
        for (int e = 0; e < 8; e++) {
#pragma unroll
            for (int d = 1; d < 64; d <<= 1) lp[e] += __shfl_xor(lp[e], d, 64);
            lp[e] += s_gb2[e];
        }
        if (lane == 0) {
            float m1 = lp[0]; int i1 = 0;
#pragma unroll
            for (int e = 1; e < 8; e++) if (lp[e] > m1) { m1 = lp[e]; i1 = e; }
            float m2 = -INFINITY;
#pragma unroll
            for (int e = 0; e < 8; e++) if (e != i1 && lp[e] > m2) m2 = lp[e];
            unsigned mbits = 0;
#pragma unroll
            for (int e = 0; e < 8; e++) if (lp[e] >= m2) mbits |= 1u << e;
            const unsigned old = sel[n];
            if (mbits != old) {
                sel[n] = (unsigned char)mbits;
                const int b = n >> 7;
#pragma unroll
                for (int e = 0; e < 8; e++) {
                    const int was = (old >> e) & 1, now = (mbits >> e) & 1;
                    if (was != now) atomicAdd(&blkcnt[b * 8 + e], now - was);
                }
            }
        }
    }
}

// ---------------- K1.5: scan, one block per expert ----------------
__global__ __launch_bounds__(256) void scan_kernel(
    const int* __restrict__ blkcnt, int* __restrict__ baseoff,
    int* __restrict__ counts)
{
    const int e = blockIdx.x;          // 0..7
    const int t = threadIdx.x;         // each thread: 8 consecutive 128-pt groups
    const int lane = t & 63, wv = t >> 6;
    __shared__ int s_w[4];

    int v[8]; int sum = 0;
#pragma unroll
    for (int i = 0; i < 8; i++) { v[i] = blkcnt[(t * 8 + i) * 8 + e]; sum += v[i]; }
    int incl = sum;
#pragma unroll
    for (int d = 1; d < 64; d <<= 1) {
        const int x = __shfl_up(incl, d, 64);
        if (lane >= d) incl += x;
    }
    if (lane == 63) s_w[wv] = incl;
    __syncthreads();
    int woff = 0;
#pragma unroll
    for (int i = 0; i < 4; i++) if (i < wv) woff += s_w[i];
    int run = woff + incl - sum;       // exclusive prefix for this thread's first group
#pragma unroll
    for (int i = 0; i < 8; i++) { baseoff[(t * 8 + i) * 8 + e] = run; run += v[i]; }
    if (t == 255) counts[e] = run;
}

// ---------------- K2: scatter points into buckets (no atomics) + zero out[] + aux ----------------
__global__ __launch_bounds__(128) void scatter_kernel(
    const unsigned char* __restrict__ sel, const int* __restrict__ baseoff,
    const int* __restrict__ counts, int* __restrict__ buckets, float* __restrict__ out)
{
    __shared__ int s_w0[8];
    const int t = threadIdx.x;
    const int n = blockIdx.x * 128 + t;
    out[n] = 0.f;                        // replaces hipMemsetAsync(d_out)
    if (blockIdx.x == 0 && t == 0) {     // aux loss (counts final after scan)
        double s = 0.0;
        for (int e = 0; e < 8; e++) { const double c = (double)counts[e]; s += c * c; }
        out[NPTS] = (float)(8.0 * s / ((double)NPTS * (double)NPTS));
    }
    const unsigned m = sel[n];
    const int w = t >> 6, lane = t & 63;
    unsigned long long bal[8];
#pragma unroll
    for (int e = 0; e < 8; e++) {
        bal[e] = __ballot((m >> e) & 1u);
        if (w == 0 && lane == 0) s_w0[e] = (int)__popcll(bal[e]);
    }
    __syncthreads();
#pragma unroll
    for (int e = 0; e < 8; e++) {
        if ((m >> e) & 1u) {
            int rank = (int)__popcll(bal[e] & ((1ull << lane) - 1ull));
            if (w == 1) rank += s_w0[e];
            buckets[e * NPTS + baseoff[blockIdx.x * 8 + e] + rank] = n;
        }
    }
}

// ---------------- K3: per-expert MFMA SIREN; direct per-lane fragment build (no s_ft) ----------------
__global__ __launch_bounds__(256) void expert_kernel(
    const float* __restrict__ coords,
    const float* __restrict__ fw, const float* __restrict__ fb,
    const float* __restrict__ wl, const float* __restrict__ bl,
    const uint4* __restrict__ packA, const float* __restrict__ biasS,
    const int* __restrict__ counts, const int* __restrict__ buckets,
    float* __restrict__ out)
{
    const int e = blockIdx.x >> 11;            // CPE == 2048
    const int chunk = blockIdx.x & (CPE - 1);
    const int cnt = counts[e];
    const int base = chunk * 128;
    if (base >= cnt) return;

    __shared__ float s_b[192];
    __shared__ float s_wl[64];
    __shared__ float s_fw[192];
    __shared__ float s_fb[64];
    __shared__ float s_bl;

    const int t = threadIdx.x;
    if (t < 192) {
        s_b[t] = biasS[e * 192 + t];
        s_fw[t] = fw[t];
    }
    if (t < 64) {
        s_fb[t] = fb[t];
        s_wl[t] = wl[e * 64 + t];
    }
    if (t == 0) s_bl = bl[e];
    __syncthreads();

    const int lane = t & 63;
    const int wv = t >> 6;
    const int g = lane >> 4, c = lane & 15;
    const int i0 = base + wv * 32 + c;
    const int i1 = i0 + 16;
    const int id0 = (i0 < cnt) ? buckets[e * NPTS + i0] : -1;
    const int id1 = (i1 < cnt) ? buckets[e * NPTS + i1] : -1;

    // ---- direct per-lane B-fragment features: lane needs k = 16s + 4g + j (s=0..3, j=0..3) ----
    BFrag B0[2], B1[2];
    {
        const float a0 = (id0 >= 0) ? coords[id0 * 3] : 0.f;
        const float a1 = (id0 >= 0) ? coords[id0 * 3 + 1] : 0.f;
        const float a2 = (id0 >= 0) ? coords[id0 * 3 + 2] : 0.f;
        const float b0 = (id1 >= 0) ? coords[id1 * 3] : 0.f;
        const float b1 = (id1 >= 0) ? coords[id1 * 3 + 1] : 0.f;
        const float b2 = (id1 >= 0) ? coords[id1 * 3 + 2] : 0.f;
        float f0[4][4], f1[4][4];
#pragma unroll
        for (int s = 0; s < 4; s++) {
#pragma unroll
            for (int j = 0; j < 4; j++) {
                const int k = 16 * s + 4 * g + j;
                const float wx = s_fw[k * 3], wy = s_fw[k * 3 + 1], wz = s_fw[k * 3 + 2];
                const float bb = s_fb[k];
                f0[s][j] = bb + a0 * wx + a1 * wy + a2 * wz;
                f1[s][j] = bb + b0 * wx + b1 * wy + b2 * wz;
            }
        }
#pragma unroll
        for (int ks = 0; ks < 2; ks++) {
            B0[ks].u[0] = cpack(f0[2 * ks][0], f0[2 * ks][1]);
            B0[ks].u[1] = cpack(f0[2 * ks][2], f0[2 * ks][3]);
            B0[ks].u[2] = cpack(f0[2 * ks + 1][0], f0[2 * ks + 1][1]);
            B0[ks].u[3] = cpack(f0[2 * ks + 1][2], f0[2 * ks + 1][3]);
            B1[ks].u[0] = cpack(f1[2 * ks][0], f1[2 * ks][1]);
            B1[ks].u[1] = cpack(f1[2 * ks][2], f1[2 * ks][3]);
            B1[ks].u[2] = cpack(f1[2 * ks + 1][0], f1[2 * ks + 1][1]);
            B1[ks].u[3] = cpack(f1[2 * ks + 1][2], f1[2 * ks + 1][3]);
        }
    }

#pragma unroll 1
    for (int ell = 0; ell < 2; ell++) {
        f4v acc0[4], acc1[4];
#pragma unroll
        for (int tau = 0; tau < 4; tau++) {
            const float4 b = *(const float4*)&s_b[ell * 64 + tau * 16 + 4 * g];
            acc0[tau][0] = b.x; acc0[tau][1] = b.y; acc0[tau][2] = b.z; acc0[tau][3] = b.w;
            acc1[tau][0] = b.x; acc1[tau][1] = b.y; acc1[tau][2] = b.z; acc1[tau][3] = b.w;
        }
        const uint4* Ab = packA + (size_t)((e * 3 + ell) * 8) * 64 + lane;
#pragma unroll
        for (int tau = 0; tau < 4; tau++) {
            BFrag A0, A1;
            A0.q = Ab[(tau * 2 + 0) * 64];
            A1.q = Ab[(tau * 2 + 1) * 64];
            acc0[tau] = __builtin_amdgcn_mfma_f32_16x16x32_bf16(A0.s, B0[0].s, acc0[tau], 0, 0, 0);
            acc0[tau] = __builtin_amdgcn_mfma_f32_16x16x32_bf16(A1.s, B0[1].s, acc0[tau], 0, 0, 0);
            acc1[tau] = __builtin_amdgcn_mfma_f32_16x16x32_bf16(A0.s, B1[0].s, acc1[tau], 0, 0, 0);
            acc1[tau] = __builtin_amdgcn_mfma_f32_16x16x32_bf16(A1.s, B1[1].s, acc1[tau], 0, 0, 0);
        }
        // sin + repack: D registers become next layer's B fragments
#pragma unroll
        for (int ks = 0; ks < 2; ks++) {
            B0[ks].u[0] = cpack(sinrev(acc0[2 * ks][0]), sinrev(acc0[2 * ks][1]));
            B0[ks].u[1] = cpack(sinrev(acc0[2 * ks][2]), sinrev(acc0[2 * ks][3]));
            B0[ks].u[2] = cpack(sinrev(acc0[2 * ks + 1][0]), sinrev(acc0[2 * ks + 1][1]));
            B0[ks].u[3] = cpack(sinrev(acc0[2 * ks + 1][2]), sinrev(acc0[2 * ks + 1][3]));
            B1[ks].u[0] = cpack(sinrev(acc1[2 * ks][0]), sinrev(acc1[2 * ks][1]));
            B1[ks].u[1] = cpack(sinrev(acc1[2 * ks][2]), sinrev(acc1[2 * ks][3]));
            B1[ks].u[2] = cpack(sinrev(acc1[2 * ks + 1][0]), sinrev(acc1[2 * ks + 1][1]));
            B1[ks].u[3] = cpack(sinrev(acc1[2 * ks + 1][2]), sinrev(acc1[2 * ks + 1][3]));
        }
    }

    // ---- layer 2 + final dot ----
    {
        f4v acc0[4], acc1[4];
#pragma unroll
        for (int tau = 0; tau < 4; tau++) {
            const float4 b = *(const float4*)&s_b[2 * 64 + tau * 16 + 4 * g];
            acc0[tau][0] = b.x; acc0[tau][1] = b.y; acc0[tau][2] = b.z; acc0[tau][3] = b.w;
            acc1[tau][0] = b.x; acc1[tau][1] = b.y; acc1[tau][2] = b.z; acc1[tau][3] = b.w;
        }
        const uint4* Ab = packA + (size_t)((e * 3 + 2) * 8) * 64 + lane;
#pragma unroll
        for (int tau = 0; tau < 4; tau++) {
            BFrag A0, A1;
            A0.q = Ab[(tau * 2 + 0) * 64];
            A1.q = Ab[(tau * 2 + 1) * 64];
            acc0[tau] = __builtin_amdgcn_mfma_f32_16x16x32_bf16(A0.s, B0[0].s, acc0[tau], 0, 0, 0);
            acc0[tau] = __builtin_amdgcn_mfma_f32_16x16x32_bf16(A1.s, B0[1].s, acc0[tau], 0, 0, 0);
            acc1[tau] = __builtin_amdgcn_mfma_f32_16x16x32_bf16(A0.s, B1[0].s, acc1[tau], 0, 0, 0);
            acc1[tau] = __builtin_amdgcn_mfma_f32_16x16x32_bf16(A1.s, B1[1].s, acc1[tau], 0, 0, 0);
        }
        float px0 = 0.f, px1 = 0.f;
#pragma unroll
        for (int tau = 0; tau < 4; tau++) {
            const float4 w = *(const float4*)&s_wl[tau * 16 + 4 * g];
            px0 += sinrev(acc0[tau][0]) * w.x + sinrev(acc0[tau][1]) * w.y
                 + sinrev(acc0[tau][2]) * w.z + sinrev(acc0[tau][3]) * w.w;
            px1 += sinrev(acc1[tau][0]) * w.x + sinrev(acc1[tau][1]) * w.y
                 + sinrev(acc1[tau][2]) * w.z + sinrev(acc1[tau][3]) * w.w;
        }
        px0 += __shfl_xor(px0, 16, 64); px0 += __shfl_xor(px0, 32, 64);
        px1 += __shfl_xor(px1, 16, 64); px1 += __shfl_xor(px1, 32, 64);
        if (g == 0) {
            if (id0 >= 0) atomicAdd(&out[id0], px0 + s_bl);
            if (id1 >= 0) atomicAdd(&out[id1], px1 + s_bl);
        }
    }
}

extern "C" void kernel_launch(void* const* d_in, const int* in_sizes, int n_in,
                              void* d_out, int out_size, void* d_ws, size_t ws_size,
                              hipStream_t stream)
{
    const float* coords = (const float*)d_in[0];
    const float* fw  = (const float*)d_in[1];
    const float* fb  = (const float*)d_in[2];
    const float* gw1 = (const float*)d_in[3];
    const float* gb1 = (const float*)d_in[4];
    const float* lng = (const float*)d_in[5];
    const float* lnb = (const float*)d_in[6];
    const float* gw2 = (const float*)d_in[7];
    const float* gb2 = (const float*)d_in[8];
    const float* we0 = (const float*)d_in[9];
    const float* be0 = (const float*)d_in[10];
    const float* wm  = (const float*)d_in[11];
    const float* bm  = (const float*)d_in[12];
    const float* wl  = (const float*)d_in[13];
    const float* bl  = (const float*)d_in[14];
    float* out = (float*)d_out;

    char* ws = (char*)d_ws;
    int* counts           = (int*)ws;                        // 64
    int* buckets          = (int*)(ws + 64);                 // 8*NPTS*4 = 8388608
    uint4* packA          = (uint4*)(ws + 8388672);          // 196608
    float* biasS          = (float*)(ws + 8585280);          // 6144
    int* blkcnt           = (int*)(ws + 8591424);            // 65536
    int* baseoff          = (int*)(ws + 8656960);            // 65536
    unsigned char* sel    = (unsigned char*)(ws + 8722496);  // 262144
    uint4* packGW1H       = (uint4*)(ws + 8984640);          // 8192
    uint4* packGW1L       = (uint4*)(ws + 8992832);          // 8192
    uint4* packGW2H       = (uint4*)(ws + 9001024);          // 2048
    uint4* packGW2L       = (uint4*)(ws + 9003072);          // 2048
    int* reflist          = (int*)(ws + 9005120);            // 1048576
    int* refcnt           = (int*)(ws + 10053696);           // 64

    hipMemsetAsync(refcnt, 0, 64, stream);

    prep_kernel<<<57, 256, 0, stream>>>(we0, be0, wm, bm, gw1, gw2, packA, biasS,
                                        packGW1H, packGW1L, packGW2H, packGW2L);
    gate_kernel<<<GGRID, 512, 0, stream>>>(coords, fw, fb, gb1, lng, lnb, gb2,
                                           packGW1H, packGW1L, packGW2H, packGW2L,
                                           sel, blkcnt, reflist, refcnt);
    refine_kernel<<<128, 256, 0, stream>>>(coords, fw, fb, gw1, gb1, lng, lnb, gw2, gb2,
                                           reflist, refcnt, sel, blkcnt);
    scan_kernel<<<8, 256, 0, stream>>>(blkcnt, baseoff, counts);
    scatter_kernel<<<GBLK, 128, 0, stream>>>(sel, baseoff, counts, buckets, out);
    expert_kernel<<<8 * CPE, 256, 0, stream>>>(coords, fw, fb, wl, bl, packA, biasS,
                                               counts, buckets, out);
}

// Round 13
// 93.351 us; speedup vs baseline: 2.2952x; 1.1176x over previous
//
#include <hip/hip_runtime.h>
#include <math.h>

#define NPTS 262144
#define GBLK (NPTS / 128)     // 2048 gate blocks / 128-pt groups
#define CPE  2048             // chunks per expert in expert grid
#define TAU  0.01f            // refine margin threshold (logit units)

typedef float f4v __attribute__((ext_vector_type(4)));
typedef short s8v __attribute__((ext_vector_type(8)));

// manual RNE (prep only; identical rounding to HW cvt)
static __device__ __forceinline__ unsigned short f2bf(float f) {
    unsigned u = __float_as_uint(f);
    u += 0x7fffu + ((u >> 16) & 1u);
    return (unsigned short)(u >> 16);
}
// HW bf16 convert (clang lowers paired fptrunc to v_cvt_pk_bf16_f32, RNE)
static __device__ __forceinline__ unsigned short f2bf_hw(float f) {
    __bf16 b = (__bf16)f;
    unsigned short u;
    __builtin_memcpy(&u, &b, 2);
    return u;
}
static __device__ __forceinline__ float bf2f(unsigned short h) {
    return __uint_as_float(((unsigned)h) << 16);
}
static __device__ __forceinline__ unsigned pk2b(unsigned short lo, unsigned short hi) {
    return ((unsigned)hi << 16) | (unsigned)lo;
}
static __device__ __forceinline__ unsigned cpack(float lo, float hi) {
    return pk2b(f2bf_hw(lo), f2bf_hw(hi));
}
static __device__ __forceinline__ float sinrev(float x) {   // sin(2*pi*x)
    return __builtin_amdgcn_sinf(x);
}

union BFrag { uint4 q; unsigned u[4]; s8v s; };

// ---------------- prep: expert A-frags + biases + gate gw2 packs + folded M1/b1' + refcnt=0 ----------------
__global__ __launch_bounds__(256) void prep_kernel(
    const float* __restrict__ we0, const float* __restrict__ be0,
    const float* __restrict__ wm, const float* __restrict__ bm,
    const float* __restrict__ gw1, const float* __restrict__ gw2,
    const float* __restrict__ fw, const float* __restrict__ fb,
    const float* __restrict__ gb1,
    uint4* __restrict__ packA, float* __restrict__ biasS,
    uint4* __restrict__ packGW2H, uint4* __restrict__ packGW2L,
    float* __restrict__ M1, float* __restrict__ b1p, int* __restrict__ refcnt)
{
    const int idx = blockIdx.x * 256 + threadIdx.x;
    const float PI2I = 0.15915494309189535f;
    if (idx < 12288) {
        const int l = idx & 63;
        const int fr = (idx >> 6) & 7;
        const int grp = idx >> 9;            // e*3 + ell
        const int e = grp / 3, ell = grp % 3;
        const int tau = fr >> 1, ks = fr & 1;
        const int g = l >> 4, m = l & 15;
        const int row = tau * 16 + m;
        const float scale = (ell == 0) ? (22.5f + 45.0f * (float)e) * PI2I : 30.0f * PI2I;
        const float* W = (ell == 0) ? (we0 + e * 4096) : (wm + ((ell - 1) * 8 + e) * 4096);
        unsigned short v[8];
#pragma unroll
        for (int i = 0; i < 8; i++) {
            const int k = 32 * ks + 4 * g + (i < 4 ? i : i + 12);
            v[i] = f2bf(W[row * 64 + k] * scale);
        }
        uint4 q;
        q.x = pk2b(v[0], v[1]); q.y = pk2b(v[2], v[3]);
        q.z = pk2b(v[4], v[5]); q.w = pk2b(v[6], v[7]);
        packA[idx] = q;
    } else if (idx < 13824) {
        const int j = idx - 12288;           // e*192 + ell*64 + r
        const int r = j & 63;
        const int grp = j >> 6;
        const int e = grp / 3, ell = grp % 3;
        const float scale = (ell == 0) ? (22.5f + 45.0f * (float)e) * PI2I : 30.0f * PI2I;
        const float b = (ell == 0) ? be0[e * 64 + r] : bm[((ell - 1) * 8 + e) * 64 + r];
        biasS[j] = b * scale;
    } else if (idx < 13952) {
        // gate gw2 hi/lo A-frags: rows 0..7 = gw2, rows 8..15 = 0; 2 frags (ks) x 64 lanes
        const int j = idx - 13824;           // 0..127
        const int l = j & 63;
        const int ks = j >> 6;
        const int g = l >> 4;
        const int row = l & 15;
        unsigned short vh[8], vl[8];
#pragma unroll
        for (int i = 0; i < 8; i++) {
            const int k = 32 * ks + 4 * g + (i < 4 ? i : i + 12);
            const float x = (row < 8) ? gw2[row * 64 + k] : 0.f;
            const unsigned short h = f2bf(x);
            vh[i] = h;
            vl[i] = f2bf(x - bf2f(h));
        }
        uint4 qh, ql;
        qh.x = pk2b(vh[0], vh[1]); qh.y = pk2b(vh[2], vh[3]);
        qh.z = pk2b(vh[4], vh[5]); qh.w = pk2b(vh[6], vh[7]);
        ql.x = pk2b(vl[0], vl[1]); ql.y = pk2b(vl[2], vl[3]);
        ql.z = pk2b(vl[4], vl[5]); ql.w = pk2b(vl[6], vl[7]);
        packGW2H[j] = qh; packGW2L[j] = ql;
    } else if (idx < 14144) {
        // M1 = gw1 @ fw  (64x3), fp64 accumulate
        const int m = idx - 13952;           // 0..191
        const int r = m / 3, d = m % 3;
        double s = 0.0;
        for (int j = 0; j < 64; j++) s += (double)gw1[r * 64 + j] * (double)fw[j * 3 + d];
        M1[m] = (float)s;
    } else if (idx < 14208) {
        // b1' = gw1 @ fb + gb1
        const int r = idx - 14144;           // 0..63
        double s = (double)gb1[r];
        for (int j = 0; j < 64; j++) s += (double)gw1[r * 64 + j] * (double)fb[j];
        b1p[r] = (float)s;
    } else if (idx == 14208) {
        *refcnt = 0;
    }
}

// ---------------- K1: gate — folded stage-1 (3 FMA/row) + MFMA stage-2 (hi/lo) ----------------
// 256 threads = 4 waves x 32 points = 128 points per block.
__global__ __launch_bounds__(256) void gate_kernel(
    const float* __restrict__ coords,
    const float* __restrict__ M1, const float* __restrict__ b1p,
    const float* __restrict__ lng, const float* __restrict__ lnb,
    const float* __restrict__ gb2,
    const uint4* __restrict__ packGW2H, const uint4* __restrict__ packGW2L,
    unsigned char* __restrict__ sel, int* __restrict__ blkcnt,
    int* __restrict__ reflist, int* __restrict__ refcnt)
{
    __shared__ float s_M1[192], s_b1p[64], s_lng[64], s_lnb[64], s_gb2[8];
    __shared__ uint4 sW2H[128], sW2L[128];      // 4 KB
    __shared__ int s_cnt[8];
    const int t = threadIdx.x;
    if (t < 128) { sW2H[t] = packGW2H[t]; sW2L[t] = packGW2L[t]; }
    if (t < 192) s_M1[t] = M1[t];
    if (t < 64) { s_b1p[t] = b1p[t]; s_lng[t] = lng[t]; s_lnb[t] = lnb[t]; }
    if (t < 8) { s_gb2[t] = gb2[t]; s_cnt[t] = 0; }
    __syncthreads();

    const int lane = t & 63;
    const int wv = t >> 6;
    const int g = lane >> 4, c = lane & 15;
    const int n0 = blockIdx.x * 128 + wv * 32 + c;
    const int n1 = n0 + 16;

    const float a0 = coords[n0 * 3], a1 = coords[n0 * 3 + 1], a2 = coords[n0 * 3 + 2];
    const float b0 = coords[n1 * 3], b1 = coords[n1 * 3 + 1], b2 = coords[n1 * 3 + 2];

    // ---- g rows directly: r = 16*tau + 4*g + j, 3 FMA each ----
    float ga[16], gb[16];
#pragma unroll
    for (int i = 0; i < 16; i++) {
        const int r = ((i >> 2) << 4) + 4 * g + (i & 3);
        const float m0 = s_M1[r * 3], m1 = s_M1[r * 3 + 1], m2 = s_M1[r * 3 + 2];
        const float bb = s_b1p[r];
        ga[i] = bb + a0 * m0 + a1 * m1 + a2 * m2;
        gb[i] = bb + b0 * m0 + b1 * m1 + b2 * m2;
    }

    // ---- LayerNorm over 64 rows (cross-lane over g groups) ----
    float s1a = 0.f, s1b = 0.f;
#pragma unroll
    for (int i = 0; i < 16; i++) { s1a += ga[i]; s1b += gb[i]; }
    s1a += __shfl_xor(s1a, 16, 64); s1a += __shfl_xor(s1a, 32, 64);
    s1b += __shfl_xor(s1b, 16, 64); s1b += __shfl_xor(s1b, 32, 64);
    const float mu0 = s1a * (1.f / 64.f), mu1 = s1b * (1.f / 64.f);
    float s2a = 0.f, s2b = 0.f;
#pragma unroll
    for (int i = 0; i < 16; i++) {
        const float d0 = ga[i] - mu0; s2a += d0 * d0;
        const float d1 = gb[i] - mu1; s2b += d1 * d1;
    }
    s2a += __shfl_xor(s2a, 16, 64); s2a += __shfl_xor(s2a, 32, 64);
    s2b += __shfl_xor(s2b, 16, 64); s2b += __shfl_xor(s2b, 32, 64);
    const float rs0 = rsqrtf(s2a * (1.f / 64.f) + 1e-5f);
    const float rs1 = rsqrtf(s2b * (1.f / 64.f) + 1e-5f);

    // ---- gn + hi/lo split + pack into B-frags ----
    BFrag Gh0[2], Gl0[2], Gh1[2], Gl1[2];
#pragma unroll
    for (int ks = 0; ks < 2; ks++) {
#pragma unroll
        for (int q = 0; q < 4; q++) {
            const int i0 = ks * 8 + 2 * q, i1 = i0 + 1;
            const int r0 = ((i0 >> 2) << 4) + 4 * g + (i0 & 3);
            const int r1 = ((i1 >> 2) << 4) + 4 * g + (i1 & 3);
            const float gnA0 = (ga[i0] - mu0) * rs0 * s_lng[r0] + s_lnb[r0];
            const float gnA1 = (ga[i1] - mu0) * rs0 * s_lng[r1] + s_lnb[r1];
            const float gnB0 = (gb[i0] - mu1) * rs1 * s_lng[r0] + s_lnb[r0];
            const float gnB1 = (gb[i1] - mu1) * rs1 * s_lng[r1] + s_lnb[r1];
            const unsigned short hA0 = f2bf_hw(gnA0), hA1 = f2bf_hw(gnA1);
            const unsigned short hB0 = f2bf_hw(gnB0), hB1 = f2bf_hw(gnB1);
            Gh0[ks].u[q] = pk2b(hA0, hA1);
            Gl0[ks].u[q] = cpack(gnA0 - bf2f(hA0), gnA1 - bf2f(hA1));
            Gh1[ks].u[q] = pk2b(hB0, hB1);
            Gl1[ks].u[q] = cpack(gnB0 - bf2f(hB0), gnB1 - bf2f(hB1));
        }
    }

    // ---- logits = gw2 @ gn via 3-term MFMA (two independent chains) ----
    f4v lacc0 = {0.f, 0.f, 0.f, 0.f}, lacc1 = {0.f, 0.f, 0.f, 0.f};
    {
        BFrag W0, W1, V0, V1;
        W0.q = sW2H[0 * 64 + lane]; W1.q = sW2H[1 * 64 + lane];
        V0.q = sW2L[0 * 64 + lane]; V1.q = sW2L[1 * 64 + lane];
        lacc0 = __builtin_amdgcn_mfma_f32_16x16x32_bf16(W0.s, Gh0[0].s, lacc0, 0, 0, 0);
        lacc1 = __builtin_amdgcn_mfma_f32_16x16x32_bf16(W0.s, Gh1[0].s, lacc1, 0, 0, 0);
        lacc0 = __builtin_amdgcn_mfma_f32_16x16x32_bf16(W1.s, Gh0[1].s, lacc0, 0, 0, 0);
        lacc1 = __builtin_amdgcn_mfma_f32_16x16x32_bf16(W1.s, Gh1[1].s, lacc1, 0, 0, 0);
        lacc0 = __builtin_amdgcn_mfma_f32_16x16x32_bf16(W0.s, Gl0[0].s, lacc0, 0, 0, 0);
        lacc1 = __builtin_amdgcn_mfma_f32_16x16x32_bf16(W0.s, Gl1[0].s, lacc1, 0, 0, 0);
        lacc0 = __builtin_amdgcn_mfma_f32_16x16x32_bf16(W1.s, Gl0[1].s, lacc0, 0, 0, 0);
        lacc1 = __builtin_amdgcn_mfma_f32_16x16x32_bf16(W1.s, Gl1[1].s, lacc1, 0, 0, 0);
        lacc0 = __builtin_amdgcn_mfma_f32_16x16x32_bf16(V0.s, Gh0[0].s, lacc0, 0, 0, 0);
        lacc1 = __builtin_amdgcn_mfma_f32_16x16x32_bf16(V0.s, Gh1[0].s, lacc1, 0, 0, 0);
        lacc0 = __builtin_amdgcn_mfma_f32_16x16x32_bf16(V1.s, Gh0[1].s, lacc0, 0, 0, 0);
        lacc1 = __builtin_amdgcn_mfma_f32_16x16x32_bf16(V1.s, Gh1[1].s, lacc1, 0, 0, 0);
    }

    float logit0[8], logit1[8];
#pragma unroll
    for (int j = 0; j < 4; j++) {
        const float o0 = __shfl_xor(lacc0[j], 16, 64);
        const float o1 = __shfl_xor(lacc1[j], 16, 64);
        logit0[j] = lacc0[j] + s_gb2[j];
        logit0[4 + j] = o0 + s_gb2[4 + j];
        logit1[j] = lacc1[j] + s_gb2[j];
        logit1[4 + j] = o1 + s_gb2[4 + j];
    }

    // ---- top-2 + margin flag (per point) ----
    unsigned mbits0 = 0, mbits1 = 0;
    bool flg0, flg1;
    {
        float m1 = logit0[0]; int i1 = 0;
#pragma unroll
        for (int e = 1; e < 8; e++) if (logit0[e] > m1) { m1 = logit0[e]; i1 = e; }
        float m2 = -INFINITY; int i2 = -1;
#pragma unroll
        for (int e = 0; e < 8; e++) if (e != i1 && logit0[e] > m2) { m2 = logit0[e]; i2 = e; }
        float m3 = -INFINITY;
#pragma unroll
        for (int e = 0; e < 8; e++) if (e != i1 && e != i2 && logit0[e] > m3) m3 = logit0[e];
#pragma unroll
        for (int e = 0; e < 8; e++) if (logit0[e] >= m2) mbits0 |= 1u << e;
        flg0 = (m2 - m3 < TAU);
    }
    {
        float m1 = logit1[0]; int i1 = 0;
#pragma unroll
        for (int e = 1; e < 8; e++) if (logit1[e] > m1) { m1 = logit1[e]; i1 = e; }
        float m2 = -INFINITY; int i2 = -1;
#pragma unroll
        for (int e = 0; e < 8; e++) if (e != i1 && logit1[e] > m2) { m2 = logit1[e]; i2 = e; }
        float m3 = -INFINITY;
#pragma unroll
        for (int e = 0; e < 8; e++) if (e != i1 && e != i2 && logit1[e] > m3) m3 = logit1[e];
#pragma unroll
        for (int e = 0; e < 8; e++) if (logit1[e] >= m2) mbits1 |= 1u << e;
        flg1 = (m2 - m3 < TAU);
    }

    const bool active = (g == 0);
    if (active) { sel[n0] = (unsigned char)mbits0; sel[n1] = (unsigned char)mbits1; }

#pragma unroll
    for (int e = 0; e < 8; e++) {
        const unsigned long long bal0 = __ballot(active && ((mbits0 >> e) & 1u));
        const unsigned long long bal1 = __ballot(active && ((mbits1 >> e) & 1u));
        if (lane == 0) atomicAdd(&s_cnt[e], (int)(__popcll(bal0) + __popcll(bal1)));
    }
    {
        const unsigned long long bal0 = __ballot(active && flg0);
        const unsigned long long bal1 = __ballot(active && flg1);
        const int p0 = (int)__popcll(bal0);
        int pos0 = 0;
        if (lane == 0 && (bal0 | bal1)) pos0 = atomicAdd(refcnt, p0 + (int)__popcll(bal1));
        pos0 = __shfl(pos0, 0, 64);
        if (active && flg0) {
            const int rank = (int)__popcll(bal0 & ((1ull << lane) - 1ull));
            reflist[pos0 + rank] = n0;
        }
        if (active && flg1) {
            const int rank = p0 + (int)__popcll(bal1 & ((1ull << lane) - 1ull));
            reflist[pos0 + rank] = n1;
        }
    }
    __syncthreads();
    if (t < 8) blkcnt[blockIdx.x * 8 + t] = s_cnt[t];
}

// ---------------- K1.25: exact-fp32 refine (reference op order), one wave per point ----------------
__global__ __launch_bounds__(256) void refine_kernel(
    const float* __restrict__ coords,
    const float* __restrict__ fw, const float* __restrict__ fb,
    const float* __restrict__ gw1, const float* __restrict__ gb1,
    const float* __restrict__ lng, const float* __restrict__ lnb,
    const float* __restrict__ gw2, const float* __restrict__ gb2,
    const int* __restrict__ reflist, const int* __restrict__ refcnt,
    unsigned char* __restrict__ sel, int* __restrict__ blkcnt)
{
    const int R = *refcnt;
    if (blockIdx.x * 4 >= R) return;            // uniform early exit, before any barrier

    __shared__ float s_gw1t[64 * 65];           // transposed + pad
    __shared__ float s_gw2[512];
    __shared__ float s_fw[192], s_fb[64], s_gb1[64], s_lng[64], s_lnb[64], s_gb2[8];
    __shared__ float s_f[4][64];

    const int t = threadIdx.x;
    for (int i = t; i < 4096; i += 256) s_gw1t[(i & 63) * 65 + (i >> 6)] = gw1[i];
    for (int i = t; i < 512; i += 256) s_gw2[i] = gw2[i];
    if (t < 192) s_fw[t] = fw[t];
    if (t < 64) { s_fb[t] = fb[t]; s_gb1[t] = gb1[t]; s_lng[t] = lng[t]; s_lnb[t] = lnb[t]; }
    if (t < 8) s_gb2[t] = gb2[t];
    __syncthreads();

    const int wv = t >> 6, lane = t & 63;
    for (int idx = blockIdx.x * 4 + wv; idx < R; idx += gridDim.x * 4) {
        const int n = reflist[idx];
        const float c0 = coords[n * 3], c1 = coords[n * 3 + 1], c2 = coords[n * 3 + 2];
        const float fr = s_fb[lane] + c0 * s_fw[lane * 3] + c1 * s_fw[lane * 3 + 1]
                       + c2 * s_fw[lane * 3 + 2];
        s_f[wv][lane] = fr;
        float a = s_gb1[lane];
#pragma unroll
        for (int k = 0; k < 64; k++)
            a += s_f[wv][k] * s_gw1t[k * 65 + lane];
        float mu = a;
#pragma unroll
        for (int d = 1; d < 64; d <<= 1) mu += __shfl_xor(mu, d, 64);
        mu *= (1.f / 64.f);
        const float dv = a - mu;
        float v = dv * dv;
#pragma unroll
        for (int d = 1; d < 64; d <<= 1) v += __shfl_xor(v, d, 64);
        const float rs = rsqrtf(v * (1.f / 64.f) + 1e-5f);
        const float gn = dv * rs * s_lng[lane] + s_lnb[lane];
        float lp[8];
#pragma unroll
        for (int e = 0; e < 8; e++) lp[e] = gn * s_gw2[e * 64 + lane];
#pragma unroll
        for (int e = 0; e < 8; e++) {
#pragma unroll
            for (int d = 1; d < 64; d <<= 1) lp[e] += __shfl_xor(lp[e], d, 64);
            lp[e] += s_gb2[e];
        }
        if (lane == 0) {
            float m1 = lp[0]; int i1 = 0;
#pragma unroll
            for (int e = 1; e < 8; e++) if (lp[e] > m1) { m1 = lp[e]; i1 = e; }
            float m2 = -INFINITY;
#pragma unroll
            for (int e = 0; e < 8; e++) if (e != i1 && lp[e] > m2) m2 = lp[e];
            unsigned mbits = 0;
#pragma unroll
            for (int e = 0; e < 8; e++) if (lp[e] >= m2) mbits |= 1u << e;
            const unsigned old = sel[n];
            if (mbits != old) {
                sel[n] = (unsigned char)mbits;
                const int b = n >> 7;
#pragma unroll
                for (int e = 0; e < 8; e++) {
                    const int was = (old >> e) & 1, now = (mbits >> e) & 1;
                    if (was != now) atomicAdd(&blkcnt[b * 8 + e], now - was);
                }
            }
        }
    }
}

// ---------------- K1.5: scan, one block per expert ----------------
__global__ __launch_bounds__(256) void scan_kernel(
    const int* __restrict__ blkcnt, int* __restrict__ baseoff,
    int* __restrict__ counts)
{
    const int e = blockIdx.x;          // 0..7
    const int t = threadIdx.x;         // each thread: 8 consecutive 128-pt groups
    const int lane = t & 63, wv = t >> 6;
    __shared__ int s_w[4];

    int v[8]; int sum = 0;
#pragma unroll
    for (int i = 0; i < 8; i++) { v[i] = blkcnt[(t * 8 + i) * 8 + e]; sum += v[i]; }
    int incl = sum;
#pragma unroll
    for (int d = 1; d < 64; d <<= 1) {
        const int x = __shfl_up(incl, d, 64);
        if (lane >= d) incl += x;
    }
    if (lane == 63) s_w[wv] = incl;
    __syncthreads();
    int woff = 0;
#pragma unroll
    for (int i = 0; i < 4; i++) if (i < wv) woff += s_w[i];
    int run = woff + incl - sum;
#pragma unroll
    for (int i = 0; i < 8; i++) { baseoff[(t * 8 + i) * 8 + e] = run; run += v[i]; }
    if (t == 255) counts[e] = run;
}

// ---------------- K2: scatter + zero out[] + aux ----------------
__global__ __launch_bounds__(128) void scatter_kernel(
    const unsigned char* __restrict__ sel, const int* __restrict__ baseoff,
    const int* __restrict__ counts, int* __restrict__ buckets, float* __restrict__ out)
{
    __shared__ int s_w0[8];
    const int t = threadIdx.x;
    const int n = blockIdx.x * 128 + t;
    out[n] = 0.f;
    if (blockIdx.x == 0 && t == 0) {
        double s = 0.0;
        for (int e = 0; e < 8; e++) { const double c = (double)counts[e]; s += c * c; }
        out[NPTS] = (float)(8.0 * s / ((double)NPTS * (double)NPTS));
    }
    const unsigned m = sel[n];
    const int w = t >> 6, lane = t & 63;
    unsigned long long bal[8];
#pragma unroll
    for (int e = 0; e < 8; e++) {
        bal[e] = __ballot((m >> e) & 1u);
        if (w == 0 && lane == 0) s_w0[e] = (int)__popcll(bal[e]);
    }
    __syncthreads();
#pragma unroll
    for (int e = 0; e < 8; e++) {
        if ((m >> e) & 1u) {
            int rank = (int)__popcll(bal[e] & ((1ull << lane) - 1ull));
            if (w == 1) rank += s_w0[e];
            buckets[e * NPTS + baseoff[blockIdx.x * 8 + e] + rank] = n;
        }
    }
}

// ---------------- K3: per-expert MFMA SIREN; direct per-lane fragment build ----------------
__global__ __launch_bounds__(256) void expert_kernel(
    const float* __restrict__ coords,
    const float* __restrict__ fw, const float* __restrict__ fb,
    const float* __restrict__ wl, const float* __restrict__ bl,
    const uint4* __restrict__ packA, const float* __restrict__ biasS,
    const int* __restrict__ counts, const int* __restrict__ buckets,
    float* __restrict__ out)
{
    const int e = blockIdx.x >> 11;            // CPE == 2048
    const int chunk = blockIdx.x & (CPE - 1);
    const int cnt = counts[e];
    const int base = chunk * 128;
    if (base >= cnt) return;

    __shared__ float s_b[192];
    __shared__ float s_wl[64];
    __shared__ float s_fw[192];
    __shared__ float s_fb[64];
    __shared__ float s_bl;

    const int t = threadIdx.x;
    if (t < 192) {
        s_b[t] = biasS[e * 192 + t];
        s_fw[t] = fw[t];
    }
    if (t < 64) {
        s_fb[t] = fb[t];
        s_wl[t] = wl[e * 64 + t];
    }
    if (t == 0) s_bl = bl[e];
    __syncthreads();

    const int lane = t & 63;
    const int wv = t >> 6;
    const int g = lane >> 4, c = lane & 15;
    const int i0 = base + wv * 32 + c;
    const int i1 = i0 + 16;
    const int id0 = (i0 < cnt) ? buckets[e * NPTS + i0] : -1;
    const int id1 = (i1 < cnt) ? buckets[e * NPTS + i1] : -1;

    BFrag B0[2], B1[2];
    {
        const float a0 = (id0 >= 0) ? coords[id0 * 3] : 0.f;
        const float a1 = (id0 >= 0) ? coords[id0 * 3 + 1] : 0.f;
        const float a2 = (id0 >= 0) ? coords[id0 * 3 + 2] : 0.f;
        const float b0 = (id1 >= 0) ? coords[id1 * 3] : 0.f;
        const float b1 = (id1 >= 0) ? coords[id1 * 3 + 1] : 0.f;
        const float b2 = (id1 >= 0) ? coords[id1 * 3 + 2] : 0.f;
        float f0[4][4], f1[4][4];
#pragma unroll
        for (int s = 0; s < 4; s++) {
#pragma unroll
            for (int j = 0; j < 4; j++) {
                const int k = 16 * s + 4 * g + j;
                const float wx = s_fw[k * 3], wy = s_fw[k * 3 + 1], wz = s_fw[k * 3 + 2];
                const float bb = s_fb[k];
                f0[s][j] = bb + a0 * wx + a1 * wy + a2 * wz;
                f1[s][j] = bb + b0 * wx + b1 * wy + b2 * wz;
            }
        }
#pragma unroll
        for (int ks = 0; ks < 2; ks++) {
            B0[ks].u[0] = cpack(f0[2 * ks][0], f0[2 * ks][1]);
            B0[ks].u[1] = cpack(f0[2 * ks][2], f0[2 * ks][3]);
            B0[ks].u[2] = cpack(f0[2 * ks + 1][0], f0[2 * ks + 1][1]);
            B0[ks].u[3] = cpack(f0[2 * ks + 1][2], f0[2 * ks + 1][3]);
            B1[ks].u[0] = cpack(f1[2 * ks][0], f1[2 * ks][1]);
            B1[ks].u[1] = cpack(f1[2 * ks][2], f1[2 * ks][3]);
            B1[ks].u[2] = cpack(f1[2 * ks + 1][0], f1[2 * ks + 1][1]);
            B1[ks].u[3] = cpack(f1[2 * ks + 1][2], f1[2 * ks + 1][3]);
        }
    }

#pragma unroll 1
    for (int ell = 0; ell < 2; ell++) {
        f4v acc0[4], acc1[4];
#pragma unroll
        for (int tau = 0; tau < 4; tau++) {
            const float4 b = *(const float4*)&s_b[ell * 64 + tau * 16 + 4 * g];
            acc0[tau][0] = b.x; acc0[tau][1] = b.y; acc0[tau][2] = b.z; acc0[tau][3] = b.w;
            acc1[tau][0] = b.x; acc1[tau][1] = b.y; acc1[tau][2] = b.z; acc1[tau][3] = b.w;
        }
        const uint4* Ab = packA + (size_t)((e * 3 + ell) * 8) * 64 + lane;
#pragma unroll
        for (int tau = 0; tau < 4; tau++) {
            BFrag A0, A1;
            A0.q = Ab[(tau * 2 + 0) * 64];
            A1.q = Ab[(tau * 2 + 1) * 64];
            acc0[tau] = __builtin_amdgcn_mfma_f32_16x16x32_bf16(A0.s, B0[0].s, acc0[tau], 0, 0, 0);
            acc0[tau] = __builtin_amdgcn_mfma_f32_16x16x32_bf16(A1.s, B0[1].s, acc0[tau], 0, 0, 0);
            acc1[tau] = __builtin_amdgcn_mfma_f32_16x16x32_bf16(A0.s, B1[0].s, acc1[tau], 0, 0, 0);
            acc1[tau] = __builtin_amdgcn_mfma_f32_16x16x32_bf16(A1.s, B1[1].s, acc1[tau], 0, 0, 0);
        }
#pragma unroll
        for (int ks = 0; ks < 2; ks++) {
            B0[ks].u[0] = cpack(sinrev(acc0[2 * ks][0]), sinrev(acc0[2 * ks][1]));
            B0[ks].u[1] = cpack(sinrev(acc0[2 * ks][2]), sinrev(acc0[2 * ks][3]));
            B0[ks].u[2] = cpack(sinrev(acc0[2 * ks + 1][0]), sinrev(acc0[2 * ks + 1][1]));
            B0[ks].u[3] = cpack(sinrev(acc0[2 * ks + 1][2]), sinrev(acc0[2 * ks + 1][3]));
            B1[ks].u[0] = cpack(sinrev(acc1[2 * ks][0]), sinrev(acc1[2 * ks][1]));
            B1[ks].u[1] = cpack(sinrev(acc1[2 * ks][2]), sinrev(acc1[2 * ks][3]));
            B1[ks].u[2] = cpack(sinrev(acc1[2 * ks + 1][0]), sinrev(acc1[2 * ks + 1][1]));
            B1[ks].u[3] = cpack(sinrev(acc1[2 * ks + 1][2]), sinrev(acc1[2 * ks + 1][3]));
        }
    }

    {
        f4v acc0[4], acc1[4];
#pragma unroll
        for (int tau = 0; tau < 4; tau++) {
            const float4 b = *(const float4*)&s_b[2 * 64 + tau * 16 + 4 * g];
            acc0[tau][0] = b.x; acc0[tau][1] = b.y; acc0[tau][2] = b.z; acc0[tau][3] = b.w;
            acc1[tau][0] = b.x; acc1[tau][1] = b.y; acc1[tau][2] = b.z; acc1[tau][3] = b.w;
        }
        const uint4* Ab = packA + (size_t)((e * 3 + 2) * 8) * 64 + lane;
#pragma unroll
        for (int tau = 0; tau < 4; tau++) {
            BFrag A0, A1;
            A0.q = Ab[(tau * 2 + 0) * 64];
            A1.q = Ab[(tau * 2 + 1) * 64];
            acc0[tau] = __builtin_amdgcn_mfma_f32_16x16x32_bf16(A0.s, B0[0].s, acc0[tau], 0, 0, 0);
            acc0[tau] = __builtin_amdgcn_mfma_f32_16x16x32_bf16(A1.s, B0[1].s, acc0[tau], 0, 0, 0);
            acc1[tau] = __builtin_amdgcn_mfma_f32_16x16x32_bf16(A0.s, B1[0].s, acc1[tau], 0, 0, 0);
            acc1[tau] = __builtin_amdgcn_mfma_f32_16x16x32_bf16(A1.s, B1[1].s, acc1[tau], 0, 0, 0);
        }
        float px0 = 0.f, px1 = 0.f;
#pragma unroll
        for (int tau = 0; tau < 4; tau++) {
            const float4 w = *(const float4*)&s_wl[tau * 16 + 4 * g];
            px0 += sinrev(acc0[tau][0]) * w.x + sinrev(acc0[tau][1]) * w.y
                 + sinrev(acc0[tau][2]) * w.z + sinrev(acc0[tau][3]) * w.w;
            px1 += sinrev(acc1[tau][0]) * w.x + sinrev(acc1[tau][1]) * w.y
                 + sinrev(acc1[tau][2]) * w.z + sinrev(acc1[tau][3]) * w.w;
        }
        px0 += __shfl_xor(px0, 16, 64); px0 += __shfl_xor(px0, 32, 64);
        px1 += __shfl_xor(px1, 16, 64); px1 += __shfl_xor(px1, 32, 64);
        if (g == 0) {
            if (id0 >= 0) atomicAdd(&out[id0], px0 + s_bl);
            if (id1 >= 0) atomicAdd(&out[id1], px1 + s_bl);
        }
    }
}

extern "C" void kernel_launch(void* const* d_in, const int* in_sizes, int n_in,
                              void* d_out, int out_size, void* d_ws, size_t ws_size,
                              hipStream_t stream)
{
    const float* coords = (const float*)d_in[0];
    const float* fw  = (const float*)d_in[1];
    const float* fb  = (const float*)d_in[2];
    const float* gw1 = (const float*)d_in[3];
    const float* gb1 = (const float*)d_in[4];
    const float* lng = (const float*)d_in[5];
    const float* lnb = (const float*)d_in[6];
    const float* gw2 = (const float*)d_in[7];
    const float* gb2 = (const float*)d_in[8];
    const float* we0 = (const float*)d_in[9];
    const float* be0 = (const float*)d_in[10];
    const float* wm  = (const float*)d_in[11];
    const float* bm  = (const float*)d_in[12];
    const float* wl  = (const float*)d_in[13];
    const float* bl  = (const float*)d_in[14];
    float* out = (float*)d_out;

    char* ws = (char*)d_ws;
    int* counts           = (int*)ws;                        // 64
    int* buckets          = (int*)(ws + 64);                 // 8*NPTS*4 = 8388608
    uint4* packA          = (uint4*)(ws + 8388672);          // 196608
    float* biasS          = (float*)(ws + 8585280);          // 6144
    int* blkcnt           = (int*)(ws + 8591424);            // 65536
    int* baseoff          = (int*)(ws + 8656960);            // 65536
    unsigned char* sel    = (unsigned char*)(ws + 8722496);  // 262144
    uint4* packGW2H       = (uint4*)(ws + 8984640);          // 2048
    uint4* packGW2L       = (uint4*)(ws + 8986688);          // 2048
    int* reflist          = (int*)(ws + 8988736);            // 1048576
    int* refcnt           = (int*)(ws + 10037312);           // 64
    float* M1             = (float*)(ws + 10037376);         // 768
    float* b1p            = (float*)(ws + 10038144);         // 256

    prep_kernel<<<58, 256, 0, stream>>>(we0, be0, wm, bm, gw1, gw2, fw, fb, gb1,
                                        packA, biasS, packGW2H, packGW2L, M1, b1p, refcnt);
    gate_kernel<<<GBLK, 256, 0, stream>>>(coords, M1, b1p, lng, lnb, gb2,
                                          packGW2H, packGW2L,
                                          sel, blkcnt, reflist, refcnt);
    refine_kernel<<<256, 256, 0, stream>>>(coords, fw, fb, gw1, gb1, lng, lnb, gw2, gb2,
                                           reflist, refcnt, sel, blkcnt);
    scan_kernel<<<8, 256, 0, stream>>>(blkcnt, baseoff, counts);
    scatter_kernel<<<GBLK, 128, 0, stream>>>(sel, baseoff, counts, buckets, out);
    expert_kernel<<<8 * CPE, 256, 0, stream>>>(coords, fw, fb, wl, bl, packA, biasS,
                                               counts, buckets, out);
}

// Round 15
// 85.769 us; speedup vs baseline: 2.4981x; 1.0884x over previous
//
#include <hip/hip_runtime.h>
#include <math.h>

#define NPTS 262144
#define GBLK (NPTS / 128)     // 2048 gate blocks / 128-pt groups
#define CPE  2048             // chunks per expert in expert grid
#define TAU  0.01f            // refine margin threshold (logit units)

typedef float f4v __attribute__((ext_vector_type(4)));
typedef short s8v __attribute__((ext_vector_type(8)));

// manual RNE (prep only; identical rounding to HW cvt)
static __device__ __forceinline__ unsigned short f2bf(float f) {
    unsigned u = __float_as_uint(f);
    u += 0x7fffu + ((u >> 16) & 1u);
    return (unsigned short)(u >> 16);
}
// HW bf16 convert (clang lowers paired fptrunc to v_cvt_pk_bf16_f32, RNE)
static __device__ __forceinline__ unsigned short f2bf_hw(float f) {
    __bf16 b = (__bf16)f;
    unsigned short u;
    __builtin_memcpy(&u, &b, 2);
    return u;
}
static __device__ __forceinline__ float bf2f(unsigned short h) {
    return __uint_as_float(((unsigned)h) << 16);
}
static __device__ __forceinline__ unsigned pk2b(unsigned short lo, unsigned short hi) {
    return ((unsigned)hi << 16) | (unsigned)lo;
}
static __device__ __forceinline__ unsigned cpack(float lo, float hi) {
    return pk2b(f2bf_hw(lo), f2bf_hw(hi));
}
static __device__ __forceinline__ float sinrev(float x) {   // sin(2*pi*x)
    return __builtin_amdgcn_sinf(x);
}

union BFrag { uint4 q; unsigned u[4]; s8v s; };

// ---- prep: expert A-frags + biases + gw2 packs + folded gate M1/b1' + folded expert M0e/b0e' ----
__global__ __launch_bounds__(256) void prep_kernel(
    const float* __restrict__ we0, const float* __restrict__ be0,
    const float* __restrict__ wm, const float* __restrict__ bm,
    const float* __restrict__ gw1, const float* __restrict__ gw2,
    const float* __restrict__ fw, const float* __restrict__ fb,
    const float* __restrict__ gb1,
    uint4* __restrict__ packA, float* __restrict__ biasS,
    uint4* __restrict__ packGW2H, uint4* __restrict__ packGW2L,
    float* __restrict__ M1, float* __restrict__ b1p,
    float* __restrict__ M0, float* __restrict__ b0p, int* __restrict__ refcnt)
{
    const int idx = blockIdx.x * 256 + threadIdx.x;
    const float PI2I = 0.15915494309189535f;
    if (idx < 12288) {
        const int l = idx & 63;
        const int fr = (idx >> 6) & 7;
        const int grp = idx >> 9;            // e*3 + ell
        const int e = grp / 3, ell = grp % 3;
        const int tau = fr >> 1, ks = fr & 1;
        const int g = l >> 4, m = l & 15;
        const int row = tau * 16 + m;
        const float scale = (ell == 0) ? (22.5f + 45.0f * (float)e) * PI2I : 30.0f * PI2I;
        const float* W = (ell == 0) ? (we0 + e * 4096) : (wm + ((ell - 1) * 8 + e) * 4096);
        unsigned short v[8];
#pragma unroll
        for (int i = 0; i < 8; i++) {
            const int k = 32 * ks + 4 * g + (i < 4 ? i : i + 12);
            v[i] = f2bf(W[row * 64 + k] * scale);
        }
        uint4 q;
        q.x = pk2b(v[0], v[1]); q.y = pk2b(v[2], v[3]);
        q.z = pk2b(v[4], v[5]); q.w = pk2b(v[6], v[7]);
        packA[idx] = q;
    } else if (idx < 13824) {
        const int j = idx - 12288;           // e*192 + ell*64 + r
        const int r = j & 63;
        const int grp = j >> 6;
        const int e = grp / 3, ell = grp % 3;
        const float scale = (ell == 0) ? (22.5f + 45.0f * (float)e) * PI2I : 30.0f * PI2I;
        const float b = (ell == 0) ? be0[e * 64 + r] : bm[((ell - 1) * 8 + e) * 64 + r];
        biasS[j] = b * scale;
    } else if (idx < 13952) {
        // gate gw2 hi/lo A-frags: rows 0..7 = gw2, rows 8..15 = 0; 2 frags (ks) x 64 lanes
        const int j = idx - 13824;           // 0..127
        const int l = j & 63;
        const int ks = j >> 6;
        const int g = l >> 4;
        const int row = l & 15;
        unsigned short vh[8], vl[8];
#pragma unroll
        for (int i = 0; i < 8; i++) {
            const int k = 32 * ks + 4 * g + (i < 4 ? i : i + 12);
            const float x = (row < 8) ? gw2[row * 64 + k] : 0.f;
            const unsigned short h = f2bf(x);
            vh[i] = h;
            vl[i] = f2bf(x - bf2f(h));
        }
        uint4 qh, ql;
        qh.x = pk2b(vh[0], vh[1]); qh.y = pk2b(vh[2], vh[3]);
        qh.z = pk2b(vh[4], vh[5]); qh.w = pk2b(vh[6], vh[7]);
        ql.x = pk2b(vl[0], vl[1]); ql.y = pk2b(vl[2], vl[3]);
        ql.z = pk2b(vl[4], vl[5]); ql.w = pk2b(vl[6], vl[7]);
        packGW2H[j] = qh; packGW2L[j] = ql;
    } else if (idx < 14144) {
        // M1 = gw1 @ fw  (64x3), fp64 accumulate
        const int m = idx - 13952;           // 0..191
        const int r = m / 3, d = m % 3;
        double s = 0.0;
        for (int j = 0; j < 64; j++) s += (double)gw1[r * 64 + j] * (double)fw[j * 3 + d];
        M1[m] = (float)s;
    } else if (idx < 14208) {
        // b1' = gw1 @ fb + gb1
        const int r = idx - 14144;           // 0..63
        double s = (double)gb1[r];
        for (int j = 0; j < 64; j++) s += (double)gw1[r * 64 + j] * (double)fb[j];
        b1p[r] = (float)s;
    } else if (idx < 15744) {
        // M0e = scale_e * (we0[e] @ fw)  (8 x 64 x 3), fp64 accumulate
        const int m = idx - 14208;           // 0..1535
        const int e = m / 192;
        const int rem = m % 192;
        const int r = rem / 3, d = rem % 3;
        const double scale = (22.5 + 45.0 * (double)e) * 0.15915494309189535;
        double s = 0.0;
        for (int j = 0; j < 64; j++) s += (double)we0[e * 4096 + r * 64 + j] * (double)fw[j * 3 + d];
        M0[m] = (float)(s * scale);
    } else if (idx < 16256) {
        // b0e' = scale_e * (we0[e] @ fb + be0[e])  (8 x 64)
        const int m = idx - 15744;           // 0..511
        const int e = m >> 6, r = m & 63;
        const double scale = (22.5 + 45.0 * (double)e) * 0.15915494309189535;
        double s = (double)be0[e * 64 + r];
        for (int j = 0; j < 64; j++) s += (double)we0[e * 4096 + r * 64 + j] * (double)fb[j];
        b0p[m] = (float)(s * scale);
    } else if (idx == 16256) {
        *refcnt = 0;
    }
}

// ---------------- K1: gate — folded stage-1 (3 FMA/row) + MFMA stage-2 (hi/lo); zeroes out[] ----------------
// 256 threads = 4 waves x 32 points = 128 points per block.
__global__ __launch_bounds__(256) void gate_kernel(
    const float* __restrict__ coords,
    const float* __restrict__ M1, const float* __restrict__ b1p,
    const float* __restrict__ lng, const float* __restrict__ lnb,
    const float* __restrict__ gb2,
    const uint4* __restrict__ packGW2H, const uint4* __restrict__ packGW2L,
    unsigned char* __restrict__ sel, int* __restrict__ blkcnt,
    int* __restrict__ reflist, int* __restrict__ refcnt, float* __restrict__ out)
{
    __shared__ float s_M1[192], s_b1p[64], s_lng[64], s_lnb[64], s_gb2[8];
    __shared__ uint4 sW2H[128], sW2L[128];      // 4 KB
    __shared__ int s_cnt[8];
    const int t = threadIdx.x;
    if (t < 128) { sW2H[t] = packGW2H[t]; sW2L[t] = packGW2L[t]; }
    if (t < 192) s_M1[t] = M1[t];
    if (t < 64) { s_b1p[t] = b1p[t]; s_lng[t] = lng[t]; s_lnb[t] = lnb[t]; }
    if (t < 8) { s_gb2[t] = gb2[t]; s_cnt[t] = 0; }
    if (t < 128) out[blockIdx.x * 128 + t] = 0.f;   // FIXED: correct, full-range zeroing
    __syncthreads();

    const int lane = t & 63;
    const int wv = t >> 6;
    const int g = lane >> 4, c = lane & 15;
    const int n0 = blockIdx.x * 128 + wv * 32 + c;
    const int n1 = n0 + 16;

    const float a0 = coords[n0 * 3], a1 = coords[n0 * 3 + 1], a2 = coords[n0 * 3 + 2];
    const float b0 = coords[n1 * 3], b1 = coords[n1 * 3 + 1], b2 = coords[n1 * 3 + 2];

    // ---- g rows directly: r = 16*tau + 4*g + j, 3 FMA each ----
    float ga[16], gb[16];
#pragma unroll
    for (int i = 0; i < 16; i++) {
        const int r = ((i >> 2) << 4) + 4 * g + (i & 3);
        const float m0 = s_M1[r * 3], m1 = s_M1[r * 3 + 1], m2 = s_M1[r * 3 + 2];
        const float bb = s_b1p[r];
        ga[i] = bb + a0 * m0 + a1 * m1 + a2 * m2;
        gb[i] = bb + b0 * m0 + b1 * m1 + b2 * m2;
    }

    // ---- LayerNorm over 64 rows (cross-lane over g groups) ----
    float s1a = 0.f, s1b = 0.f;
#pragma unroll
    for (int i = 0; i < 16; i++) { s1a += ga[i]; s1b += gb[i]; }
    s1a += __shfl_xor(s1a, 16, 64); s1a += __shfl_xor(s1a, 32, 64);
    s1b += __shfl_xor(s1b, 16, 64); s1b += __shfl_xor(s1b, 32, 64);
    const float mu0 = s1a * (1.f / 64.f), mu1 = s1b * (1.f / 64.f);
    float s2a = 0.f, s2b = 0.f;
#pragma unroll
    for (int i = 0; i < 16; i++) {
        const float d0 = ga[i] - mu0; s2a += d0 * d0;
        const float d1 = gb[i] - mu1; s2b += d1 * d1;
    }
    s2a += __shfl_xor(s2a, 16, 64); s2a += __shfl_xor(s2a, 32, 64);
    s2b += __shfl_xor(s2b, 16, 64); s2b += __shfl_xor(s2b, 32, 64);
    const float rs0 = rsqrtf(s2a * (1.f / 64.f) + 1e-5f);
    const float rs1 = rsqrtf(s2b * (1.f / 64.f) + 1e-5f);

    // ---- gn + hi/lo split + pack into B-frags ----
    BFrag Gh0[2], Gl0[2], Gh1[2], Gl1[2];
#pragma unroll
    for (int ks = 0; ks < 2; ks++) {
#pragma unroll
        for (int q = 0; q < 4; q++) {
            const int i0 = ks * 8 + 2 * q, i1 = i0 + 1;
            const int r0 = ((i0 >> 2) << 4) + 4 * g + (i0 & 3);
            const int r1 = ((i1 >> 2) << 4) + 4 * g + (i1 & 3);
            const float gnA0 = (ga[i0] - mu0) * rs0 * s_lng[r0] + s_lnb[r0];
            const float gnA1 = (ga[i1] - mu0) * rs0 * s_lng[r1] + s_lnb[r1];
            const float gnB0 = (gb[i0] - mu1) * rs1 * s_lng[r0] + s_lnb[r0];
            const float gnB1 = (gb[i1] - mu1) * rs1 * s_lng[r1] + s_lnb[r1];
            const unsigned short hA0 = f2bf_hw(gnA0), hA1 = f2bf_hw(gnA1);
            const unsigned short hB0 = f2bf_hw(gnB0), hB1 = f2bf_hw(gnB1);
            Gh0[ks].u[q] = pk2b(hA0, hA1);
            Gl0[ks].u[q] = cpack(gnA0 - bf2f(hA0), gnA1 - bf2f(hA1));
            Gh1[ks].u[q] = pk2b(hB0, hB1);
            Gl1[ks].u[q] = cpack(gnB0 - bf2f(hB0), gnB1 - bf2f(hB1));
        }
    }

    // ---- logits = gw2 @ gn via 3-term MFMA (two independent chains) ----
    f4v lacc0 = {0.f, 0.f, 0.f, 0.f}, lacc1 = {0.f, 0.f, 0.f, 0.f};
    {
        BFrag W0, W1, V0, V1;
        W0.q = sW2H[0 * 64 + lane]; W1.q = sW2H[1 * 64 + lane];
        V0.q = sW2L[0 * 64 + lane]; V1.q = sW2L[1 * 64 + lane];
        lacc0 = __builtin_amdgcn_mfma_f32_16x16x32_bf16(W0.s, Gh0[0].s, lacc0, 0, 0, 0);
        lacc1 = __builtin_amdgcn_mfma_f32_16x16x32_bf16(W0.s, Gh1[0].s, lacc1, 0, 0, 0);
        lacc0 = __builtin_amdgcn_mfma_f32_16x16x32_bf16(W1.s, Gh0[1].s, lacc0, 0, 0, 0);
        lacc1 = __builtin_amdgcn_mfma_f32_16x16x32_bf16(W1.s, Gh1[1].s, lacc1, 0, 0, 0);
        lacc0 = __builtin_amdgcn_mfma_f32_16x16x32_bf16(W0.s, Gl0[0].s, lacc0, 0, 0, 0);
        lacc1 = __builtin_amdgcn_mfma_f32_16x16x32_bf16(W0.s, Gl1[0].s, lacc1, 0, 0, 0);
        lacc0 = __builtin_amdgcn_mfma_f32_16x16x32_bf16(W1.s, Gl0[1].s, lacc0, 0, 0, 0);
        lacc1 = __builtin_amdgcn_mfma_f32_16x16x32_bf16(W1.s, Gl1[1].s, lacc1, 0, 0, 0);
        lacc0 = __builtin_amdgcn_mfma_f32_16x16x32_bf16(V0.s, Gh0[0].s, lacc0, 0, 0, 0);
        lacc1 = __builtin_amdgcn_mfma_f32_16x16x32_bf16(V0.s, Gh1[0].s, lacc1, 0, 0, 0);
        lacc0 = __builtin_amdgcn_mfma_f32_16x16x32_bf16(V1.s, Gh0[1].s, lacc0, 0, 0, 0);
        lacc1 = __builtin_amdgcn_mfma_f32_16x16x32_bf16(V1.s, Gh1[1].s, lacc1, 0, 0, 0);
    }

    float logit0[8], logit1[8];
#pragma unroll
    for (int j = 0; j < 4; j++) {
        const float o0 = __shfl_xor(lacc0[j], 16, 64);
        const float o1 = __shfl_xor(lacc1[j], 16, 64);
        logit0[j] = lacc0[j] + s_gb2[j];
        logit0[4 + j] = o0 + s_gb2[4 + j];
        logit1[j] = lacc1[j] + s_gb2[j];
        logit1[4 + j] = o1 + s_gb2[4 + j];
    }

    // ---- top-2 + margin flag (per point) ----
    unsigned mbits0 = 0, mbits1 = 0;
    bool flg0, flg1;
    {
        float m1 = logit0[0]; int i1 = 0;
#pragma unroll
        for (int e = 1; e < 8; e++) if (logit0[e] > m1) { m1 = logit0[e]; i1 = e; }
        float m2 = -INFINITY; int i2 = -1;
#pragma unroll
        for (int e = 0; e < 8; e++) if (e != i1 && logit0[e] > m2) { m2 = logit0[e]; i2 = e; }
        float m3 = -INFINITY;
#pragma unroll
        for (int e = 0; e < 8; e++) if (e != i1 && e != i2 && logit0[e] > m3) m3 = logit0[e];
#pragma unroll
        for (int e = 0; e < 8; e++) if (logit0[e] >= m2) mbits0 |= 1u << e;
        flg0 = (m2 - m3 < TAU);
    }
    {
        float m1 = logit1[0]; int i1 = 0;
#pragma unroll
        for (int e = 1; e < 8; e++) if (logit1[e] > m1) { m1 = logit1[e]; i1 = e; }
        float m2 = -INFINITY; int i2 = -1;
#pragma unroll
        for (int e = 0; e < 8; e++) if (e != i1 && logit1[e] > m2) { m2 = logit1[e]; i2 = e; }
        float m3 = -INFINITY;
#pragma unroll
        for (int e = 0; e < 8; e++) if (e != i1 && e != i2 && logit1[e] > m3) m3 = logit1[e];
#pragma unroll
        for (int e = 0; e < 8; e++) if (logit1[e] >= m2) mbits1 |= 1u << e;
        flg1 = (m2 - m3 < TAU);
    }

    const bool active = (g == 0);
    if (active) { sel[n0] = (unsigned char)mbits0; sel[n1] = (unsigned char)mbits1; }

#pragma unroll
    for (int e = 0; e < 8; e++) {
        const unsigned long long bal0 = __ballot(active && ((mbits0 >> e) & 1u));
        const unsigned long long bal1 = __ballot(active && ((mbits1 >> e) & 1u));
        if (lane == 0) atomicAdd(&s_cnt[e], (int)(__popcll(bal0) + __popcll(bal1)));
    }
    {
        const unsigned long long bal0 = __ballot(active && flg0);
        const unsigned long long bal1 = __ballot(active && flg1);
        const int p0 = (int)__popcll(bal0);
        int pos0 = 0;
        if (lane == 0 && (bal0 | bal1)) pos0 = atomicAdd(refcnt, p0 + (int)__popcll(bal1));
        pos0 = __shfl(pos0, 0, 64);
        if (active && flg0) {
            const int rank = (int)__popcll(bal0 & ((1ull << lane) - 1ull));
            reflist[pos0 + rank] = n0;
        }
        if (active && flg1) {
            const int rank = p0 + (int)__popcll(bal1 & ((1ull << lane) - 1ull));
            reflist[pos0 + rank] = n1;
        }
    }
    __syncthreads();
    if (t < 8) blkcnt[blockIdx.x * 8 + t] = s_cnt[t];
}

// ---------------- K1.25: exact-fp32 refine (reference op order), one wave per point ----------------
__global__ __launch_bounds__(256) void refine_kernel(
    const float* __restrict__ coords,
    const float* __restrict__ fw, const float* __restrict__ fb,
    const float* __restrict__ gw1, const float* __restrict__ gb1,
    const float* __restrict__ lng, const float* __restrict__ lnb,
    const float* __restrict__ gw2, const float* __restrict__ gb2,
    const int* __restrict__ reflist, const int* __restrict__ refcnt,
    unsigned char* __restrict__ sel, int* __restrict__ blkcnt)
{
    const int R = *refcnt;
    if (blockIdx.x * 4 >= R) return;            // uniform early exit, before any barrier

    __shared__ float s_gw1t[64 * 65];           // transposed + pad
    __shared__ float s_gw2[512];
    __shared__ float s_fw[192], s_fb[64], s_gb1[64], s_lng[64], s_lnb[64], s_gb2[8];
    __shared__ float s_f[4][64];

    const int t = threadIdx.x;
    for (int i = t; i < 4096; i += 256) s_gw1t[(i & 63) * 65 + (i >> 6)] = gw1[i];
    for (int i = t; i < 512; i += 256) s_gw2[i] = gw2[i];
    if (t < 192) s_fw[t] = fw[t];
    if (t < 64) { s_fb[t] = fb[t]; s_gb1[t] = gb1[t]; s_lng[t] = lng[t]; s_lnb[t] = lnb[t]; }
    if (t < 8) s_gb2[t] = gb2[t];
    __syncthreads();

    const int wv = t >> 6, lane = t & 63;
    for (int idx = blockIdx.x * 4 + wv; idx < R; idx += gridDim.x * 4) {
        const int n = reflist[idx];
        const float c0 = coords[n * 3], c1 = coords[n * 3 + 1], c2 = coords[n * 3 + 2];
        const float fr = s_fb[lane] + c0 * s_fw[lane * 3] + c1 * s_fw[lane * 3 + 1]
                       + c2 * s_fw[lane * 3 + 2];
        s_f[wv][lane] = fr;
        float a = s_gb1[lane];
#pragma unroll
        for (int k = 0; k < 64; k++)
            a += s_f[wv][k] * s_gw1t[k * 65 + lane];
        float mu = a;
#pragma unroll
        for (int d = 1; d < 64; d <<= 1) mu += __shfl_xor(mu, d, 64);
        mu *= (1.f / 64.f);
        const float dv = a - mu;
        float v = dv * dv;
#pragma unroll
        for (int d = 1; d < 64; d <<= 1) v += __shfl_xor(v, d, 64);
        const float rs = rsqrtf(v * (1.f / 64.f) + 1e-5f);
        const float gn = dv * rs * s_lng[lane] + s_lnb[lane];
        float lp[8];
#pragma unroll
        for (int e = 0; e < 8; e++) lp[e] = gn * s_gw2[e * 64 + lane];
#pragma unroll
        for (int e = 0; e < 8; e++) {
#pragma unroll
            for (int d = 1; d < 64; d <<= 1) lp[e] += __shfl_xor(lp[e], d, 64);
            lp[e] += s_gb2[e];
        }
        if (lane == 0) {
            float m1 = lp[0]; int i1 = 0;
#pragma unroll
            for (int e = 1; e < 8; e++) if (lp[e] > m1) { m1 = lp[e]; i1 = e; }
            float m2 = -INFINITY;
#pragma unroll
            for (int e = 0; e < 8; e++) if (e != i1 && lp[e] > m2) m2 = lp[e];
            unsigned mbits = 0;
#pragma unroll
            for (int e = 0; e < 8; e++) if (lp[e] >= m2) mbits |= 1u << e;
            const unsigned old = sel[n];
            if (mbits != old) {
                sel[n] = (unsigned char)mbits;
                const int b = n >> 7;
#pragma unroll
                for (int e = 0; e < 8; e++) {
                    const int was = (old >> e) & 1, now = (mbits >> e) & 1;
                    if (was != now) atomicAdd(&blkcnt[b * 8 + e], now - was);
                }
            }
        }
    }
}

// ---------------- K1.5: scan, one block per expert ----------------
__global__ __launch_bounds__(256) void scan_kernel(
    const int* __restrict__ blkcnt, int* __restrict__ baseoff,
    int* __restrict__ counts)
{
    const int e = blockIdx.x;          // 0..7
    const int t = threadIdx.x;         // each thread: 8 consecutive 128-pt groups
    const int lane = t & 63, wv = t >> 6;
    __shared__ int s_w[4];

    int v[8]; int sum = 0;
#pragma unroll
    for (int i = 0; i < 8; i++) { v[i] = blkcnt[(t * 8 + i) * 8 + e]; sum += v[i]; }
    int incl = sum;
#pragma unroll
    for (int d = 1; d < 64; d <<= 1) {
        const int x = __shfl_up(incl, d, 64);
        if (lane >= d) incl += x;
    }
    if (lane == 63) s_w[wv] = incl;
    __syncthreads();
    int woff = 0;
#pragma unroll
    for (int i = 0; i < 4; i++) if (i < wv) woff += s_w[i];
    int run = woff + incl - sum;
#pragma unroll
    for (int i = 0; i < 8; i++) { baseoff[(t * 8 + i) * 8 + e] = run; run += v[i]; }
    if (t == 255) counts[e] = run;
}

// ---------------- K2: scatter + aux ----------------
__global__ __launch_bounds__(128) void scatter_kernel(
    const unsigned char* __restrict__ sel, const int* __restrict__ baseoff,
    const int* __restrict__ counts, int* __restrict__ buckets, float* __restrict__ out)
{
    __shared__ int s_w0[8];
    const int t = threadIdx.x;
    const int n = blockIdx.x * 128 + t;
    if (blockIdx.x == 0 && t == 0) {
        double s = 0.0;
        for (int e = 0; e < 8; e++) { const double c = (double)counts[e]; s += c * c; }
        out[NPTS] = (float)(8.0 * s / ((double)NPTS * (double)NPTS));
    }
    const unsigned m = sel[n];
    const int w = t >> 6, lane = t & 63;
    unsigned long long bal[8];
#pragma unroll
    for (int e = 0; e < 8; e++) {
        bal[e] = __ballot((m >> e) & 1u);
        if (w == 0 && lane == 0) s_w0[e] = (int)__popcll(bal[e]);
    }
    __syncthreads();
#pragma unroll
    for (int e = 0; e < 8; e++) {
        if ((m >> e) & 1u) {
            int rank = (int)__popcll(bal[e] & ((1ull << lane) - 1ull));
            if (w == 1) rank += s_w0[e];
            buckets[e * NPTS + baseoff[blockIdx.x * 8 + e] + rank] = n;
        }
    }
}

// ---------------- K3: per-expert MFMA SIREN; layer-0 folded to 3-FMA direct D-layout ----------------
__global__ __launch_bounds__(256) void expert_kernel(
    const float* __restrict__ coords,
    const float* __restrict__ M0, const float* __restrict__ b0p,
    const float* __restrict__ wl, const float* __restrict__ bl,
    const uint4* __restrict__ packA, const float* __restrict__ biasS,
    const int* __restrict__ counts, const int* __restrict__ buckets,
    float* __restrict__ out)
{
    const int e = blockIdx.x >> 11;            // CPE == 2048
    const int chunk = blockIdx.x & (CPE - 1);
    const int cnt = counts[e];
    const int base = chunk * 128;
    if (base >= cnt) return;

    __shared__ float s_b[192];                 // biasS[e]: ell=1 at [64..127], ell=2 at [128..191]
    __shared__ float s_wl[64];
    __shared__ float s_M0[192];
    __shared__ float s_b0p[64];
    __shared__ float s_bl;

    const int t = threadIdx.x;
    if (t < 192) {
        s_b[t] = biasS[e * 192 + t];
        s_M0[t] = M0[e * 192 + t];
    }
    if (t < 64) {
        s_b0p[t] = b0p[e * 64 + t];
        s_wl[t] = wl[e * 64 + t];
    }
    if (t == 0) s_bl = bl[e];
    __syncthreads();

    const int lane = t & 63;
    const int wv = t >> 6;
    const int g = lane >> 4, c = lane & 15;
    const int i0 = base + wv * 32 + c;
    const int i1 = i0 + 16;
    const int id0 = (i0 < cnt) ? buckets[e * NPTS + i0] : -1;
    const int id1 = (i1 < cnt) ? buckets[e * NPTS + i1] : -1;

    const float a0 = (id0 >= 0) ? coords[id0 * 3] : 0.f;
    const float a1 = (id0 >= 0) ? coords[id0 * 3 + 1] : 0.f;
    const float a2 = (id0 >= 0) ? coords[id0 * 3 + 2] : 0.f;
    const float b0 = (id1 >= 0) ? coords[id1 * 3] : 0.f;
    const float b1 = (id1 >= 0) ? coords[id1 * 3 + 1] : 0.f;
    const float b2 = (id1 >= 0) ? coords[id1 * 3 + 2] : 0.f;

    // ---- layer 0 folded: z0[r] = b0p[r] + M0[r]·c, directly in D layout (r = 16*tau + 4*g + j) ----
    f4v acc0[4], acc1[4];
#pragma unroll
    for (int tau = 0; tau < 4; tau++) {
#pragma unroll
        for (int j = 0; j < 4; j++) {
            const int r = tau * 16 + 4 * g + j;
            const float m0 = s_M0[r * 3], m1 = s_M0[r * 3 + 1], m2 = s_M0[r * 3 + 2];
            const float bb = s_b0p[r];
            acc0[tau][j] = bb + a0 * m0 + a1 * m1 + a2 * m2;
            acc1[tau][j] = bb + b0 * m0 + b1 * m1 + b2 * m2;
        }
    }

    // ---- sin + repack -> layer-1 B fragments ----
    BFrag B0[2], B1[2];
#pragma unroll
    for (int ks = 0; ks < 2; ks++) {
        B0[ks].u[0] = cpack(sinrev(acc0[2 * ks][0]), sinrev(acc0[2 * ks][1]));
        B0[ks].u[1] = cpack(sinrev(acc0[2 * ks][2]), sinrev(acc0[2 * ks][3]));
        B0[ks].u[2] = cpack(sinrev(acc0[2 * ks + 1][0]), sinrev(acc0[2 * ks + 1][1]));
        B0[ks].u[3] = cpack(sinrev(acc0[2 * ks + 1][2]), sinrev(acc0[2 * ks + 1][3]));
        B1[ks].u[0] = cpack(sinrev(acc1[2 * ks][0]), sinrev(acc1[2 * ks][1]));
        B1[ks].u[1] = cpack(sinrev(acc1[2 * ks][2]), sinrev(acc1[2 * ks][3]));
        B1[ks].u[2] = cpack(sinrev(acc1[2 * ks + 1][0]), sinrev(acc1[2 * ks + 1][1]));
        B1[ks].u[3] = cpack(sinrev(acc1[2 * ks + 1][2]), sinrev(acc1[2 * ks + 1][3]));
    }

    // ---- layer 1 (MFMA) ----
    {
#pragma unroll
        for (int tau = 0; tau < 4; tau++) {
            const float4 b = *(const float4*)&s_b[64 + tau * 16 + 4 * g];
            acc0[tau][0] = b.x; acc0[tau][1] = b.y; acc0[tau][2] = b.z; acc0[tau][3] = b.w;
            acc1[tau][0] = b.x; acc1[tau][1] = b.y; acc1[tau][2] = b.z; acc1[tau][3] = b.w;
        }
        const uint4* Ab = packA + (size_t)((e * 3 + 1) * 8) * 64 + lane;
#pragma unroll
        for (int tau = 0; tau < 4; tau++) {
            BFrag A0, A1;
            A0.q = Ab[(tau * 2 + 0) * 64];
            A1.q = Ab[(tau * 2 + 1) * 64];
            acc0[tau] = __builtin_amdgcn_mfma_f32_16x16x32_bf16(A0.s, B0[0].s, acc0[tau], 0, 0, 0);
            acc0[tau] = __builtin_amdgcn_mfma_f32_16x16x32_bf16(A1.s, B0[1].s, acc0[tau], 0, 0, 0);
            acc1[tau] = __builtin_amdgcn_mfma_f32_16x16x32_bf16(A0.s, B1[0].s, acc1[tau], 0, 0, 0);
            acc1[tau] = __builtin_amdgcn_mfma_f32_16x16x32_bf16(A1.s, B1[1].s, acc1[tau], 0, 0, 0);
        }
#pragma unroll
        for (int ks = 0; ks < 2; ks++) {
            B0[ks].u[0] = cpack(sinrev(acc0[2 * ks][0]), sinrev(acc0[2 * ks][1]));
            B0[ks].u[1] = cpack(sinrev(acc0[2 * ks][2]), sinrev(acc0[2 * ks][3]));
            B0[ks].u[2] = cpack(sinrev(acc0[2 * ks + 1][0]), sinrev(acc0[2 * ks + 1][1]));
            B0[ks].u[3] = cpack(sinrev(acc0[2 * ks + 1][2]), sinrev(acc0[2 * ks + 1][3]));
            B1[ks].u[0] = cpack(sinrev(acc1[2 * ks][0]), sinrev(acc1[2 * ks][1]));
            B1[ks].u[1] = cpack(sinrev(acc1[2 * ks][2]), sinrev(acc1[2 * ks][3]));
            B1[ks].u[2] = cpack(sinrev(acc1[2 * ks + 1][0]), sinrev(acc1[2 * ks + 1][1]));
            B1[ks].u[3] = cpack(sinrev(acc1[2 * ks + 1][2]), sinrev(acc1[2 * ks + 1][3]));
        }
    }

    // ---- layer 2 + final dot ----
    {
#pragma unroll
        for (int tau = 0; tau < 4; tau++) {
            const float4 b = *(const float4*)&s_b[128 + tau * 16 + 4 * g];
            acc0[tau][0] = b.x; acc0[tau][1] = b.y; acc0[tau][2] = b.z; acc0[tau][3] = b.w;
            acc1[tau][0] = b.x; acc1[tau][1] = b.y; acc1[tau][2] = b.z; acc1[tau][3] = b.w;
        }
        const uint4* Ab = packA + (size_t)((e * 3 + 2) * 8) * 64 + lane;
#pragma unroll
        for (int tau = 0; tau < 4; tau++) {
            BFrag A0, A1;
            A0.q = Ab[(tau * 2 + 0) * 64];
            A1.q = Ab[(tau * 2 + 1) * 64];
            acc0[tau] = __builtin_amdgcn_mfma_f32_16x16x32_bf16(A0.s, B0[0].s, acc0[tau], 0, 0, 0);
            acc0[tau] = __builtin_amdgcn_mfma_f32_16x16x32_bf16(A1.s, B0[1].s, acc0[tau], 0, 0, 0);
            acc1[tau] = __builtin_amdgcn_mfma_f32_16x16x32_bf16(A0.s, B1[0].s, acc1[tau], 0, 0, 0);
            acc1[tau] = __builtin_amdgcn_mfma_f32_16x16x32_bf16(A1.s, B1[1].s, acc1[tau], 0, 0, 0);
        }
        float px0 = 0.f, px1 = 0.f;
#pragma unroll
        for (int tau = 0; tau < 4; tau++) {
            const float4 w = *(const float4*)&s_wl[tau * 16 + 4 * g];
            px0 += sinrev(acc0[tau][0]) * w.x + sinrev(acc0[tau][1]) * w.y
                 + sinrev(acc0[tau][2]) * w.z + sinrev(acc0[tau][3]) * w.w;
            px1 += sinrev(acc1[tau][0]) * w.x + sinrev(acc1[tau][1]) * w.y
                 + sinrev(acc1[tau][2]) * w.z + sinrev(acc1[tau][3]) * w.w;
        }
        px0 += __shfl_xor(px0, 16, 64); px0 += __shfl_xor(px0, 32, 64);
        px1 += __shfl_xor(px1, 16, 64); px1 += __shfl_xor(px1, 32, 64);
        if (g == 0) {
            if (id0 >= 0) atomicAdd(&out[id0], px0 + s_bl);
            if (id1 >= 0) atomicAdd(&out[id1], px1 + s_bl);
        }
    }
}

extern "C" void kernel_launch(void* const* d_in, const int* in_sizes, int n_in,
                              void* d_out, int out_size, void* d_ws, size_t ws_size,
                              hipStream_t stream)
{
    const float* coords = (const float*)d_in[0];
    const float* fw  = (const float*)d_in[1];
    const float* fb  = (const float*)d_in[2];
    const float* gw1 = (const float*)d_in[3];
    const float* gb1 = (const float*)d_in[4];
    const float* lng = (const float*)d_in[5];
    const float* lnb = (const float*)d_in[6];
    const float* gw2 = (const float*)d_in[7];
    const float* gb2 = (const float*)d_in[8];
    const float* we0 = (const float*)d_in[9];
    const float* be0 = (const float*)d_in[10];
    const float* wm  = (const float*)d_in[11];
    const float* bm  = (const float*)d_in[12];
    const float* wl  = (const float*)d_in[13];
    const float* bl  = (const float*)d_in[14];
    float* out = (float*)d_out;

    char* ws = (char*)d_ws;
    int* counts           = (int*)ws;                        // 64
    int* buckets          = (int*)(ws + 64);                 // 8*NPTS*4 = 8388608
    uint4* packA          = (uint4*)(ws + 8388672);          // 196608
    float* biasS          = (float*)(ws + 8585280);          // 6144
    int* blkcnt           = (int*)(ws + 8591424);            // 65536
    int* baseoff          = (int*)(ws + 8656960);            // 65536
    unsigned char* sel    = (unsigned char*)(ws + 8722496);  // 262144
    uint4* packGW2H       = (uint4*)(ws + 8984640);          // 2048
    uint4* packGW2L       = (uint4*)(ws + 8986688);          // 2048
    int* reflist          = (int*)(ws + 8988736);            // 1048576
    int* refcnt           = (int*)(ws + 10037312);           // 64
    float* M1             = (float*)(ws + 10037376);         // 768
    float* b1p            = (float*)(ws + 10038144);         // 256
    float* M0             = (float*)(ws + 10038400);         // 8*192*4 = 6144
    float* b0p            = (float*)(ws + 10044544);         // 8*64*4 = 2048

    prep_kernel<<<64, 256, 0, stream>>>(we0, be0, wm, bm, gw1, gw2, fw, fb, gb1,
                                        packA, biasS, packGW2H, packGW2L, M1, b1p,
                                        M0, b0p, refcnt);
    gate_kernel<<<GBLK, 256, 0, stream>>>(coords, M1, b1p, lng, lnb, gb2,
                                          packGW2H, packGW2L,
                                          sel, blkcnt, reflist, refcnt, out);
    refine_kernel<<<256, 256, 0, stream>>>(coords, fw, fb, gw1, gb1, lng, lnb, gw2, gb2,
                                           reflist, refcnt, sel, blkcnt);
    scan_kernel<<<8, 256, 0, stream>>>(blkcnt, baseoff, counts);
    scatter_kernel<<<GBLK, 128, 0, stream>>>(sel, baseoff, counts, buckets, out);
    expert_kernel<<<8 * CPE, 256, 0, stream>>>(coords, M0, b0p, wl, bl, packA, biasS,
                                               counts, buckets, out);
}